// Round 12
// baseline (1404.689 us; speedup 1.0000x reference)
//
#include <hip/hip_runtime.h>
#include <hip/hip_bf16.h>
#include <math.h>
#include <stddef.h>

#define BB 32
#define TT 262
#define DD 512
#define SS 16
#define RR 32
#define SEQ 512
#define NV 256
#define PRED 96
#define MROWS (BB*TT)   // 8384

typedef __attribute__((ext_vector_type(4))) float f32x4;
typedef __attribute__((ext_vector_type(8))) short s16x8;

// ---------------- bf16 helpers ----------------
__device__ inline ushort f2bu(float x) {
    __hip_bfloat16 h = __float2bfloat16(x);
    ushort u; __builtin_memcpy(&u, &h, 2); return u;
}
__device__ inline float bu2f(ushort u) {
    __hip_bfloat16 h; __builtin_memcpy(&h, &u, 2);
    return __bfloat162float(h);
}
// activation 3K pack: [hi | lo | hi]
__device__ inline void pack_act(ushort* base, int col, int Kd, float v) {
    ushort hu = f2bu(v);
    float hf = bu2f(hu);
    ushort lu = f2bu(v - hf);
    base[col] = hu; base[Kd + col] = lu; base[2*Kd + col] = hu;
}

// async global->LDS, 16B per lane
__device__ inline void gload_lds16(const void* g, void* l) {
    __builtin_amdgcn_global_load_lds(
        (const __attribute__((address_space(1))) void*)g,
        (__attribute__((address_space(3))) void*)l, 16, 0, 0);
}

// ---------------------------------------------------------------------------
// weight 3K pack: [hi | hi | lo], K=512 rows
// ---------------------------------------------------------------------------
__global__ __launch_bounds__(256)
void pack3w(const float* __restrict__ in, ushort* __restrict__ out, int total)
{
    int idx = blockIdx.x * 256 + threadIdx.x;
    if (idx >= total) return;
    int r = idx >> 9, k = idx & 511;
    float x = in[idx];
    ushort hu = f2bu(x);
    float hf = bu2f(hu);
    ushort lu = f2bu(x - hf);
    size_t b = (size_t)r * 1536;
    out[b + k] = hu; out[b + 512 + k] = hu; out[b + 1024 + k] = lu;
}

// ---------------------------------------------------------------------------
// combined scan-projection weight (dt path folded through wdt)
// ---------------------------------------------------------------------------
__global__ __launch_bounds__(256)
void mkcomb(const float* __restrict__ wx, const float* __restrict__ wdt,
            ushort* __restrict__ comb3)
{
    int n  = blockIdx.x;
    int li = blockIdx.y;
    const float* wxl = wx + (size_t)li*64*512;
    ushort* outb = comb3 + ((size_t)li*544 + n)*1536;
    if (n < 512) {
        __shared__ float wr[32];
        if (threadIdx.x < 32)
            wr[threadIdx.x] = wdt[(size_t)li*512*32 + (size_t)n*32 + threadIdx.x];
        __syncthreads();
        for (int kk = threadIdx.x; kk < 512; kk += 256) {
            float acc = 0.f;
            #pragma unroll
            for (int r = 0; r < 32; ++r)
                acc = fmaf(wr[r], wxl[r*512 + kk], acc);
            ushort hu = f2bu(acc); float hf = bu2f(hu);
            ushort lu = f2bu(acc - hf);
            outb[kk] = hu; outb[512+kk] = hu; outb[1024+kk] = lu;
        }
    } else {
        int s = n - 512;
        for (int kk = threadIdx.x; kk < 512; kk += 256) {
            float v = wxl[(32+s)*512 + kk];
            ushort hu = f2bu(v); float hf = bu2f(hu);
            ushort lu = f2bu(v - hf);
            outb[kk] = hu; outb[512+kk] = hu; outb[1024+kk] = lu;
        }
    }
}

// ---------------------------------------------------------------------------
// per-(b,n) mean/std over SEQ
// ---------------------------------------------------------------------------
__global__ __launch_bounds__(256)
void stats_kernel(const float* __restrict__ x_enc,
                  float* __restrict__ mean, float* __restrict__ stdv)
{
    int b  = blockIdx.x >> 2;
    int n0 = (blockIdx.x & 3) << 6;
    int lane = threadIdx.x & 63;
    int w    = threadIdx.x >> 6;
    int n = n0 + lane;
    float s = 0.f, s2 = 0.f;
    for (int t = w; t < SEQ; t += 4) {
        float v = x_enc[((size_t)b*SEQ + t)*NV + n];
        s += v; s2 += v*v;
    }
    __shared__ float ls[4][64], ls2[4][64];
    ls[w][lane] = s; ls2[w][lane] = s2;
    __syncthreads();
    if (w == 0) {
        s  = ls[0][lane] + ls[1][lane] + ls[2][lane] + ls[3][lane];
        s2 = ls2[0][lane] + ls2[1][lane] + ls2[2][lane] + ls2[3][lane];
        float mu  = s * (1.f/SEQ);
        float var = s2 * (1.f/SEQ) - mu*mu;
        mean[b*NV + n] = mu;
        stdv[b*NV + n] = sqrtf(var + 1e-5f);
    }
}

// ---------------------------------------------------------------------------
// tok3: normalized transpose packed [hi|lo|hi] over K=512
// ---------------------------------------------------------------------------
__global__ __launch_bounds__(256)
void tok_kernel(const float* __restrict__ x_enc, const float* __restrict__ x_mark,
                const float* __restrict__ mean, const float* __restrict__ stdv,
                ushort* __restrict__ tok3)
{
    int b  = blockIdx.x / 40;
    int r  = blockIdx.x % 40;
    int tt = r / 5;
    int vt = r % 5;
    int t0 = tt << 6, v0 = vt << 6;
    __shared__ float tile[64][65];
    int lv = threadIdx.x & 63;
    for (int i = threadIdx.x >> 6; i < 64; i += 4) {
        int t = t0 + i, v = v0 + lv;
        float val = 0.f;
        if (v < NV) {
            val = (x_enc[((size_t)b*SEQ + t)*NV + v] - mean[b*NV + v]) / stdv[b*NV + v];
        } else if (v < TT) {
            val = x_mark[((size_t)b*SEQ + t)*6 + (v - NV)];
        }
        tile[i][lv] = val;
    }
    __syncthreads();
    for (int i = threadIdx.x >> 6; i < 64; i += 4) {
        int v = v0 + i;
        if (v < TT) {
            size_t row = (size_t)b*TT + v;
            pack_act(tok3 + row*1536, t0 + lv, 512, tile[lv][i]);
        }
    }
}

// ---------------------------------------------------------------------------
// bf16 MFMA GEMM over packed 3K operands (NT; K3 multiple of 64).
// ---------------------------------------------------------------------------
template<int HAS_BIAS, int RELU, int WF32, int W3, int SCANEP>
__global__ __launch_bounds__(256)
void gemm3(const ushort* __restrict__ A3, int lda3,
           const ushort* __restrict__ W3p, int ldw3,
           const float* __restrict__ bias,
           float* __restrict__ C, int ldc,
           ushort* __restrict__ C3, int N_out,
           float* __restrict__ bcbuf,
           int M, int Nn, int K3)
{
    __shared__ ushort lds[2][2][128*64];   // [buf][A=0/W=1] : 64 KB
    const int tid  = threadIdx.x;
    const int lane = tid & 63;
    const int wid  = tid >> 6;
    const int wr = wid >> 1, wc = wid & 1;
    const int m0 = blockIdx.x * 128;
    const int n0 = blockIdx.y * 128;

    const int l8 = lane >> 3;
    const int sl = lane & 7;
    const int ssl = sl ^ l8;

    int arow[4], wrow[4];
    #pragma unroll
    for (int q = 0; q < 4; ++q) {
        int r = (wid*4 + q)*8 + l8;
        int ar = m0 + r; if (ar > M-1) ar = M-1;
        arow[q] = ar;
        int wrr = n0 + r; if (wrr > Nn-1) wrr = Nn-1;
        wrow[q] = wrr;
    }

    f32x4 acc[4][4];
    #pragma unroll
    for (int i = 0; i < 4; ++i)
        #pragma unroll
        for (int j = 0; j < 4; ++j) acc[i][j] = (f32x4){0.f,0.f,0.f,0.f};

    const int nk = K3 >> 6;
    const int rl = lane & 15;
    const int kq = lane >> 4;

    auto stage = [&](int buf_, int kt_) {
        #pragma unroll
        for (int q = 0; q < 4; ++q) {
            int c = wid*4 + q;
            gload_lds16(A3 + (size_t)arow[q]*lda3 + kt_*64 + ssl*8,
                        (void*)&lds[buf_][0][c*512]);
            gload_lds16(W3p + (size_t)wrow[q]*ldw3 + kt_*64 + ssl*8,
                        (void*)&lds[buf_][1][c*512]);
        }
    };

    stage(0, 0);
    __syncthreads();

    for (int kt = 0; kt < nk; ++kt) {
        int cur = kt & 1;
        if (kt + 1 < nk) stage(cur ^ 1, kt + 1);
        #pragma unroll
        for (int kk = 0; kk < 2; ++kk) {
            s16x8 av[4], wv[4];
            #pragma unroll
            for (int mi = 0; mi < 4; ++mi) {
                int row = wr*64 + mi*16 + rl;
                int ck = (kk*4 + kq) ^ (row & 7);
                av[mi] = *(const s16x8*)&lds[cur][0][row*64 + (ck<<3)];
            }
            #pragma unroll
            for (int ni = 0; ni < 4; ++ni) {
                int row = wc*64 + ni*16 + rl;
                int ck = (kk*4 + kq) ^ (row & 7);
                wv[ni] = *(const s16x8*)&lds[cur][1][row*64 + (ck<<3)];
            }
            #pragma unroll
            for (int mi = 0; mi < 4; ++mi)
                #pragma unroll
                for (int ni = 0; ni < 4; ++ni)
                    acc[mi][ni] = __builtin_amdgcn_mfma_f32_16x16x32_bf16(
                        av[mi], wv[ni], acc[mi][ni], 0, 0, 0);
        }
        __syncthreads();
    }

    #pragma unroll
    for (int ni = 0; ni < 4; ++ni) {
        int n = n0 + wc*64 + ni*16 + rl;
        if (n >= Nn) continue;
        float bv = (HAS_BIAS && !SCANEP) ? bias[n] : 0.f;
        #pragma unroll
        for (int mi = 0; mi < 4; ++mi) {
            #pragma unroll
            for (int j = 0; j < 4; ++j) {
                int m = m0 + wr*64 + mi*16 + kq*4 + j;
                if (m >= M) continue;
                float v = acc[mi][ni][j];
                if (SCANEP) {
                    if (n < 512) {
                        v += bias[n];
                        v = fmaxf(v, 0.f) + log1pf(__expf(-fabsf(v)));
                        C[(size_t)m*ldc + n] = v;
                    } else {
                        bcbuf[(size_t)m*32 + (n - 512)] = v;
                    }
                } else {
                    if (HAS_BIAS) v += bv;
                    if (RELU) v = fmaxf(v, 0.f);
                    if (WF32) C[(size_t)m*ldc + n] = v;
                    if (W3)   pack_act(C3 + (size_t)m*(3*N_out), n, N_out, v);
                }
            }
        }
    }
}

// ---------------------------------------------------------------------------
// conv + SiLU (fp32 xc + packed xc3), in-place silu on z-half of xz
// ---------------------------------------------------------------------------
__global__ __launch_bounds__(256)
void conv_silu(float* __restrict__ xz, const float* __restrict__ cw,
               const float* __restrict__ cb, float* __restrict__ xc,
               ushort* __restrict__ xc3, int rev)
{
    int idx = blockIdx.x * 256 + threadIdx.x;
    int d  = idx & (DD-1);
    int bt = idx >> 9;
    int t  = bt % TT;
    float cur = xz[(size_t)bt*2*DD + d];
    int tn = rev ? t + 1 : t - 1;
    float prev = 0.f;
    if (tn >= 0 && tn < TT)
        prev = xz[((size_t)bt + (rev ? 1 : -1))*2*DD + d];
    float v = prev*cw[d*2] + cur*cw[d*2+1] + cb[d];
    float sv = v / (1.f + __expf(-v));
    xc[idx] = sv;
    pack_act(xc3 + (size_t)bt*1536, d, 512, sv);
    float z = xz[(size_t)bt*2*DD + DD + d];
    xz[(size_t)bt*2*DD + DD + d] = z / (1.f + __expf(-z));
}

// ---------------------------------------------------------------------------
// scan5: one thread owns (b, d) with ALL 16 states in registers. NO shuffles.
// grid = BB*4 = 128 blocks, block 128 (d's). Per-dir launch.
// B/C staged per-16-steps in [16][40] LDS (16B-aligned rows, broadcast reads).
// ---------------------------------------------------------------------------
__global__ __launch_bounds__(128)
void scan5(const float* __restrict__ sp_g, const float* __restrict__ xc_g,
           const float* __restrict__ xz_g, const float* __restrict__ bc_g,
           const float* __restrict__ alog, const float* __restrict__ dparam,
           ushort* __restrict__ y3, int rev)
{
    int dq = blockIdx.x & 3;
    int b  = blockIdx.x >> 2;
    int tid = threadIdx.x;
    int d = dq*128 + tid;
    size_t bbase = (size_t)b*TT;

    float Ac[16];
    #pragma unroll
    for (int s = 0; s < 16; ++s) Ac[s] = -__expf(alog[d*SS + s]);
    float dp = dparam[d];
    float h0=0,h1=0,h2=0,h3=0,h4=0,h5=0,h6=0,h7=0;
    float h8=0,h9=0,h10=0,h11=0,h12=0,h13=0,h14=0,h15=0;

    __shared__ float bcs[16][40];          // row stride 160B -> f4 aligned
    int rbc = tid >> 3, cbc = (tid & 7) << 2;

    auto growc = [&](int t) {
        if (t > TT-1) t = TT-1;
        return rev ? TT-1-t : t;
    };

    float4 bcpre = *(const float4*)(bc_g + (bbase + growc(rbc))*32 + cbc);

    float s4[4], x4[4], z4[4], sn[4], xn[4], zn[4];
    auto ld4 = [&](int tb, float* S, float* X, float* Z) {
        #pragma unroll
        for (int i = 0; i < 4; ++i) {
            size_t p = bbase + growc(tb + i);
            S[i] = sp_g[p*DD + d];
            X[i] = xc_g[p*DD + d];
            Z[i] = xz_g[p*2*DD + DD + d];
        }
    };
    ld4(0, s4, x4, z4);

    const int NCH = 17;                    // 17*16 = 272 >= 262
    for (int c = 0; c < NCH; ++c) {
        __syncthreads();
        *(float4*)&bcs[rbc][cbc] = bcpre;
        __syncthreads();
        if (c + 1 < NCH)
            bcpre = *(const float4*)(bc_g + (bbase + growc((c+1)*16 + rbc))*32 + cbc);
        #pragma unroll
        for (int g = 0; g < 4; ++g) {
            int tb = c*16 + g*4;
            if (tb + 4 < NCH*16) ld4(tb + 4, sn, xn, zn);
            #pragma unroll
            for (int i = 0; i < 4; ++i) {
                int st = g*4 + i;
                float4 B0 = *(const float4*)&bcs[st][0];
                float4 B1 = *(const float4*)&bcs[st][4];
                float4 B2 = *(const float4*)&bcs[st][8];
                float4 B3 = *(const float4*)&bcs[st][12];
                float4 C0 = *(const float4*)&bcs[st][16];
                float4 C1 = *(const float4*)&bcs[st][20];
                float4 C2 = *(const float4*)&bcs[st][24];
                float4 C3 = *(const float4*)&bcs[st][28];
                float spv = s4[i], xcv = x4[i];
                float dtxc = spv * xcv;
                float acc = 0.f;
                h0  = fmaf(__expf(spv*Ac[0]),  h0,  dtxc*B0.x); acc = fmaf(h0,  C0.x, acc);
                h1  = fmaf(__expf(spv*Ac[1]),  h1,  dtxc*B0.y); acc = fmaf(h1,  C0.y, acc);
                h2  = fmaf(__expf(spv*Ac[2]),  h2,  dtxc*B0.z); acc = fmaf(h2,  C0.z, acc);
                h3  = fmaf(__expf(spv*Ac[3]),  h3,  dtxc*B0.w); acc = fmaf(h3,  C0.w, acc);
                h4  = fmaf(__expf(spv*Ac[4]),  h4,  dtxc*B1.x); acc = fmaf(h4,  C1.x, acc);
                h5  = fmaf(__expf(spv*Ac[5]),  h5,  dtxc*B1.y); acc = fmaf(h5,  C1.y, acc);
                h6  = fmaf(__expf(spv*Ac[6]),  h6,  dtxc*B1.z); acc = fmaf(h6,  C1.z, acc);
                h7  = fmaf(__expf(spv*Ac[7]),  h7,  dtxc*B1.w); acc = fmaf(h7,  C1.w, acc);
                h8  = fmaf(__expf(spv*Ac[8]),  h8,  dtxc*B2.x); acc = fmaf(h8,  C2.x, acc);
                h9  = fmaf(__expf(spv*Ac[9]),  h9,  dtxc*B2.y); acc = fmaf(h9,  C2.y, acc);
                h10 = fmaf(__expf(spv*Ac[10]), h10, dtxc*B2.z); acc = fmaf(h10, C2.z, acc);
                h11 = fmaf(__expf(spv*Ac[11]), h11, dtxc*B2.w); acc = fmaf(h11, C2.w, acc);
                h12 = fmaf(__expf(spv*Ac[12]), h12, dtxc*B3.x); acc = fmaf(h12, C3.x, acc);
                h13 = fmaf(__expf(spv*Ac[13]), h13, dtxc*B3.y); acc = fmaf(h13, C3.y, acc);
                h14 = fmaf(__expf(spv*Ac[14]), h14, dtxc*B3.z); acc = fmaf(h14, C3.z, acc);
                h15 = fmaf(__expf(spv*Ac[15]), h15, dtxc*B3.w); acc = fmaf(h15, C3.w, acc);
                int t = tb + i;
                if (t < TT) {
                    int tg = rev ? TT-1-t : t;
                    float yv = (acc + dp*xcv) * z4[i];
                    pack_act(y3 + (bbase + tg)*1536, d, 512, yv);
                }
            }
            #pragma unroll
            for (int i = 0; i < 4; ++i) { s4[i]=sn[i]; x4[i]=xn[i]; z4[i]=zn[i]; }
        }
    }
}

// ---------------------------------------------------------------------------
// LayerNorm (up to 3 summed inputs), optional 3K-pack output
// ---------------------------------------------------------------------------
__global__ __launch_bounds__(64)
void ln_kernel(float* __restrict__ dst, const float* __restrict__ a,
               const float* __restrict__ b, const float* __restrict__ c,
               const float* __restrict__ g, const float* __restrict__ beta,
               ushort* __restrict__ out3)
{
    int row = blockIdx.x;
    int lane = threadIdx.x;
    size_t base = (size_t)row * DD;
    float x[8];
    #pragma unroll
    for (int j = 0; j < 2; ++j) {
        int e4 = j*64 + lane;
        float4 v = *(const float4*)(a + base + (size_t)e4*4);
        if (b) { float4 t = *(const float4*)(b + base + (size_t)e4*4); v.x+=t.x; v.y+=t.y; v.z+=t.z; v.w+=t.w; }
        if (c) { float4 t = *(const float4*)(c + base + (size_t)e4*4); v.x+=t.x; v.y+=t.y; v.z+=t.z; v.w+=t.w; }
        x[j*4+0]=v.x; x[j*4+1]=v.y; x[j*4+2]=v.z; x[j*4+3]=v.w;
    }
    float s = 0.f;
    #pragma unroll
    for (int i = 0; i < 8; ++i) s += x[i];
    #pragma unroll
    for (int m = 1; m < 64; m <<= 1) s += __shfl_xor(s, m);
    float mu = s * (1.f/DD);
    float vs = 0.f;
    #pragma unroll
    for (int i = 0; i < 8; ++i) { float dd = x[i]-mu; vs += dd*dd; }
    #pragma unroll
    for (int m = 1; m < 64; m <<= 1) vs += __shfl_xor(vs, m);
    float r = rsqrtf(vs*(1.f/DD) + 1e-5f);
    #pragma unroll
    for (int j = 0; j < 2; ++j) {
        int e4 = j*64 + lane;
        float4 gv = *(const float4*)(g    + (size_t)e4*4);
        float4 bv = *(const float4*)(beta + (size_t)e4*4);
        float4 o;
        o.x = (x[j*4+0]-mu)*r*gv.x + bv.x;
        o.y = (x[j*4+1]-mu)*r*gv.y + bv.y;
        o.z = (x[j*4+2]-mu)*r*gv.z + bv.z;
        o.w = (x[j*4+3]-mu)*r*gv.w + bv.w;
        *(float4*)(dst + base + (size_t)e4*4) = o;
        if (out3) {
            ushort* ob = out3 + (size_t)row*1536;
            pack_act(ob, e4*4+0, 512, o.x);
            pack_act(ob, e4*4+1, 512, o.y);
            pack_act(ob, e4*4+2, 512, o.z);
            pack_act(ob, e4*4+3, 512, o.w);
        }
    }
}

// ---------------------------------------------------------------------------
// projection + transpose + de-norm
// ---------------------------------------------------------------------------
__global__ __launch_bounds__(128)
void proj_kernel(const float* __restrict__ hf, const float* __restrict__ pw,
                 const float* __restrict__ pb, const float* __restrict__ mean,
                 const float* __restrict__ stdv, float* __restrict__ out)
{
    int b  = blockIdx.x >> 5;
    int n0 = (blockIdx.x & 31) << 3;
    __shared__ float rows[8][DD];
    for (int i = threadIdx.x; i < 8*128; i += 128) {
        int rj = i >> 7, c4 = i & 127;
        ((float4*)rows[rj])[c4] =
            *(const float4*)(hf + ((size_t)b*TT + n0 + rj)*DD + (size_t)c4*4);
    }
    __syncthreads();
    int p = threadIdx.x;
    if (p < PRED) {
        float acc[8];
        #pragma unroll
        for (int j = 0; j < 8; ++j) acc[j] = 0.f;
        for (int k4 = 0; k4 < 128; ++k4) {
            float4 w = *(const float4*)(pw + (size_t)p*DD + (size_t)k4*4);
            #pragma unroll
            for (int j = 0; j < 8; ++j) {
                float4 rv = ((const float4*)rows[j])[k4];
                acc[j] += w.x*rv.x + w.y*rv.y + w.z*rv.z + w.w*rv.w;
            }
        }
        float bias = pb[p];
        #pragma unroll
        for (int j = 0; j < 8; ++j) {
            int n = n0 + j;
            out[((size_t)b*PRED + p)*NV + n] =
                (acc[j] + bias)*stdv[b*NV + n] + mean[b*NV + n];
        }
    }
}

// ---------------------------------------------------------------------------
extern "C" void kernel_launch(void* const* d_in, const int* in_sizes, int n_in,
                              void* d_out, int out_size, void* d_ws, size_t ws_size,
                              hipStream_t stream)
{
    (void)in_sizes; (void)n_in; (void)out_size; (void)ws_size;
    const float* x_enc   = (const float*)d_in[0];
    const float* x_mark  = (const float*)d_in[1];
    const float* emb_w   = (const float*)d_in[2];
    const float* emb_b   = (const float*)d_in[3];
    const float* m_win   = (const float*)d_in[4];
    const float* m_convw = (const float*)d_in[5];
    const float* m_convb = (const float*)d_in[6];
    const float* m_wx    = (const float*)d_in[7];
    const float* m_wdt   = (const float*)d_in[8];
    const float* m_bdt   = (const float*)d_in[9];
    const float* m_alog  = (const float*)d_in[10];
    const float* m_dpar  = (const float*)d_in[11];
    const float* m_wout  = (const float*)d_in[12];
    const float* ln1_g   = (const float*)d_in[13];
    const float* ln1_b   = (const float*)d_in[14];
    const float* ff1_w   = (const float*)d_in[15];
    const float* ff1_b   = (const float*)d_in[16];
    const float* ff2_w   = (const float*)d_in[17];
    const float* ff2_b   = (const float*)d_in[18];
    const float* ln2_g   = (const float*)d_in[19];
    const float* ln2_b   = (const float*)d_in[20];
    const float* lnf_g   = (const float*)d_in[21];
    const float* lnf_b   = (const float*)d_in[22];
    const float* proj_w  = (const float*)d_in[23];
    const float* proj_b  = (const float*)d_in[24];
    float* out = (float*)d_out;

    float* ws = (float*)d_ws;
    const size_t NBT = (size_t)MROWS;
    size_t off = 0;
    float* mean = ws + off; off += 8192;
    float* stdv = ws + off; off += 8192;
    ushort* w_emb3  = (ushort*)(ws + off); off += 393216;    // 512*1536 bf16
    ushort* w_win3  = (ushort*)(ws + off); off += 3145728;   // 4096*1536
    ushort* w_wout3 = (ushort*)(ws + off); off += 1572864;   // 2048*1536
    ushort* w_ff13  = (ushort*)(ws + off); off += 786432;    // 1024*1536
    ushort* w_ff23  = (ushort*)(ws + off); off += 786432;    // 1024*1536
    ushort* w_comb3 = (ushort*)(ws + off); off += 1671168;   // 4*544*1536
    ushort* tok3 = (ushort*)(ws + off); off += NBT*768;      // aliased: xc3, y3
    ushort* xc3 = tok3;
    ushort* y3  = tok3;
    float* h   = ws + off; off += NBT*DD;
    ushort* h3 = (ushort*)(ws + off); off += NBT*768;
    float* xz  = ws + off; off += NBT*2*DD;
    ushort* fft3 = (ushort*)xz;                              // alias (xz dead at ffn time)
    float* xc  = ws + off; off += NBT*DD;
    float* bc  = ws + off; off += NBT*32;
    float* sp  = ws + off; off += NBT*DD;
    float* fbuf = ws + off; off += NBT*DD;
    float* rbuf = ws + off; off += NBT*DD;

    // ---- weight packing (every call; deterministic) ----
    pack3w<<<dim3((512*512+255)/256),  256, 0, stream>>>(emb_w, w_emb3, 512*512);
    pack3w<<<dim3((4096*512+255)/256), 256, 0, stream>>>(m_win, w_win3, 4096*512);
    pack3w<<<dim3((2048*512+255)/256), 256, 0, stream>>>(m_wout, w_wout3, 2048*512);
    pack3w<<<dim3((1024*512+255)/256), 256, 0, stream>>>(ff1_w, w_ff13, 1024*512);
    pack3w<<<dim3((1024*512+255)/256), 256, 0, stream>>>(ff2_w, w_ff23, 1024*512);
    mkcomb<<<dim3(544,4), 256, 0, stream>>>(m_wx, m_wdt, w_comb3);

    stats_kernel<<<dim3(BB*4), 256, 0, stream>>>(x_enc, mean, stdv);
    tok_kernel<<<dim3(BB*40), 256, 0, stream>>>(x_enc, x_mark, mean, stdv, tok3);

    // h = tok @ emb_w.T + emb_b   (fp32 h + packed h3)
    gemm3<1,0,1,1,0><<<dim3(66,4), 256, 0, stream>>>(tok3, 1536, w_emb3, 1536,
        emb_b, h, DD, h3, DD, nullptr, MROWS, 512, 1536);

    for (int l = 0; l < 2; ++l) {
        for (int dir = 0; dir < 2; ++dir) {
            int li = l*2 + dir;
            gemm3<0,0,1,0,0><<<dim3(66,8), 256, 0, stream>>>(h3, 1536,
                w_win3 + (size_t)li*1024*1536, 1536, nullptr,
                xz, 2*DD, nullptr, 0, nullptr, MROWS, 1024, 1536);
            conv_silu<<<dim3((MROWS*DD)/256), 256, 0, stream>>>(
                xz, m_convw + (size_t)li*DD*2, m_convb + (size_t)li*DD,
                xc, xc3, dir);
            gemm3<0,0,0,0,1><<<dim3(66,5), 256, 0, stream>>>(xc3, 1536,
                w_comb3 + (size_t)li*544*1536, 1536, m_bdt + (size_t)li*DD,
                sp, 512, nullptr, 0, bc, MROWS, 544, 1536);
            scan5<<<dim3(BB*4), 128, 0, stream>>>(sp, xc, xz, bc,
                m_alog + (size_t)li*DD*SS, m_dpar + (size_t)li*DD, y3, dir);
            gemm3<0,0,1,0,0><<<dim3(66,4), 256, 0, stream>>>(y3, 1536,
                w_wout3 + (size_t)li*512*1536, 1536, nullptr,
                (dir == 0) ? fbuf : rbuf, DD, nullptr, 0, nullptr,
                MROWS, 512, 1536);
        }
        ln_kernel<<<dim3(MROWS), 64, 0, stream>>>(h, h, fbuf, rbuf,
            ln1_g + l*DD, ln1_b + l*DD, h3);
        gemm3<1,1,0,1,0><<<dim3(66,4), 256, 0, stream>>>(h3, 1536,
            w_ff13 + (size_t)l*512*1536, 1536, ff1_b + l*DD,
            nullptr, 0, fft3, DD, nullptr, MROWS, 512, 1536);
        gemm3<1,0,1,0,0><<<dim3(66,4), 256, 0, stream>>>(fft3, 1536,
            w_ff23 + (size_t)l*512*1536, 1536, ff2_b + l*DD,
            xc, DD, nullptr, 0, nullptr, MROWS, 512, 1536);
        ln_kernel<<<dim3(MROWS), 64, 0, stream>>>(h, h, xc, nullptr,
            ln2_g + l*DD, ln2_b + l*DD, h3);
    }
    ln_kernel<<<dim3(MROWS), 64, 0, stream>>>(fbuf, h, nullptr, nullptr,
                                              lnf_g, lnf_b, nullptr);
    proj_kernel<<<dim3(BB*32), 128, 0, stream>>>(fbuf, proj_w, proj_b, mean, stdv, out);
}

// Round 13
// 1244.347 us; speedup vs baseline: 1.1289x; 1.1289x over previous
//
#include <hip/hip_runtime.h>
#include <hip/hip_bf16.h>
#include <math.h>
#include <stddef.h>

#define BB 32
#define TT 262
#define DD 512
#define SS 16
#define RR 32
#define SEQ 512
#define NV 256
#define PRED 96
#define MROWS (BB*TT)   // 8384

typedef __attribute__((ext_vector_type(4))) float f32x4;
typedef __attribute__((ext_vector_type(8))) short s16x8;

// ---------------- bf16 helpers ----------------
__device__ inline ushort f2bu(float x) {
    __hip_bfloat16 h = __float2bfloat16(x);
    ushort u; __builtin_memcpy(&u, &h, 2); return u;
}
__device__ inline float bu2f(ushort u) {
    __hip_bfloat16 h; __builtin_memcpy(&h, &u, 2);
    return __bfloat162float(h);
}
// activation 3K pack: [hi | lo | hi]
__device__ inline void pack_act(ushort* base, int col, int Kd, float v) {
    ushort hu = f2bu(v);
    float hf = bu2f(hu);
    ushort lu = f2bu(v - hf);
    base[col] = hu; base[Kd + col] = lu; base[2*Kd + col] = hu;
}

// async global->LDS, 16B per lane
__device__ inline void gload_lds16(const void* g, void* l) {
    __builtin_amdgcn_global_load_lds(
        (const __attribute__((address_space(1))) void*)g,
        (__attribute__((address_space(3))) void*)l, 16, 0, 0);
}

// ---------------------------------------------------------------------------
// weight 3K pack: [hi | hi | lo], K=512 rows
// ---------------------------------------------------------------------------
__global__ __launch_bounds__(256)
void pack3w(const float* __restrict__ in, ushort* __restrict__ out, int total)
{
    int idx = blockIdx.x * 256 + threadIdx.x;
    if (idx >= total) return;
    int r = idx >> 9, k = idx & 511;
    float x = in[idx];
    ushort hu = f2bu(x);
    float hf = bu2f(hu);
    ushort lu = f2bu(x - hf);
    size_t b = (size_t)r * 1536;
    out[b + k] = hu; out[b + 512 + k] = hu; out[b + 1024 + k] = lu;
}

// ---------------------------------------------------------------------------
// combined scan-projection weight (dt path folded through wdt)
// ---------------------------------------------------------------------------
__global__ __launch_bounds__(256)
void mkcomb(const float* __restrict__ wx, const float* __restrict__ wdt,
            ushort* __restrict__ comb3)
{
    int n  = blockIdx.x;
    int li = blockIdx.y;
    const float* wxl = wx + (size_t)li*64*512;
    ushort* outb = comb3 + ((size_t)li*544 + n)*1536;
    if (n < 512) {
        __shared__ float wr[32];
        if (threadIdx.x < 32)
            wr[threadIdx.x] = wdt[(size_t)li*512*32 + (size_t)n*32 + threadIdx.x];
        __syncthreads();
        for (int kk = threadIdx.x; kk < 512; kk += 256) {
            float acc = 0.f;
            #pragma unroll
            for (int r = 0; r < 32; ++r)
                acc = fmaf(wr[r], wxl[r*512 + kk], acc);
            ushort hu = f2bu(acc); float hf = bu2f(hu);
            ushort lu = f2bu(acc - hf);
            outb[kk] = hu; outb[512+kk] = hu; outb[1024+kk] = lu;
        }
    } else {
        int s = n - 512;
        for (int kk = threadIdx.x; kk < 512; kk += 256) {
            float v = wxl[(32+s)*512 + kk];
            ushort hu = f2bu(v); float hf = bu2f(hu);
            ushort lu = f2bu(v - hf);
            outb[kk] = hu; outb[512+kk] = hu; outb[1024+kk] = lu;
        }
    }
}

// ---------------------------------------------------------------------------
// per-(b,n) mean/std over SEQ
// ---------------------------------------------------------------------------
__global__ __launch_bounds__(256)
void stats_kernel(const float* __restrict__ x_enc,
                  float* __restrict__ mean, float* __restrict__ stdv)
{
    int b  = blockIdx.x >> 2;
    int n0 = (blockIdx.x & 3) << 6;
    int lane = threadIdx.x & 63;
    int w    = threadIdx.x >> 6;
    int n = n0 + lane;
    float s = 0.f, s2 = 0.f;
    for (int t = w; t < SEQ; t += 4) {
        float v = x_enc[((size_t)b*SEQ + t)*NV + n];
        s += v; s2 += v*v;
    }
    __shared__ float ls[4][64], ls2[4][64];
    ls[w][lane] = s; ls2[w][lane] = s2;
    __syncthreads();
    if (w == 0) {
        s  = ls[0][lane] + ls[1][lane] + ls[2][lane] + ls[3][lane];
        s2 = ls2[0][lane] + ls2[1][lane] + ls2[2][lane] + ls2[3][lane];
        float mu  = s * (1.f/SEQ);
        float var = s2 * (1.f/SEQ) - mu*mu;
        mean[b*NV + n] = mu;
        stdv[b*NV + n] = sqrtf(var + 1e-5f);
    }
}

// ---------------------------------------------------------------------------
// tok3: normalized transpose packed [hi|lo|hi] over K=512
// ---------------------------------------------------------------------------
__global__ __launch_bounds__(256)
void tok_kernel(const float* __restrict__ x_enc, const float* __restrict__ x_mark,
                const float* __restrict__ mean, const float* __restrict__ stdv,
                ushort* __restrict__ tok3)
{
    int b  = blockIdx.x / 40;
    int r  = blockIdx.x % 40;
    int tt = r / 5;
    int vt = r % 5;
    int t0 = tt << 6, v0 = vt << 6;
    __shared__ float tile[64][65];
    int lv = threadIdx.x & 63;
    for (int i = threadIdx.x >> 6; i < 64; i += 4) {
        int t = t0 + i, v = v0 + lv;
        float val = 0.f;
        if (v < NV) {
            val = (x_enc[((size_t)b*SEQ + t)*NV + v] - mean[b*NV + v]) / stdv[b*NV + v];
        } else if (v < TT) {
            val = x_mark[((size_t)b*SEQ + t)*6 + (v - NV)];
        }
        tile[i][lv] = val;
    }
    __syncthreads();
    for (int i = threadIdx.x >> 6; i < 64; i += 4) {
        int v = v0 + i;
        if (v < TT) {
            size_t row = (size_t)b*TT + v;
            pack_act(tok3 + row*1536, t0 + lv, 512, tile[lv][i]);
        }
    }
}

// ---------------------------------------------------------------------------
// bf16 MFMA GEMM over packed 3K operands (NT; K3 multiple of 64).
// 1D grid, bijective XCD-aware swizzle (8 XCDs): each XCD gets a contiguous
// chunk of m-major tile ids -> shared W-panel stays in its private L2.
// ---------------------------------------------------------------------------
template<int HAS_BIAS, int RELU, int WF32, int W3, int SCANEP>
__global__ __launch_bounds__(256)
void gemm3(const ushort* __restrict__ A3, int lda3,
           const ushort* __restrict__ W3p, int ldw3,
           const float* __restrict__ bias,
           float* __restrict__ C, int ldc,
           ushort* __restrict__ C3, int N_out,
           float* __restrict__ bcbuf,
           int M, int Nn, int K3)
{
    __shared__ ushort lds[2][2][128*64];   // [buf][A=0/W=1] : 64 KB
    const int tid  = threadIdx.x;
    const int lane = tid & 63;
    const int wid  = tid >> 6;
    const int wr = wid >> 1, wc = wid & 1;

    // bijective XCD swizzle (m204): nwg = gridDim.x
    int nwg = gridDim.x;
    int q8 = nwg >> 3, r8 = nwg & 7;
    int xcd = blockIdx.x & 7;
    int idx = blockIdx.x >> 3;
    int swz = (xcd < r8 ? xcd*(q8+1) : r8*(q8+1) + (xcd-r8)*q8) + idx;
    const int m0 = (swz % 66) * 128;
    const int n0 = (swz / 66) * 128;

    const int l8 = lane >> 3;
    const int sl = lane & 7;
    const int ssl = sl ^ l8;

    int arow[4], wrow[4];
    #pragma unroll
    for (int qq = 0; qq < 4; ++qq) {
        int r = (wid*4 + qq)*8 + l8;
        int ar = m0 + r; if (ar > M-1) ar = M-1;
        arow[qq] = ar;
        int wrr = n0 + r; if (wrr > Nn-1) wrr = Nn-1;
        wrow[qq] = wrr;
    }

    f32x4 acc[4][4];
    #pragma unroll
    for (int i = 0; i < 4; ++i)
        #pragma unroll
        for (int j = 0; j < 4; ++j) acc[i][j] = (f32x4){0.f,0.f,0.f,0.f};

    const int nk = K3 >> 6;
    const int rl = lane & 15;
    const int kq = lane >> 4;

    auto stage = [&](int buf_, int kt_) {
        #pragma unroll
        for (int qq = 0; qq < 4; ++qq) {
            int c = wid*4 + qq;
            gload_lds16(A3 + (size_t)arow[qq]*lda3 + kt_*64 + ssl*8,
                        (void*)&lds[buf_][0][c*512]);
            gload_lds16(W3p + (size_t)wrow[qq]*ldw3 + kt_*64 + ssl*8,
                        (void*)&lds[buf_][1][c*512]);
        }
    };

    stage(0, 0);
    __syncthreads();

    for (int kt = 0; kt < nk; ++kt) {
        int cur = kt & 1;
        if (kt + 1 < nk) stage(cur ^ 1, kt + 1);
        #pragma unroll
        for (int kk = 0; kk < 2; ++kk) {
            s16x8 av[4], wv[4];
            #pragma unroll
            for (int mi = 0; mi < 4; ++mi) {
                int row = wr*64 + mi*16 + rl;
                int ck = (kk*4 + kq) ^ (row & 7);
                av[mi] = *(const s16x8*)&lds[cur][0][row*64 + (ck<<3)];
            }
            #pragma unroll
            for (int ni = 0; ni < 4; ++ni) {
                int row = wc*64 + ni*16 + rl;
                int ck = (kk*4 + kq) ^ (row & 7);
                wv[ni] = *(const s16x8*)&lds[cur][1][row*64 + (ck<<3)];
            }
            #pragma unroll
            for (int mi = 0; mi < 4; ++mi)
                #pragma unroll
                for (int ni = 0; ni < 4; ++ni)
                    acc[mi][ni] = __builtin_amdgcn_mfma_f32_16x16x32_bf16(
                        av[mi], wv[ni], acc[mi][ni], 0, 0, 0);
        }
        __syncthreads();
    }

    #pragma unroll
    for (int ni = 0; ni < 4; ++ni) {
        int n = n0 + wc*64 + ni*16 + rl;
        if (n >= Nn) continue;
        float bv = (HAS_BIAS && !SCANEP) ? bias[n] : 0.f;
        #pragma unroll
        for (int mi = 0; mi < 4; ++mi) {
            #pragma unroll
            for (int j = 0; j < 4; ++j) {
                int m = m0 + wr*64 + mi*16 + kq*4 + j;
                if (m >= M) continue;
                float v = acc[mi][ni][j];
                if (SCANEP) {
                    if (n < 512) {
                        v += bias[n];
                        v = fmaxf(v, 0.f) + log1pf(__expf(-fabsf(v)));
                        C[(size_t)m*ldc + n] = v;
                    } else {
                        bcbuf[(size_t)m*32 + (n - 512)] = v;
                    }
                } else {
                    if (HAS_BIAS) v += bv;
                    if (RELU) v = fmaxf(v, 0.f);
                    if (WF32) C[(size_t)m*ldc + n] = v;
                    if (W3)   pack_act(C3 + (size_t)m*(3*N_out), n, N_out, v);
                }
            }
        }
    }
}

// ---------------------------------------------------------------------------
// conv + SiLU (fp32 xc + packed xc3), in-place silu on z-half of xz
// ---------------------------------------------------------------------------
__global__ __launch_bounds__(256)
void conv_silu(float* __restrict__ xz, const float* __restrict__ cw,
               const float* __restrict__ cb, float* __restrict__ xc,
               ushort* __restrict__ xc3, int rev)
{
    int idx = blockIdx.x * 256 + threadIdx.x;
    int d  = idx & (DD-1);
    int bt = idx >> 9;
    int t  = bt % TT;
    float cur = xz[(size_t)bt*2*DD + d];
    int tn = rev ? t + 1 : t - 1;
    float prev = 0.f;
    if (tn >= 0 && tn < TT)
        prev = xz[((size_t)bt + (rev ? 1 : -1))*2*DD + d];
    float v = prev*cw[d*2] + cur*cw[d*2+1] + cb[d];
    float sv = v / (1.f + __expf(-v));
    xc[idx] = sv;
    pack_act(xc3 + (size_t)bt*1536, d, 512, sv);
    float z = xz[(size_t)bt*2*DD + DD + d];
    xz[(size_t)bt*2*DD + DD + d] = z / (1.f + __expf(-z));
}

// ---------------------------------------------------------------------------
// Scan V3 (known-good): LDS-chunked, block=(b, 64 d), 256 thr = 64d x 4sg.
// ---------------------------------------------------------------------------
#define CH 32
__global__ __launch_bounds__(256)
void scan2(const float* __restrict__ sp_g, const float* __restrict__ xc_g,
           const float* __restrict__ xz_g, const float* __restrict__ bc_g,
           const float* __restrict__ alog, const float* __restrict__ dparam,
           ushort* __restrict__ y3, int rev)
{
    int b  = blockIdx.x >> 3;
    int d0 = (blockIdx.x & 7) << 6;
    int tid = threadIdx.x;
    int sg = tid & 3;
    int dl = tid >> 2;
    int d  = d0 + dl;

    __shared__ float t_sp[CH][68], t_xc[CH][68], t_zs[CH][68], t_bc[CH][36];

    float Ac[4];
    #pragma unroll
    for (int j = 0; j < 4; ++j)
        Ac[j] = -__expf(alog[d*SS + sg*4 + j]);
    float dp = dparam[d];
    float h0=0.f, h1=0.f, h2=0.f, h3=0.f;
    size_t bbase = (size_t)b*TT;

    int r_a = tid >> 4, c_a = (tid & 15) << 2;
    int r_a2 = (tid + 256) >> 4, c_a2 = ((tid + 256) & 15) << 2;
    int r_b = tid >> 3, c_b = (tid & 7) << 2;

#define GROW(tg_) (rev ? (TT-1-(tg_)) : (tg_))
#define LOADCH(c_, s0,s1, x0,x1, z0,z1, bc0) { \
        int tgA = (c_)*CH + r_a;  if (tgA > TT-1) tgA = TT-1; \
        int tgB = (c_)*CH + r_a2; if (tgB > TT-1) tgB = TT-1; \
        int tgC = (c_)*CH + r_b;  if (tgC > TT-1) tgC = TT-1; \
        size_t pA = bbase + GROW(tgA), pB = bbase + GROW(tgB), pC = bbase + GROW(tgC); \
        s0 = *(const float4*)(sp_g + pA*DD + d0 + c_a); \
        s1 = *(const float4*)(sp_g + pB*DD + d0 + c_a2); \
        x0 = *(const float4*)(xc_g + pA*DD + d0 + c_a); \
        x1 = *(const float4*)(xc_g + pB*DD + d0 + c_a2); \
        z0 = *(const float4*)(xz_g + pA*2*DD + DD + d0 + c_a); \
        z1 = *(const float4*)(xz_g + pB*2*DD + DD + d0 + c_a2); \
        bc0 = *(const float4*)(bc_g + pC*32 + c_b); }

    float4 s0,s1,x0,x1,z0,z1,bc0;
    LOADCH(0, s0,s1,x0,x1,z0,z1,bc0);

    const int nch = (TT + CH - 1) / CH;
    for (int c = 0; c < nch; ++c) {
        __syncthreads();
        *(float4*)&t_sp[r_a ][c_a ] = s0;
        *(float4*)&t_sp[r_a2][c_a2] = s1;
        *(float4*)&t_xc[r_a ][c_a ] = x0;
        *(float4*)&t_xc[r_a2][c_a2] = x1;
        *(float4*)&t_zs[r_a ][c_a ] = z0;
        *(float4*)&t_zs[r_a2][c_a2] = z1;
        *(float4*)&t_bc[r_b ][c_b ] = bc0;
        if (c + 1 < nch)
            LOADCH(c+1, s0,s1,x0,x1,z0,z1,bc0);
        __syncthreads();

        int tbase = c*CH;
        #pragma unroll 4
        for (int i = 0; i < CH; ++i) {
            float spv = t_sp[i][dl];
            float xcv = t_xc[i][dl];
            float4 Bv = *(const float4*)&t_bc[i][sg*4];
            float4 Cv = *(const float4*)&t_bc[i][16 + sg*4];
            float dtxc = spv * xcv;
            float e0 = __expf(spv*Ac[0]);
            float e1 = __expf(spv*Ac[1]);
            float e2 = __expf(spv*Ac[2]);
            float e3 = __expf(spv*Ac[3]);
            h0 = fmaf(e0, h0, dtxc*Bv.x);
            h1 = fmaf(e1, h1, dtxc*Bv.y);
            h2 = fmaf(e2, h2, dtxc*Bv.z);
            h3 = fmaf(e3, h3, dtxc*Bv.w);
            float dot = h0*Cv.x + h1*Cv.y + h2*Cv.z + h3*Cv.w;
            dot += __shfl_xor(dot, 1);
            dot += __shfl_xor(dot, 2);
            int t = tbase + i;
            if (sg == 0 && t < TT) {
                int tg = GROW(t);
                float yv = (dot + dp*xcv) * t_zs[i][dl];
                pack_act(y3 + (bbase + tg)*1536, d, 512, yv);
            }
        }
    }
#undef LOADCH
#undef GROW
}

// ---------------------------------------------------------------------------
// LayerNorm (up to 3 summed inputs), optional 3K-pack output
// ---------------------------------------------------------------------------
__global__ __launch_bounds__(64)
void ln_kernel(float* __restrict__ dst, const float* __restrict__ a,
               const float* __restrict__ b, const float* __restrict__ c,
               const float* __restrict__ g, const float* __restrict__ beta,
               ushort* __restrict__ out3)
{
    int row = blockIdx.x;
    int lane = threadIdx.x;
    size_t base = (size_t)row * DD;
    float x[8];
    #pragma unroll
    for (int j = 0; j < 2; ++j) {
        int e4 = j*64 + lane;
        float4 v = *(const float4*)(a + base + (size_t)e4*4);
        if (b) { float4 t = *(const float4*)(b + base + (size_t)e4*4); v.x+=t.x; v.y+=t.y; v.z+=t.z; v.w+=t.w; }
        if (c) { float4 t = *(const float4*)(c + base + (size_t)e4*4); v.x+=t.x; v.y+=t.y; v.z+=t.z; v.w+=t.w; }
        x[j*4+0]=v.x; x[j*4+1]=v.y; x[j*4+2]=v.z; x[j*4+3]=v.w;
    }
    float s = 0.f;
    #pragma unroll
    for (int i = 0; i < 8; ++i) s += x[i];
    #pragma unroll
    for (int m = 1; m < 64; m <<= 1) s += __shfl_xor(s, m);
    float mu = s * (1.f/DD);
    float vs = 0.f;
    #pragma unroll
    for (int i = 0; i < 8; ++i) { float dd = x[i]-mu; vs += dd*dd; }
    #pragma unroll
    for (int m = 1; m < 64; m <<= 1) vs += __shfl_xor(vs, m);
    float r = rsqrtf(vs*(1.f/DD) + 1e-5f);
    #pragma unroll
    for (int j = 0; j < 2; ++j) {
        int e4 = j*64 + lane;
        float4 gv = *(const float4*)(g    + (size_t)e4*4);
        float4 bv = *(const float4*)(beta + (size_t)e4*4);
        float4 o;
        o.x = (x[j*4+0]-mu)*r*gv.x + bv.x;
        o.y = (x[j*4+1]-mu)*r*gv.y + bv.y;
        o.z = (x[j*4+2]-mu)*r*gv.z + bv.z;
        o.w = (x[j*4+3]-mu)*r*gv.w + bv.w;
        *(float4*)(dst + base + (size_t)e4*4) = o;
        if (out3) {
            ushort* ob = out3 + (size_t)row*1536;
            pack_act(ob, e4*4+0, 512, o.x);
            pack_act(ob, e4*4+1, 512, o.y);
            pack_act(ob, e4*4+2, 512, o.z);
            pack_act(ob, e4*4+3, 512, o.w);
        }
    }
}

// ---------------------------------------------------------------------------
// projection + transpose + de-norm
// ---------------------------------------------------------------------------
__global__ __launch_bounds__(128)
void proj_kernel(const float* __restrict__ hf, const float* __restrict__ pw,
                 const float* __restrict__ pb, const float* __restrict__ mean,
                 const float* __restrict__ stdv, float* __restrict__ out)
{
    int b  = blockIdx.x >> 5;
    int n0 = (blockIdx.x & 31) << 3;
    __shared__ float rows[8][DD];
    for (int i = threadIdx.x; i < 8*128; i += 128) {
        int rj = i >> 7, c4 = i & 127;
        ((float4*)rows[rj])[c4] =
            *(const float4*)(hf + ((size_t)b*TT + n0 + rj)*DD + (size_t)c4*4);
    }
    __syncthreads();
    int p = threadIdx.x;
    if (p < PRED) {
        float acc[8];
        #pragma unroll
        for (int j = 0; j < 8; ++j) acc[j] = 0.f;
        for (int k4 = 0; k4 < 128; ++k4) {
            float4 w = *(const float4*)(pw + (size_t)p*DD + (size_t)k4*4);
            #pragma unroll
            for (int j = 0; j < 8; ++j) {
                float4 rv = ((const float4*)rows[j])[k4];
                acc[j] += w.x*rv.x + w.y*rv.y + w.z*rv.z + w.w*rv.w;
            }
        }
        float bias = pb[p];
        #pragma unroll
        for (int j = 0; j < 8; ++j) {
            int n = n0 + j;
            out[((size_t)b*PRED + p)*NV + n] =
                (acc[j] + bias)*stdv[b*NV + n] + mean[b*NV + n];
        }
    }
}

// ---------------------------------------------------------------------------
extern "C" void kernel_launch(void* const* d_in, const int* in_sizes, int n_in,
                              void* d_out, int out_size, void* d_ws, size_t ws_size,
                              hipStream_t stream)
{
    (void)in_sizes; (void)n_in; (void)out_size; (void)ws_size;
    const float* x_enc   = (const float*)d_in[0];
    const float* x_mark  = (const float*)d_in[1];
    const float* emb_w   = (const float*)d_in[2];
    const float* emb_b   = (const float*)d_in[3];
    const float* m_win   = (const float*)d_in[4];
    const float* m_convw = (const float*)d_in[5];
    const float* m_convb = (const float*)d_in[6];
    const float* m_wx    = (const float*)d_in[7];
    const float* m_wdt   = (const float*)d_in[8];
    const float* m_bdt   = (const float*)d_in[9];
    const float* m_alog  = (const float*)d_in[10];
    const float* m_dpar  = (const float*)d_in[11];
    const float* m_wout  = (const float*)d_in[12];
    const float* ln1_g   = (const float*)d_in[13];
    const float* ln1_b   = (const float*)d_in[14];
    const float* ff1_w   = (const float*)d_in[15];
    const float* ff1_b   = (const float*)d_in[16];
    const float* ff2_w   = (const float*)d_in[17];
    const float* ff2_b   = (const float*)d_in[18];
    const float* ln2_g   = (const float*)d_in[19];
    const float* ln2_b   = (const float*)d_in[20];
    const float* lnf_g   = (const float*)d_in[21];
    const float* lnf_b   = (const float*)d_in[22];
    const float* proj_w  = (const float*)d_in[23];
    const float* proj_b  = (const float*)d_in[24];
    float* out = (float*)d_out;

    float* ws = (float*)d_ws;
    const size_t NBT = (size_t)MROWS;
    size_t off = 0;
    float* mean = ws + off; off += 8192;
    float* stdv = ws + off; off += 8192;
    ushort* w_emb3  = (ushort*)(ws + off); off += 393216;    // 512*1536 bf16
    ushort* w_win3  = (ushort*)(ws + off); off += 3145728;   // 4096*1536
    ushort* w_wout3 = (ushort*)(ws + off); off += 1572864;   // 2048*1536
    ushort* w_ff13  = (ushort*)(ws + off); off += 786432;    // 1024*1536
    ushort* w_ff23  = (ushort*)(ws + off); off += 786432;    // 1024*1536
    ushort* w_comb3 = (ushort*)(ws + off); off += 1671168;   // 4*544*1536
    ushort* tok3 = (ushort*)(ws + off); off += NBT*768;      // aliased: xc3, y3
    ushort* xc3 = tok3;
    ushort* y3  = tok3;
    float* h   = ws + off; off += NBT*DD;
    ushort* h3 = (ushort*)(ws + off); off += NBT*768;
    float* xz  = ws + off; off += NBT*2*DD;
    ushort* fft3 = (ushort*)xz;                              // alias (xz dead at ffn time)
    float* xc  = ws + off; off += NBT*DD;
    float* bc  = ws + off; off += NBT*32;
    float* sp  = ws + off; off += NBT*DD;
    float* fbuf = ws + off; off += NBT*DD;
    float* rbuf = ws + off; off += NBT*DD;

    // ---- weight packing (every call; deterministic) ----
    pack3w<<<dim3((512*512+255)/256),  256, 0, stream>>>(emb_w, w_emb3, 512*512);
    pack3w<<<dim3((4096*512+255)/256), 256, 0, stream>>>(m_win, w_win3, 4096*512);
    pack3w<<<dim3((2048*512+255)/256), 256, 0, stream>>>(m_wout, w_wout3, 2048*512);
    pack3w<<<dim3((1024*512+255)/256), 256, 0, stream>>>(ff1_w, w_ff13, 1024*512);
    pack3w<<<dim3((1024*512+255)/256), 256, 0, stream>>>(ff2_w, w_ff23, 1024*512);
    mkcomb<<<dim3(544,4), 256, 0, stream>>>(m_wx, m_wdt, w_comb3);

    stats_kernel<<<dim3(BB*4), 256, 0, stream>>>(x_enc, mean, stdv);
    tok_kernel<<<dim3(BB*40), 256, 0, stream>>>(x_enc, x_mark, mean, stdv, tok3);

    // h = tok @ emb_w.T + emb_b   (fp32 h + packed h3)
    gemm3<1,0,1,1,0><<<dim3(66*4), 256, 0, stream>>>(tok3, 1536, w_emb3, 1536,
        emb_b, h, DD, h3, DD, nullptr, MROWS, 512, 1536);

    for (int l = 0; l < 2; ++l) {
        for (int dir = 0; dir < 2; ++dir) {
            int li = l*2 + dir;
            gemm3<0,0,1,0,0><<<dim3(66*8), 256, 0, stream>>>(h3, 1536,
                w_win3 + (size_t)li*1024*1536, 1536, nullptr,
                xz, 2*DD, nullptr, 0, nullptr, MROWS, 1024, 1536);
            conv_silu<<<dim3((MROWS*DD)/256), 256, 0, stream>>>(
                xz, m_convw + (size_t)li*DD*2, m_convb + (size_t)li*DD,
                xc, xc3, dir);
            gemm3<0,0,0,0,1><<<dim3(66*5), 256, 0, stream>>>(xc3, 1536,
                w_comb3 + (size_t)li*544*1536, 1536, m_bdt + (size_t)li*DD,
                sp, 512, nullptr, 0, bc, MROWS, 544, 1536);
            scan2<<<dim3(BB*8), 256, 0, stream>>>(sp, xc, xz, bc,
                m_alog + (size_t)li*DD*SS, m_dpar + (size_t)li*DD, y3, dir);
            gemm3<0,0,1,0,0><<<dim3(66*4), 256, 0, stream>>>(y3, 1536,
                w_wout3 + (size_t)li*512*1536, 1536, nullptr,
                (dir == 0) ? fbuf : rbuf, DD, nullptr, 0, nullptr,
                MROWS, 512, 1536);
        }
        ln_kernel<<<dim3(MROWS), 64, 0, stream>>>(h, h, fbuf, rbuf,
            ln1_g + l*DD, ln1_b + l*DD, h3);
        gemm3<1,1,0,1,0><<<dim3(66*4), 256, 0, stream>>>(h3, 1536,
            w_ff13 + (size_t)l*512*1536, 1536, ff1_b + l*DD,
            nullptr, 0, fft3, DD, nullptr, MROWS, 512, 1536);
        gemm3<1,0,1,0,0><<<dim3(66*4), 256, 0, stream>>>(fft3, 1536,
            w_ff23 + (size_t)l*512*1536, 1536, ff2_b + l*DD,
            xc, DD, nullptr, 0, nullptr, MROWS, 512, 1536);
        ln_kernel<<<dim3(MROWS), 64, 0, stream>>>(h, h, xc, nullptr,
            ln2_g + l*DD, ln2_b + l*DD, h3);
    }
    ln_kernel<<<dim3(MROWS), 64, 0, stream>>>(fbuf, h, nullptr, nullptr,
                                              lnf_g, lnf_b, nullptr);
    proj_kernel<<<dim3(BB*32), 128, 0, stream>>>(fbuf, proj_w, proj_b, mean, stdv, out);
}

// Round 14
// 1100.743 us; speedup vs baseline: 1.2761x; 1.1305x over previous
//
#include <hip/hip_runtime.h>
#include <hip/hip_bf16.h>
#include <math.h>
#include <stddef.h>

#define BB 32
#define TT 262
#define DD 512
#define SS 16
#define RR 32
#define SEQ 512
#define NV 256
#define PRED 96
#define MROWS (BB*TT)   // 8384

typedef __attribute__((ext_vector_type(4))) float f32x4;
typedef __attribute__((ext_vector_type(8))) short s16x8;

// ---------------- bf16 helpers ----------------
__device__ inline ushort f2bu(float x) {
    __hip_bfloat16 h = __float2bfloat16(x);
    ushort u; __builtin_memcpy(&u, &h, 2); return u;
}
__device__ inline float bu2f(ushort u) {
    __hip_bfloat16 h; __builtin_memcpy(&h, &u, 2);
    return __bfloat162float(h);
}
// activation 2K pack: [hi | lo]
__device__ inline void pack_act(ushort* base, int col, int Kd, float v) {
    ushort hu = f2bu(v);
    float hf = bu2f(hu);
    ushort lu = f2bu(v - hf);
    base[col] = hu; base[Kd + col] = lu;
}

// async global->LDS, 16B per lane
__device__ inline void gload_lds16(const void* g, void* l) {
    __builtin_amdgcn_global_load_lds(
        (const __attribute__((address_space(1))) void*)g,
        (__attribute__((address_space(3))) void*)l, 16, 0, 0);
}

// ---------------------------------------------------------------------------
// weight 2K pack: [hi | hi], K=512 rows
// ---------------------------------------------------------------------------
__global__ __launch_bounds__(256)
void pack2w(const float* __restrict__ in, ushort* __restrict__ out, int total)
{
    int idx = blockIdx.x * 256 + threadIdx.x;
    if (idx >= total) return;
    int r = idx >> 9, k = idx & 511;
    float x = in[idx];
    ushort hu = f2bu(x);
    size_t b = (size_t)r * 1024;
    out[b + k] = hu; out[b + 512 + k] = hu;
}

// ---------------------------------------------------------------------------
// combined scan-projection weight (dt path folded through wdt), [hi|hi]
// ---------------------------------------------------------------------------
__global__ __launch_bounds__(256)
void mkcomb(const float* __restrict__ wx, const float* __restrict__ wdt,
            ushort* __restrict__ comb2)
{
    int n  = blockIdx.x;
    int li = blockIdx.y;
    const float* wxl = wx + (size_t)li*64*512;
    ushort* outb = comb2 + ((size_t)li*544 + n)*1024;
    if (n < 512) {
        __shared__ float wr[32];
        if (threadIdx.x < 32)
            wr[threadIdx.x] = wdt[(size_t)li*512*32 + (size_t)n*32 + threadIdx.x];
        __syncthreads();
        for (int kk = threadIdx.x; kk < 512; kk += 256) {
            float acc = 0.f;
            #pragma unroll
            for (int r = 0; r < 32; ++r)
                acc = fmaf(wr[r], wxl[r*512 + kk], acc);
            ushort hu = f2bu(acc);
            outb[kk] = hu; outb[512+kk] = hu;
        }
    } else {
        int s = n - 512;
        for (int kk = threadIdx.x; kk < 512; kk += 256) {
            float v = wxl[(32+s)*512 + kk];
            ushort hu = f2bu(v);
            outb[kk] = hu; outb[512+kk] = hu;
        }
    }
}

// ---------------------------------------------------------------------------
// per-(b,n) mean/std over SEQ
// ---------------------------------------------------------------------------
__global__ __launch_bounds__(256)
void stats_kernel(const float* __restrict__ x_enc,
                  float* __restrict__ mean, float* __restrict__ stdv)
{
    int b  = blockIdx.x >> 2;
    int n0 = (blockIdx.x & 3) << 6;
    int lane = threadIdx.x & 63;
    int w    = threadIdx.x >> 6;
    int n = n0 + lane;
    float s = 0.f, s2 = 0.f;
    for (int t = w; t < SEQ; t += 4) {
        float v = x_enc[((size_t)b*SEQ + t)*NV + n];
        s += v; s2 += v*v;
    }
    __shared__ float ls[4][64], ls2[4][64];
    ls[w][lane] = s; ls2[w][lane] = s2;
    __syncthreads();
    if (w == 0) {
        s  = ls[0][lane] + ls[1][lane] + ls[2][lane] + ls[3][lane];
        s2 = ls2[0][lane] + ls2[1][lane] + ls2[2][lane] + ls2[3][lane];
        float mu  = s * (1.f/SEQ);
        float var = s2 * (1.f/SEQ) - mu*mu;
        mean[b*NV + n] = mu;
        stdv[b*NV + n] = sqrtf(var + 1e-5f);
    }
}

// ---------------------------------------------------------------------------
// tok2: normalized transpose packed [hi|lo] over K=512
// ---------------------------------------------------------------------------
__global__ __launch_bounds__(256)
void tok_kernel(const float* __restrict__ x_enc, const float* __restrict__ x_mark,
                const float* __restrict__ mean, const float* __restrict__ stdv,
                ushort* __restrict__ tok2)
{
    int b  = blockIdx.x / 40;
    int r  = blockIdx.x % 40;
    int tt = r / 5;
    int vt = r % 5;
    int t0 = tt << 6, v0 = vt << 6;
    __shared__ float tile[64][65];
    int lv = threadIdx.x & 63;
    for (int i = threadIdx.x >> 6; i < 64; i += 4) {
        int t = t0 + i, v = v0 + lv;
        float val = 0.f;
        if (v < NV) {
            val = (x_enc[((size_t)b*SEQ + t)*NV + v] - mean[b*NV + v]) / stdv[b*NV + v];
        } else if (v < TT) {
            val = x_mark[((size_t)b*SEQ + t)*6 + (v - NV)];
        }
        tile[i][lv] = val;
    }
    __syncthreads();
    for (int i = threadIdx.x >> 6; i < 64; i += 4) {
        int v = v0 + i;
        if (v < TT) {
            size_t row = (size_t)b*TT + v;
            pack_act(tok2 + row*1024, t0 + lv, 512, tile[lv][i]);
        }
    }
}

// ---------------------------------------------------------------------------
// bf16 MFMA GEMM over packed 2K operands (NT; K2 multiple of 64).
// 1D grid, bijective XCD-aware swizzle (8 XCDs).
// ---------------------------------------------------------------------------
template<int HAS_BIAS, int RELU, int WF32, int W3, int SCANEP>
__global__ __launch_bounds__(256)
void gemm3(const ushort* __restrict__ A3, int lda3,
           const ushort* __restrict__ W3p, int ldw3,
           const float* __restrict__ bias,
           float* __restrict__ C, int ldc,
           ushort* __restrict__ C3, int N_out,
           float* __restrict__ bcbuf,
           int M, int Nn, int K3)
{
    __shared__ ushort lds[2][2][128*64];   // [buf][A=0/W=1] : 64 KB
    const int tid  = threadIdx.x;
    const int lane = tid & 63;
    const int wid  = tid >> 6;
    const int wr = wid >> 1, wc = wid & 1;

    // bijective XCD swizzle (m204)
    int nwg = gridDim.x;
    int q8 = nwg >> 3, r8 = nwg & 7;
    int xcd = blockIdx.x & 7;
    int idx = blockIdx.x >> 3;
    int swz = (xcd < r8 ? xcd*(q8+1) : r8*(q8+1) + (xcd-r8)*q8) + idx;
    const int m0 = (swz % 66) * 128;
    const int n0 = (swz / 66) * 128;

    const int l8 = lane >> 3;
    const int sl = lane & 7;
    const int ssl = sl ^ l8;

    int arow[4], wrow[4];
    #pragma unroll
    for (int qq = 0; qq < 4; ++qq) {
        int r = (wid*4 + qq)*8 + l8;
        int ar = m0 + r; if (ar > M-1) ar = M-1;
        arow[qq] = ar;
        int wrr = n0 + r; if (wrr > Nn-1) wrr = Nn-1;
        wrow[qq] = wrr;
    }

    f32x4 acc[4][4];
    #pragma unroll
    for (int i = 0; i < 4; ++i)
        #pragma unroll
        for (int j = 0; j < 4; ++j) acc[i][j] = (f32x4){0.f,0.f,0.f,0.f};

    const int nk = K3 >> 6;
    const int rl = lane & 15;
    const int kq = lane >> 4;

    auto stage = [&](int buf_, int kt_) {
        #pragma unroll
        for (int qq = 0; qq < 4; ++qq) {
            int c = wid*4 + qq;
            gload_lds16(A3 + (size_t)arow[qq]*lda3 + kt_*64 + ssl*8,
                        (void*)&lds[buf_][0][c*512]);
            gload_lds16(W3p + (size_t)wrow[qq]*ldw3 + kt_*64 + ssl*8,
                        (void*)&lds[buf_][1][c*512]);
        }
    };

    stage(0, 0);
    __syncthreads();

    for (int kt = 0; kt < nk; ++kt) {
        int cur = kt & 1;
        if (kt + 1 < nk) stage(cur ^ 1, kt + 1);
        #pragma unroll
        for (int kk = 0; kk < 2; ++kk) {
            s16x8 av[4], wv[4];
            #pragma unroll
            for (int mi = 0; mi < 4; ++mi) {
                int row = wr*64 + mi*16 + rl;
                int ck = (kk*4 + kq) ^ (row & 7);
                av[mi] = *(const s16x8*)&lds[cur][0][row*64 + (ck<<3)];
            }
            #pragma unroll
            for (int ni = 0; ni < 4; ++ni) {
                int row = wc*64 + ni*16 + rl;
                int ck = (kk*4 + kq) ^ (row & 7);
                wv[ni] = *(const s16x8*)&lds[cur][1][row*64 + (ck<<3)];
            }
            #pragma unroll
            for (int mi = 0; mi < 4; ++mi)
                #pragma unroll
                for (int ni = 0; ni < 4; ++ni)
                    acc[mi][ni] = __builtin_amdgcn_mfma_f32_16x16x32_bf16(
                        av[mi], wv[ni], acc[mi][ni], 0, 0, 0);
        }
        __syncthreads();
    }

    #pragma unroll
    for (int ni = 0; ni < 4; ++ni) {
        int n = n0 + wc*64 + ni*16 + rl;
        if (n >= Nn) continue;
        float bv = (HAS_BIAS && !SCANEP) ? bias[n] : 0.f;
        #pragma unroll
        for (int mi = 0; mi < 4; ++mi) {
            #pragma unroll
            for (int j = 0; j < 4; ++j) {
                int m = m0 + wr*64 + mi*16 + kq*4 + j;
                if (m >= M) continue;
                float v = acc[mi][ni][j];
                if (SCANEP) {
                    if (n < 512) {
                        v += bias[n];
                        v = fmaxf(v, 0.f) + log1pf(__expf(-fabsf(v)));
                        C[(size_t)m*ldc + n] = v;
                    } else {
                        bcbuf[(size_t)m*32 + (n - 512)] = v;
                    }
                } else {
                    if (HAS_BIAS) v += bv;
                    if (RELU) v = fmaxf(v, 0.f);
                    if (WF32) C[(size_t)m*ldc + n] = v;
                    if (W3)   pack_act(C3 + (size_t)m*(2*N_out), n, N_out, v);
                }
            }
        }
    }
}

// ---------------------------------------------------------------------------
// conv + SiLU (fp32 xc + packed xc2), in-place silu on z-half of xz
// ---------------------------------------------------------------------------
__global__ __launch_bounds__(256)
void conv_silu(float* __restrict__ xz, const float* __restrict__ cw,
               const float* __restrict__ cb, float* __restrict__ xc,
               ushort* __restrict__ xc2, int rev)
{
    int idx = blockIdx.x * 256 + threadIdx.x;
    int d  = idx & (DD-1);
    int bt = idx >> 9;
    int t  = bt % TT;
    float cur = xz[(size_t)bt*2*DD + d];
    int tn = rev ? t + 1 : t - 1;
    float prev = 0.f;
    if (tn >= 0 && tn < TT)
        prev = xz[((size_t)bt + (rev ? 1 : -1))*2*DD + d];
    float v = prev*cw[d*2] + cur*cw[d*2+1] + cb[d];
    float sv = v / (1.f + __expf(-v));
    xc[idx] = sv;
    pack_act(xc2 + (size_t)bt*1024, d, 512, sv);
    float z = xz[(size_t)bt*2*DD + DD + d];
    xz[(size_t)bt*2*DD + DD + d] = z / (1.f + __expf(-z));
}

// ---------------------------------------------------------------------------
// Scan V3 (known-good): LDS-chunked, block=(b, 64 d), 256 thr = 64d x 4sg.
// ---------------------------------------------------------------------------
#define CH 32
__global__ __launch_bounds__(256)
void scan2(const float* __restrict__ sp_g, const float* __restrict__ xc_g,
           const float* __restrict__ xz_g, const float* __restrict__ bc_g,
           const float* __restrict__ alog, const float* __restrict__ dparam,
           ushort* __restrict__ y2, int rev)
{
    int b  = blockIdx.x >> 3;
    int d0 = (blockIdx.x & 7) << 6;
    int tid = threadIdx.x;
    int sg = tid & 3;
    int dl = tid >> 2;
    int d  = d0 + dl;

    __shared__ float t_sp[CH][68], t_xc[CH][68], t_zs[CH][68], t_bc[CH][36];

    float Ac[4];
    #pragma unroll
    for (int j = 0; j < 4; ++j)
        Ac[j] = -__expf(alog[d*SS + sg*4 + j]);
    float dp = dparam[d];
    float h0=0.f, h1=0.f, h2=0.f, h3=0.f;
    size_t bbase = (size_t)b*TT;

    int r_a = tid >> 4, c_a = (tid & 15) << 2;
    int r_a2 = (tid + 256) >> 4, c_a2 = ((tid + 256) & 15) << 2;
    int r_b = tid >> 3, c_b = (tid & 7) << 2;

#define GROW(tg_) (rev ? (TT-1-(tg_)) : (tg_))
#define LOADCH(c_, s0,s1, x0,x1, z0,z1, bc0) { \
        int tgA = (c_)*CH + r_a;  if (tgA > TT-1) tgA = TT-1; \
        int tgB = (c_)*CH + r_a2; if (tgB > TT-1) tgB = TT-1; \
        int tgC = (c_)*CH + r_b;  if (tgC > TT-1) tgC = TT-1; \
        size_t pA = bbase + GROW(tgA), pB = bbase + GROW(tgB), pC = bbase + GROW(tgC); \
        s0 = *(const float4*)(sp_g + pA*DD + d0 + c_a); \
        s1 = *(const float4*)(sp_g + pB*DD + d0 + c_a2); \
        x0 = *(const float4*)(xc_g + pA*DD + d0 + c_a); \
        x1 = *(const float4*)(xc_g + pB*DD + d0 + c_a2); \
        z0 = *(const float4*)(xz_g + pA*2*DD + DD + d0 + c_a); \
        z1 = *(const float4*)(xz_g + pB*2*DD + DD + d0 + c_a2); \
        bc0 = *(const float4*)(bc_g + pC*32 + c_b); }

    float4 s0,s1,x0,x1,z0,z1,bc0;
    LOADCH(0, s0,s1,x0,x1,z0,z1,bc0);

    const int nch = (TT + CH - 1) / CH;
    for (int c = 0; c < nch; ++c) {
        __syncthreads();
        *(float4*)&t_sp[r_a ][c_a ] = s0;
        *(float4*)&t_sp[r_a2][c_a2] = s1;
        *(float4*)&t_xc[r_a ][c_a ] = x0;
        *(float4*)&t_xc[r_a2][c_a2] = x1;
        *(float4*)&t_zs[r_a ][c_a ] = z0;
        *(float4*)&t_zs[r_a2][c_a2] = z1;
        *(float4*)&t_bc[r_b ][c_b ] = bc0;
        if (c + 1 < nch)
            LOADCH(c+1, s0,s1,x0,x1,z0,z1,bc0);
        __syncthreads();

        int tbase = c*CH;
        #pragma unroll 4
        for (int i = 0; i < CH; ++i) {
            float spv = t_sp[i][dl];
            float xcv = t_xc[i][dl];
            float4 Bv = *(const float4*)&t_bc[i][sg*4];
            float4 Cv = *(const float4*)&t_bc[i][16 + sg*4];
            float dtxc = spv * xcv;
            float e0 = __expf(spv*Ac[0]);
            float e1 = __expf(spv*Ac[1]);
            float e2 = __expf(spv*Ac[2]);
            float e3 = __expf(spv*Ac[3]);
            h0 = fmaf(e0, h0, dtxc*Bv.x);
            h1 = fmaf(e1, h1, dtxc*Bv.y);
            h2 = fmaf(e2, h2, dtxc*Bv.z);
            h3 = fmaf(e3, h3, dtxc*Bv.w);
            float dot = h0*Cv.x + h1*Cv.y + h2*Cv.z + h3*Cv.w;
            dot += __shfl_xor(dot, 1);
            dot += __shfl_xor(dot, 2);
            int t = tbase + i;
            if (sg == 0 && t < TT) {
                int tg = GROW(t);
                float yv = (dot + dp*xcv) * t_zs[i][dl];
                pack_act(y2 + (bbase + tg)*1024, d, 512, yv);
            }
        }
    }
#undef LOADCH
#undef GROW
}

// ---------------------------------------------------------------------------
// LayerNorm (up to 3 summed inputs), optional 2K-pack output
// ---------------------------------------------------------------------------
__global__ __launch_bounds__(64)
void ln_kernel(float* __restrict__ dst, const float* __restrict__ a,
               const float* __restrict__ b, const float* __restrict__ c,
               const float* __restrict__ g, const float* __restrict__ beta,
               ushort* __restrict__ out2)
{
    int row = blockIdx.x;
    int lane = threadIdx.x;
    size_t base = (size_t)row * DD;
    float x[8];
    #pragma unroll
    for (int j = 0; j < 2; ++j) {
        int e4 = j*64 + lane;
        float4 v = *(const float4*)(a + base + (size_t)e4*4);
        if (b) { float4 t = *(const float4*)(b + base + (size_t)e4*4); v.x+=t.x; v.y+=t.y; v.z+=t.z; v.w+=t.w; }
        if (c) { float4 t = *(const float4*)(c + base + (size_t)e4*4); v.x+=t.x; v.y+=t.y; v.z+=t.z; v.w+=t.w; }
        x[j*4+0]=v.x; x[j*4+1]=v.y; x[j*4+2]=v.z; x[j*4+3]=v.w;
    }
    float s = 0.f;
    #pragma unroll
    for (int i = 0; i < 8; ++i) s += x[i];
    #pragma unroll
    for (int m = 1; m < 64; m <<= 1) s += __shfl_xor(s, m);
    float mu = s * (1.f/DD);
    float vs = 0.f;
    #pragma unroll
    for (int i = 0; i < 8; ++i) { float dd = x[i]-mu; vs += dd*dd; }
    #pragma unroll
    for (int m = 1; m < 64; m <<= 1) vs += __shfl_xor(vs, m);
    float r = rsqrtf(vs*(1.f/DD) + 1e-5f);
    #pragma unroll
    for (int j = 0; j < 2; ++j) {
        int e4 = j*64 + lane;
        float4 gv = *(const float4*)(g    + (size_t)e4*4);
        float4 bv = *(const float4*)(beta + (size_t)e4*4);
        float4 o;
        o.x = (x[j*4+0]-mu)*r*gv.x + bv.x;
        o.y = (x[j*4+1]-mu)*r*gv.y + bv.y;
        o.z = (x[j*4+2]-mu)*r*gv.z + bv.z;
        o.w = (x[j*4+3]-mu)*r*gv.w + bv.w;
        *(float4*)(dst + base + (size_t)e4*4) = o;
        if (out2) {
            ushort* ob = out2 + (size_t)row*1024;
            pack_act(ob, e4*4+0, 512, o.x);
            pack_act(ob, e4*4+1, 512, o.y);
            pack_act(ob, e4*4+2, 512, o.z);
            pack_act(ob, e4*4+3, 512, o.w);
        }
    }
}

// ---------------------------------------------------------------------------
// projection + transpose + de-norm
// ---------------------------------------------------------------------------
__global__ __launch_bounds__(128)
void proj_kernel(const float* __restrict__ hf, const float* __restrict__ pw,
                 const float* __restrict__ pb, const float* __restrict__ mean,
                 const float* __restrict__ stdv, float* __restrict__ out)
{
    int b  = blockIdx.x >> 5;
    int n0 = (blockIdx.x & 31) << 3;
    __shared__ float rows[8][DD];
    for (int i = threadIdx.x; i < 8*128; i += 128) {
        int rj = i >> 7, c4 = i & 127;
        ((float4*)rows[rj])[c4] =
            *(const float4*)(hf + ((size_t)b*TT + n0 + rj)*DD + (size_t)c4*4);
    }
    __syncthreads();
    int p = threadIdx.x;
    if (p < PRED) {
        float acc[8];
        #pragma unroll
        for (int j = 0; j < 8; ++j) acc[j] = 0.f;
        for (int k4 = 0; k4 < 128; ++k4) {
            float4 w = *(const float4*)(pw + (size_t)p*DD + (size_t)k4*4);
            #pragma unroll
            for (int j = 0; j < 8; ++j) {
                float4 rv = ((const float4*)rows[j])[k4];
                acc[j] += w.x*rv.x + w.y*rv.y + w.z*rv.z + w.w*rv.w;
            }
        }
        float bias = pb[p];
        #pragma unroll
        for (int j = 0; j < 8; ++j) {
            int n = n0 + j;
            out[((size_t)b*PRED + p)*NV + n] =
                (acc[j] + bias)*stdv[b*NV + n] + mean[b*NV + n];
        }
    }
}

// ---------------------------------------------------------------------------
extern "C" void kernel_launch(void* const* d_in, const int* in_sizes, int n_in,
                              void* d_out, int out_size, void* d_ws, size_t ws_size,
                              hipStream_t stream)
{
    (void)in_sizes; (void)n_in; (void)out_size; (void)ws_size;
    const float* x_enc   = (const float*)d_in[0];
    const float* x_mark  = (const float*)d_in[1];
    const float* emb_w   = (const float*)d_in[2];
    const float* emb_b   = (const float*)d_in[3];
    const float* m_win   = (const float*)d_in[4];
    const float* m_convw = (const float*)d_in[5];
    const float* m_convb = (const float*)d_in[6];
    const float* m_wx    = (const float*)d_in[7];
    const float* m_wdt   = (const float*)d_in[8];
    const float* m_bdt   = (const float*)d_in[9];
    const float* m_alog  = (const float*)d_in[10];
    const float* m_dpar  = (const float*)d_in[11];
    const float* m_wout  = (const float*)d_in[12];
    const float* ln1_g   = (const float*)d_in[13];
    const float* ln1_b   = (const float*)d_in[14];
    const float* ff1_w   = (const float*)d_in[15];
    const float* ff1_b   = (const float*)d_in[16];
    const float* ff2_w   = (const float*)d_in[17];
    const float* ff2_b   = (const float*)d_in[18];
    const float* ln2_g   = (const float*)d_in[19];
    const float* ln2_b   = (const float*)d_in[20];
    const float* lnf_g   = (const float*)d_in[21];
    const float* lnf_b   = (const float*)d_in[22];
    const float* proj_w  = (const float*)d_in[23];
    const float* proj_b  = (const float*)d_in[24];
    float* out = (float*)d_out;

    float* ws = (float*)d_ws;
    const size_t NBT = (size_t)MROWS;
    size_t off = 0;
    float* mean = ws + off; off += 8192;
    float* stdv = ws + off; off += 8192;
    ushort* w_emb2  = (ushort*)(ws + off); off += 393216;    // >= 512*1024 bf16
    ushort* w_win2  = (ushort*)(ws + off); off += 3145728;   // >= 4096*1024
    ushort* w_wout2 = (ushort*)(ws + off); off += 1572864;   // >= 2048*1024
    ushort* w_ff12  = (ushort*)(ws + off); off += 786432;    // >= 1024*1024
    ushort* w_ff22  = (ushort*)(ws + off); off += 786432;
    ushort* w_comb2 = (ushort*)(ws + off); off += 1671168;   // >= 4*544*1024
    ushort* tok2 = (ushort*)(ws + off); off += NBT*768;      // aliased: xc2, y2
    ushort* xc2 = tok2;
    ushort* y2  = tok2;
    float* h   = ws + off; off += NBT*DD;
    ushort* h2 = (ushort*)(ws + off); off += NBT*768;
    float* xz  = ws + off; off += NBT*2*DD;
    ushort* fft2 = (ushort*)xz;                              // alias (xz dead at ffn time)
    float* xc  = ws + off; off += NBT*DD;
    float* bc  = ws + off; off += NBT*32;
    float* sp  = ws + off; off += NBT*DD;
    float* fbuf = ws + off; off += NBT*DD;
    float* rbuf = ws + off; off += NBT*DD;

    // ---- weight packing (every call; deterministic) ----
    pack2w<<<dim3((512*512+255)/256),  256, 0, stream>>>(emb_w, w_emb2, 512*512);
    pack2w<<<dim3((4096*512+255)/256), 256, 0, stream>>>(m_win, w_win2, 4096*512);
    pack2w<<<dim3((2048*512+255)/256), 256, 0, stream>>>(m_wout, w_wout2, 2048*512);
    pack2w<<<dim3((1024*512+255)/256), 256, 0, stream>>>(ff1_w, w_ff12, 1024*512);
    pack2w<<<dim3((1024*512+255)/256), 256, 0, stream>>>(ff2_w, w_ff22, 1024*512);
    mkcomb<<<dim3(544,4), 256, 0, stream>>>(m_wx, m_wdt, w_comb2);

    stats_kernel<<<dim3(BB*4), 256, 0, stream>>>(x_enc, mean, stdv);
    tok_kernel<<<dim3(BB*40), 256, 0, stream>>>(x_enc, x_mark, mean, stdv, tok2);

    // h = tok @ emb_w.T + emb_b   (fp32 h + packed h2)
    gemm3<1,0,1,1,0><<<dim3(66*4), 256, 0, stream>>>(tok2, 1024, w_emb2, 1024,
        emb_b, h, DD, h2, DD, nullptr, MROWS, 512, 1024);

    for (int l = 0; l < 2; ++l) {
        for (int dir = 0; dir < 2; ++dir) {
            int li = l*2 + dir;
            gemm3<0,0,1,0,0><<<dim3(66*8), 256, 0, stream>>>(h2, 1024,
                w_win2 + (size_t)li*1024*1024, 1024, nullptr,
                xz, 2*DD, nullptr, 0, nullptr, MROWS, 1024, 1024);
            conv_silu<<<dim3((MROWS*DD)/256), 256, 0, stream>>>(
                xz, m_convw + (size_t)li*DD*2, m_convb + (size_t)li*DD,
                xc, xc2, dir);
            gemm3<0,0,0,0,1><<<dim3(66*5), 256, 0, stream>>>(xc2, 1024,
                w_comb2 + (size_t)li*544*1024, 1024, m_bdt + (size_t)li*DD,
                sp, 512, nullptr, 0, bc, MROWS, 544, 1024);
            scan2<<<dim3(BB*8), 256, 0, stream>>>(sp, xc, xz, bc,
                m_alog + (size_t)li*DD*SS, m_dpar + (size_t)li*DD, y2, dir);
            gemm3<0,0,1,0,0><<<dim3(66*4), 256, 0, stream>>>(y2, 1024,
                w_wout2 + (size_t)li*512*1024, 1024, nullptr,
                (dir == 0) ? fbuf : rbuf, DD, nullptr, 0, nullptr,
                MROWS, 512, 1024);
        }
        ln_kernel<<<dim3(MROWS), 64, 0, stream>>>(h, h, fbuf, rbuf,
            ln1_g + l*DD, ln1_b + l*DD, h2);
        gemm3<1,1,0,1,0><<<dim3(66*4), 256, 0, stream>>>(h2, 1024,
            w_ff12 + (size_t)l*512*1024, 1024, ff1_b + l*DD,
            nullptr, 0, fft2, DD, nullptr, MROWS, 512, 1024);
        gemm3<1,0,1,0,0><<<dim3(66*4), 256, 0, stream>>>(fft2, 1024,
            w_ff22 + (size_t)l*512*1024, 1024, ff2_b + l*DD,
            xc, DD, nullptr, 0, nullptr, MROWS, 512, 1024);
        ln_kernel<<<dim3(MROWS), 64, 0, stream>>>(h, h, xc, nullptr,
            ln2_g + l*DD, ln2_b + l*DD, h2);
    }
    ln_kernel<<<dim3(MROWS), 64, 0, stream>>>(fbuf, h, nullptr, nullptr,
                                              lnf_g, lnf_b, nullptr);
    proj_kernel<<<dim3(BB*32), 128, 0, stream>>>(fbuf, proj_w, proj_b, mean, stdv, out);
}

// Round 16
// 1060.265 us; speedup vs baseline: 1.3248x; 1.0382x over previous
//
#include <hip/hip_runtime.h>
#include <hip/hip_bf16.h>
#include <math.h>
#include <stddef.h>

#define BB 32
#define TT 262
#define DD 512
#define SS 16
#define RR 32
#define SEQ 512
#define NV 256
#define PRED 96
#define MROWS (BB*TT)   // 8384
#define NCHK 8
#define CSZ 33          // 8*33 = 264 >= 262

typedef __attribute__((ext_vector_type(4))) float f32x4;
typedef __attribute__((ext_vector_type(8))) short s16x8;

// ---------------- bf16 helpers ----------------
__device__ inline ushort f2bu(float x) {
    __hip_bfloat16 h = __float2bfloat16(x);
    ushort u; __builtin_memcpy(&u, &h, 2); return u;
}
__device__ inline float bu2f(ushort u) {
    __hip_bfloat16 h; __builtin_memcpy(&h, &u, 2);
    return __bfloat162float(h);
}
// activation 2K pack: [hi | lo]
__device__ inline void pack_act(ushort* base, int col, int Kd, float v) {
    ushort hu = f2bu(v);
    float hf = bu2f(hu);
    ushort lu = f2bu(v - hf);
    base[col] = hu; base[Kd + col] = lu;
}

// async global->LDS, 16B per lane
__device__ inline void gload_lds16(const void* g, void* l) {
    __builtin_amdgcn_global_load_lds(
        (const __attribute__((address_space(1))) void*)g,
        (__attribute__((address_space(3))) void*)l, 16, 0, 0);
}

// ---------------------------------------------------------------------------
// weight 2K pack: [hi | hi], K=512 rows
// ---------------------------------------------------------------------------
__global__ __launch_bounds__(256)
void pack2w(const float* __restrict__ in, ushort* __restrict__ out, int total)
{
    int idx = blockIdx.x * 256 + threadIdx.x;
    if (idx >= total) return;
    int r = idx >> 9, k = idx & 511;
    float x = in[idx];
    ushort hu = f2bu(x);
    size_t b = (size_t)r * 1024;
    out[b + k] = hu; out[b + 512 + k] = hu;
}

// ---------------------------------------------------------------------------
// combined scan-projection weight (dt path folded through wdt), [hi|hi]
// ---------------------------------------------------------------------------
__global__ __launch_bounds__(256)
void mkcomb(const float* __restrict__ wx, const float* __restrict__ wdt,
            ushort* __restrict__ comb2)
{
    int n  = blockIdx.x;
    int li = blockIdx.y;
    const float* wxl = wx + (size_t)li*64*512;
    ushort* outb = comb2 + ((size_t)li*544 + n)*1024;
    if (n < 512) {
        __shared__ float wr[32];
        if (threadIdx.x < 32)
            wr[threadIdx.x] = wdt[(size_t)li*512*32 + (size_t)n*32 + threadIdx.x];
        __syncthreads();
        for (int kk = threadIdx.x; kk < 512; kk += 256) {
            float acc = 0.f;
            #pragma unroll
            for (int r = 0; r < 32; ++r)
                acc = fmaf(wr[r], wxl[r*512 + kk], acc);
            ushort hu = f2bu(acc);
            outb[kk] = hu; outb[512+kk] = hu;
        }
    } else {
        int s = n - 512;
        for (int kk = threadIdx.x; kk < 512; kk += 256) {
            float v = wxl[(32+s)*512 + kk];
            ushort hu = f2bu(v);
            outb[kk] = hu; outb[512+kk] = hu;
        }
    }
}

// ---------------------------------------------------------------------------
// per-(b,n) mean/std over SEQ
// ---------------------------------------------------------------------------
__global__ __launch_bounds__(256)
void stats_kernel(const float* __restrict__ x_enc,
                  float* __restrict__ mean, float* __restrict__ stdv)
{
    int b  = blockIdx.x >> 2;
    int n0 = (blockIdx.x & 3) << 6;
    int lane = threadIdx.x & 63;
    int w    = threadIdx.x >> 6;
    int n = n0 + lane;
    float s = 0.f, s2 = 0.f;
    for (int t = w; t < SEQ; t += 4) {
        float v = x_enc[((size_t)b*SEQ + t)*NV + n];
        s += v; s2 += v*v;
    }
    __shared__ float ls[4][64], ls2[4][64];
    ls[w][lane] = s; ls2[w][lane] = s2;
    __syncthreads();
    if (w == 0) {
        s  = ls[0][lane] + ls[1][lane] + ls[2][lane] + ls[3][lane];
        s2 = ls2[0][lane] + ls2[1][lane] + ls2[2][lane] + ls2[3][lane];
        float mu  = s * (1.f/SEQ);
        float var = s2 * (1.f/SEQ) - mu*mu;
        mean[b*NV + n] = mu;
        stdv[b*NV + n] = sqrtf(var + 1e-5f);
    }
}

// ---------------------------------------------------------------------------
// tok2: normalized transpose packed [hi|lo] over K=512
// ---------------------------------------------------------------------------
__global__ __launch_bounds__(256)
void tok_kernel(const float* __restrict__ x_enc, const float* __restrict__ x_mark,
                const float* __restrict__ mean, const float* __restrict__ stdv,
                ushort* __restrict__ tok2)
{
    int b  = blockIdx.x / 40;
    int r  = blockIdx.x % 40;
    int tt = r / 5;
    int vt = r % 5;
    int t0 = tt << 6, v0 = vt << 6;
    __shared__ float tile[64][65];
    int lv = threadIdx.x & 63;
    for (int i = threadIdx.x >> 6; i < 64; i += 4) {
        int t = t0 + i, v = v0 + lv;
        float val = 0.f;
        if (v < NV) {
            val = (x_enc[((size_t)b*SEQ + t)*NV + v] - mean[b*NV + v]) / stdv[b*NV + v];
        } else if (v < TT) {
            val = x_mark[((size_t)b*SEQ + t)*6 + (v - NV)];
        }
        tile[i][lv] = val;
    }
    __syncthreads();
    for (int i = threadIdx.x >> 6; i < 64; i += 4) {
        int v = v0 + i;
        if (v < TT) {
            size_t row = (size_t)b*TT + v;
            pack_act(tok2 + row*1024, t0 + lv, 512, tile[lv][i]);
        }
    }
}

// ---------------------------------------------------------------------------
// bf16 MFMA GEMM over packed 2K operands (NT; K2 multiple of 64).
// 1D grid, bijective XCD-aware swizzle (8 XCDs).
// ---------------------------------------------------------------------------
template<int HAS_BIAS, int RELU, int WF32, int W3, int SCANEP>
__global__ __launch_bounds__(256)
void gemm3(const ushort* __restrict__ A3, int lda3,
           const ushort* __restrict__ W3p, int ldw3,
           const float* __restrict__ bias,
           float* __restrict__ C, int ldc,
           ushort* __restrict__ C3, int N_out,
           float* __restrict__ bcbuf,
           int M, int Nn, int K3)
{
    __shared__ ushort lds[2][2][128*64];   // [buf][A=0/W=1] : 64 KB
    const int tid  = threadIdx.x;
    const int lane = tid & 63;
    const int wid  = tid >> 6;
    const int wr = wid >> 1, wc = wid & 1;

    // bijective XCD swizzle (m204)
    int nwg = gridDim.x;
    int q8 = nwg >> 3, r8 = nwg & 7;
    int xcd = blockIdx.x & 7;
    int idx = blockIdx.x >> 3;
    int swz = (xcd < r8 ? xcd*(q8+1) : r8*(q8+1) + (xcd-r8)*q8) + idx;
    const int m0 = (swz % 66) * 128;
    const int n0 = (swz / 66) * 128;

    const int l8 = lane >> 3;
    const int sl = lane & 7;
    const int ssl = sl ^ l8;

    int arow[4], wrow[4];
    #pragma unroll
    for (int qq = 0; qq < 4; ++qq) {
        int r = (wid*4 + qq)*8 + l8;
        int ar = m0 + r; if (ar > M-1) ar = M-1;
        arow[qq] = ar;
        int wrr = n0 + r; if (wrr > Nn-1) wrr = Nn-1;
        wrow[qq] = wrr;
    }

    f32x4 acc[4][4];
    #pragma unroll
    for (int i = 0; i < 4; ++i)
        #pragma unroll
        for (int j = 0; j < 4; ++j) acc[i][j] = (f32x4){0.f,0.f,0.f,0.f};

    const int nk = K3 >> 6;
    const int rl = lane & 15;
    const int kq = lane >> 4;

    auto stage = [&](int buf_, int kt_) {
        #pragma unroll
        for (int qq = 0; qq < 4; ++qq) {
            int c = wid*4 + qq;
            gload_lds16(A3 + (size_t)arow[qq]*lda3 + kt_*64 + ssl*8,
                        (void*)&lds[buf_][0][c*512]);
            gload_lds16(W3p + (size_t)wrow[qq]*ldw3 + kt_*64 + ssl*8,
                        (void*)&lds[buf_][1][c*512]);
        }
    };

    stage(0, 0);
    __syncthreads();

    for (int kt = 0; kt < nk; ++kt) {
        int cur = kt & 1;
        if (kt + 1 < nk) stage(cur ^ 1, kt + 1);
        #pragma unroll
        for (int kk = 0; kk < 2; ++kk) {
            s16x8 av[4], wv[4];
            #pragma unroll
            for (int mi = 0; mi < 4; ++mi) {
                int row = wr*64 + mi*16 + rl;
                int ck = (kk*4 + kq) ^ (row & 7);
                av[mi] = *(const s16x8*)&lds[cur][0][row*64 + (ck<<3)];
            }
            #pragma unroll
            for (int ni = 0; ni < 4; ++ni) {
                int row = wc*64 + ni*16 + rl;
                int ck = (kk*4 + kq) ^ (row & 7);
                wv[ni] = *(const s16x8*)&lds[cur][1][row*64 + (ck<<3)];
            }
            #pragma unroll
            for (int mi = 0; mi < 4; ++mi)
                #pragma unroll
                for (int ni = 0; ni < 4; ++ni)
                    acc[mi][ni] = __builtin_amdgcn_mfma_f32_16x16x32_bf16(
                        av[mi], wv[ni], acc[mi][ni], 0, 0, 0);
        }
        __syncthreads();
    }

    #pragma unroll
    for (int ni = 0; ni < 4; ++ni) {
        int n = n0 + wc*64 + ni*16 + rl;
        if (n >= Nn) continue;
        float bv = (HAS_BIAS && !SCANEP) ? bias[n] : 0.f;
        #pragma unroll
        for (int mi = 0; mi < 4; ++mi) {
            #pragma unroll
            for (int j = 0; j < 4; ++j) {
                int m = m0 + wr*64 + mi*16 + kq*4 + j;
                if (m >= M) continue;
                float v = acc[mi][ni][j];
                if (SCANEP) {
                    if (n < 512) {
                        v += bias[n];
                        v = fmaxf(v, 0.f) + log1pf(__expf(-fabsf(v)));
                        C[(size_t)m*ldc + n] = v;
                    } else {
                        bcbuf[(size_t)m*32 + (n - 512)] = v;
                    }
                } else {
                    if (HAS_BIAS) v += bv;
                    if (RELU) v = fmaxf(v, 0.f);
                    if (WF32) C[(size_t)m*ldc + n] = v;
                    if (W3)   pack_act(C3 + (size_t)m*(2*N_out), n, N_out, v);
                }
            }
        }
    }
}

// ---------------------------------------------------------------------------
// conv + SiLU (fp32 xc + packed xc2), in-place silu on z-half of xz
// ---------------------------------------------------------------------------
__global__ __launch_bounds__(256)
void conv_silu(float* __restrict__ xz, const float* __restrict__ cw,
               const float* __restrict__ cb, float* __restrict__ xc,
               ushort* __restrict__ xc2, int rev)
{
    int idx = blockIdx.x * 256 + threadIdx.x;
    int d  = idx & (DD-1);
    int bt = idx >> 9;
    int t  = bt % TT;
    float cur = xz[(size_t)bt*2*DD + d];
    int tn = rev ? t + 1 : t - 1;
    float prev = 0.f;
    if (tn >= 0 && tn < TT)
        prev = xz[((size_t)bt + (rev ? 1 : -1))*2*DD + d];
    float v = prev*cw[d*2] + cur*cw[d*2+1] + cb[d];
    float sv = v / (1.f + __expf(-v));
    xc[idx] = sv;
    pack_act(xc2 + (size_t)bt*1024, d, 512, sv);
    float z = xz[(size_t)bt*2*DD + DD + d];
    xz[(size_t)bt*2*DD + DD + d] = z / (1.f + __expf(-z));
}

// ---------------------------------------------------------------------------
// Chunked scan, pass 1: per-chunk local scan + decay product (no output).
// grid (256, NCHK-1), block 256 = 64d x 4sg. All t in-range for c < NCHK-1.
// ---------------------------------------------------------------------------
__global__ __launch_bounds__(256)
void scan_p1(const float* __restrict__ sp_g, const float* __restrict__ xc_g,
             const float* __restrict__ bc_g, const float* __restrict__ alog,
             float* __restrict__ hs, float* __restrict__ ps, int rev)
{
    int sblk = blockIdx.x;
    int c    = blockIdx.y;
    int b  = sblk >> 3;
    int d0 = (sblk & 7) << 6;
    int tid = threadIdx.x;
    int sg = tid & 3;
    int dl = tid >> 2;
    int d  = d0 + dl;

    float Ac[4];
    #pragma unroll
    for (int j = 0; j < 4; ++j)
        Ac[j] = -__expf(alog[d*SS + sg*4 + j]);
    float h0=0.f,h1=0.f,h2=0.f,h3=0.f;
    float p0=1.f,p1=1.f,p2=1.f,p3=1.f;
    size_t bbase = (size_t)b*TT;
    int t0 = c*CSZ;
    #pragma unroll 3
    for (int i = 0; i < CSZ; ++i) {
        int t = t0 + i;
        size_t p = bbase + (rev ? TT-1-t : t);
        float spv = sp_g[p*DD + d];
        float xcv = xc_g[p*DD + d];
        float4 Bv = *(const float4*)(bc_g + p*32 + sg*4);
        float dtxc = spv*xcv;
        float e0 = __expf(spv*Ac[0]);
        float e1 = __expf(spv*Ac[1]);
        float e2 = __expf(spv*Ac[2]);
        float e3 = __expf(spv*Ac[3]);
        h0 = fmaf(e0,h0,dtxc*Bv.x); p0 *= e0;
        h1 = fmaf(e1,h1,dtxc*Bv.y); p1 *= e1;
        h2 = fmaf(e2,h2,dtxc*Bv.z); p2 *= e2;
        h3 = fmaf(e3,h3,dtxc*Bv.w); p3 *= e3;
    }
    size_t o = ((size_t)c*256 + sblk)*256 + tid;
    float4 hv; hv.x=h0; hv.y=h1; hv.z=h2; hv.w=h3;
    float4 pv; pv.x=p0; pv.y=p1; pv.z=p2; pv.w=p3;
    ((float4*)hs)[o] = hv;
    ((float4*)ps)[o] = pv;
}

// ---------------------------------------------------------------------------
// Chunked scan, combine: prefix over chunks (elementwise, diagonal transfer).
// grid 256, block 256. hin[c] = state entering chunk c+1.
// ---------------------------------------------------------------------------
__global__ __launch_bounds__(256)
void scan_comb(const float* __restrict__ hs, const float* __restrict__ ps,
               float* __restrict__ hin)
{
    size_t gid = (size_t)blockIdx.x*256 + threadIdx.x;   // 65536
    float4 h = {0.f,0.f,0.f,0.f};
    for (int c = 0; c < NCHK-1; ++c) {
        size_t o = (size_t)c*65536 + gid;
        float4 hl = ((const float4*)hs)[o];
        float4 pv = ((const float4*)ps)[o];
        h.x = fmaf(pv.x, h.x, hl.x);
        h.y = fmaf(pv.y, h.y, hl.y);
        h.z = fmaf(pv.z, h.z, hl.z);
        h.w = fmaf(pv.w, h.w, hl.w);
        ((float4*)hin)[o] = h;
    }
}

// ---------------------------------------------------------------------------
// Chunked scan, pass 2: replay chunk with known h_in, emit y. grid (256,NCHK).
// ---------------------------------------------------------------------------
__global__ __launch_bounds__(256)
void scan_p2(const float* __restrict__ sp_g, const float* __restrict__ xc_g,
             const float* __restrict__ xz_g, const float* __restrict__ bc_g,
             const float* __restrict__ alog, const float* __restrict__ dparam,
             const float* __restrict__ hin, ushort* __restrict__ y2, int rev)
{
    int sblk = blockIdx.x;
    int c    = blockIdx.y;
    int b  = sblk >> 3;
    int d0 = (sblk & 7) << 6;
    int tid = threadIdx.x;
    int sg = tid & 3;
    int dl = tid >> 2;
    int d  = d0 + dl;

    float Ac[4];
    #pragma unroll
    for (int j = 0; j < 4; ++j)
        Ac[j] = -__expf(alog[d*SS + sg*4 + j]);
    float dp = dparam[d];
    float h0=0.f,h1=0.f,h2=0.f,h3=0.f;
    if (c > 0) {
        float4 hv = ((const float4*)hin)[((size_t)(c-1)*256 + sblk)*256 + tid];
        h0=hv.x; h1=hv.y; h2=hv.z; h3=hv.w;
    }
    size_t bbase = (size_t)b*TT;
    int t0 = c*CSZ;
    #pragma unroll 3
    for (int i = 0; i < CSZ; ++i) {
        int t = t0 + i;
        int tc = t < TT ? t : TT-1;
        size_t p = bbase + (rev ? TT-1-tc : tc);
        float spv = sp_g[p*DD + d];
        float xcv = xc_g[p*DD + d];
        float zsv = xz_g[p*2*DD + DD + d];
        float4 Bv = *(const float4*)(bc_g + p*32 + sg*4);
        float4 Cv = *(const float4*)(bc_g + p*32 + 16 + sg*4);
        float dtxc = spv*xcv;
        float e0 = __expf(spv*Ac[0]);
        float e1 = __expf(spv*Ac[1]);
        float e2 = __expf(spv*Ac[2]);
        float e3 = __expf(spv*Ac[3]);
        h0 = fmaf(e0,h0,dtxc*Bv.x);
        h1 = fmaf(e1,h1,dtxc*Bv.y);
        h2 = fmaf(e2,h2,dtxc*Bv.z);
        h3 = fmaf(e3,h3,dtxc*Bv.w);
        float dot = h0*Cv.x + h1*Cv.y + h2*Cv.z + h3*Cv.w;
        dot += __shfl_xor(dot, 1);
        dot += __shfl_xor(dot, 2);
        if (sg == 0 && t < TT) {
            int tg = rev ? TT-1-t : t;
            float yv = (dot + dp*xcv) * zsv;
            pack_act(y2 + (bbase + tg)*1024, d, 512, yv);
        }
    }
}

// ---------------------------------------------------------------------------
// LayerNorm (up to 3 summed inputs), optional 2K-pack output
// ---------------------------------------------------------------------------
__global__ __launch_bounds__(64)
void ln_kernel(float* __restrict__ dst, const float* __restrict__ a,
               const float* __restrict__ b, const float* __restrict__ c,
               const float* __restrict__ g, const float* __restrict__ beta,
               ushort* __restrict__ out2)
{
    int row = blockIdx.x;
    int lane = threadIdx.x;
    size_t base = (size_t)row * DD;
    float x[8];
    #pragma unroll
    for (int j = 0; j < 2; ++j) {
        int e4 = j*64 + lane;
        float4 v = *(const float4*)(a + base + (size_t)e4*4);
        if (b) { float4 t = *(const float4*)(b + base + (size_t)e4*4); v.x+=t.x; v.y+=t.y; v.z+=t.z; v.w+=t.w; }
        if (c) { float4 t = *(const float4*)(c + base + (size_t)e4*4); v.x+=t.x; v.y+=t.y; v.z+=t.z; v.w+=t.w; }
        x[j*4+0]=v.x; x[j*4+1]=v.y; x[j*4+2]=v.z; x[j*4+3]=v.w;
    }
    float s = 0.f;
    #pragma unroll
    for (int i = 0; i < 8; ++i) s += x[i];
    #pragma unroll
    for (int m = 1; m < 64; m <<= 1) s += __shfl_xor(s, m);
    float mu = s * (1.f/DD);
    float vs = 0.f;
    #pragma unroll
    for (int i = 0; i < 8; ++i) { float dd = x[i]-mu; vs += dd*dd; }
    #pragma unroll
    for (int m = 1; m < 64; m <<= 1) vs += __shfl_xor(vs, m);
    float r = rsqrtf(vs*(1.f/DD) + 1e-5f);
    #pragma unroll
    for (int j = 0; j < 2; ++j) {
        int e4 = j*64 + lane;
        float4 gv = *(const float4*)(g    + (size_t)e4*4);
        float4 bv = *(const float4*)(beta + (size_t)e4*4);
        float4 o;
        o.x = (x[j*4+0]-mu)*r*gv.x + bv.x;
        o.y = (x[j*4+1]-mu)*r*gv.y + bv.y;
        o.z = (x[j*4+2]-mu)*r*gv.z + bv.z;
        o.w = (x[j*4+3]-mu)*r*gv.w + bv.w;
        *(float4*)(dst + base + (size_t)e4*4) = o;
        if (out2) {
            ushort* ob = out2 + (size_t)row*1024;
            pack_act(ob, e4*4+0, 512, o.x);
            pack_act(ob, e4*4+1, 512, o.y);
            pack_act(ob, e4*4+2, 512, o.z);
            pack_act(ob, e4*4+3, 512, o.w);
        }
    }
}

// ---------------------------------------------------------------------------
// projection + transpose + de-norm
// ---------------------------------------------------------------------------
__global__ __launch_bounds__(128)
void proj_kernel(const float* __restrict__ hf, const float* __restrict__ pw,
                 const float* __restrict__ pb, const float* __restrict__ mean,
                 const float* __restrict__ stdv, float* __restrict__ out)
{
    int b  = blockIdx.x >> 5;
    int n0 = (blockIdx.x & 31) << 3;
    __shared__ float rows[8][DD];
    for (int i = threadIdx.x; i < 8*128; i += 128) {
        int rj = i >> 7, c4 = i & 127;
        ((float4*)rows[rj])[c4] =
            *(const float4*)(hf + ((size_t)b*TT + n0 + rj)*DD + (size_t)c4*4);
    }
    __syncthreads();
    int p = threadIdx.x;
    if (p < PRED) {
        float acc[8];
        #pragma unroll
        for (int j = 0; j < 8; ++j) acc[j] = 0.f;
        for (int k4 = 0; k4 < 128; ++k4) {
            float4 w = *(const float4*)(pw + (size_t)p*DD + (size_t)k4*4);
            #pragma unroll
            for (int j = 0; j < 8; ++j) {
                float4 rv = ((const float4*)rows[j])[k4];
                acc[j] += w.x*rv.x + w.y*rv.y + w.z*rv.z + w.w*rv.w;
            }
        }
        float bias = pb[p];
        #pragma unroll
        for (int j = 0; j < 8; ++j) {
            int n = n0 + j;
            out[((size_t)b*PRED + p)*NV + n] =
                (acc[j] + bias)*stdv[b*NV + n] + mean[b*NV + n];
        }
    }
}

// ---------------------------------------------------------------------------
extern "C" void kernel_launch(void* const* d_in, const int* in_sizes, int n_in,
                              void* d_out, int out_size, void* d_ws, size_t ws_size,
                              hipStream_t stream)
{
    (void)in_sizes; (void)n_in; (void)out_size; (void)ws_size;
    const float* x_enc   = (const float*)d_in[0];
    const float* x_mark  = (const float*)d_in[1];
    const float* emb_w   = (const float*)d_in[2];
    const float* emb_b   = (const float*)d_in[3];
    const float* m_win   = (const float*)d_in[4];
    const float* m_convw = (const float*)d_in[5];
    const float* m_convb = (const float*)d_in[6];
    const float* m_wx    = (const float*)d_in[7];
    const float* m_wdt   = (const float*)d_in[8];
    const float* m_bdt   = (const float*)d_in[9];
    const float* m_alog  = (const float*)d_in[10];
    const float* m_dpar  = (const float*)d_in[11];
    const float* m_wout  = (const float*)d_in[12];
    const float* ln1_g   = (const float*)d_in[13];
    const float* ln1_b   = (const float*)d_in[14];
    const float* ff1_w   = (const float*)d_in[15];
    const float* ff1_b   = (const float*)d_in[16];
    const float* ff2_w   = (const float*)d_in[17];
    const float* ff2_b   = (const float*)d_in[18];
    const float* ln2_g   = (const float*)d_in[19];
    const float* ln2_b   = (const float*)d_in[20];
    const float* lnf_g   = (const float*)d_in[21];
    const float* lnf_b   = (const float*)d_in[22];
    const float* proj_w  = (const float*)d_in[23];
    const float* proj_b  = (const float*)d_in[24];
    float* out = (float*)d_out;

    float* ws = (float*)d_ws;
    const size_t NBT = (size_t)MROWS;
    size_t off = 0;
    float* mean = ws + off; off += 8192;
    float* stdv = ws + off; off += 8192;
    ushort* w_emb2  = (ushort*)(ws + off); off += 393216;
    ushort* w_win2  = (ushort*)(ws + off); off += 3145728;
    ushort* w_wout2 = (ushort*)(ws + off); off += 1572864;
    ushort* w_ff12  = (ushort*)(ws + off); off += 786432;
    ushort* w_ff22  = (ushort*)(ws + off); off += 786432;
    ushort* w_comb2 = (ushort*)(ws + off); off += 1671168;
    ushort* tok2 = (ushort*)(ws + off); off += NBT*768;      // aliased: xc2, y2
    ushort* xc2 = tok2;
    ushort* y2  = tok2;
    float* h   = ws + off; off += NBT*DD;
    ushort* h2 = (ushort*)(ws + off); off += NBT*768;
    float* xz  = ws + off; off += NBT*2*DD;
    ushort* fft2 = (ushort*)xz;                              // alias
    float* xc  = ws + off; off += NBT*DD;
    float* bc  = ws + off; off += NBT*32;
    float* sp  = ws + off; off += NBT*DD;
    float* fbuf = ws + off; off += NBT*DD;
    float* rbuf = ws + off; off += NBT*DD;
    float* hs  = ws + off; off += (NCHK-1)*65536*4;          // 1.84M f
    float* psb = ws + off; off += (NCHK-1)*65536*4;
    float* hin = ws + off; off += (NCHK-1)*65536*4;

    // ---- weight packing ----
    pack2w<<<dim3((512*512+255)/256),  256, 0, stream>>>(emb_w, w_emb2, 512*512);
    pack2w<<<dim3((4096*512+255)/256), 256, 0, stream>>>(m_win, w_win2, 4096*512);
    pack2w<<<dim3((2048*512+255)/256), 256, 0, stream>>>(m_wout, w_wout2, 2048*512);
    pack2w<<<dim3((1024*512+255)/256), 256, 0, stream>>>(ff1_w, w_ff12, 1024*512);
    pack2w<<<dim3((1024*512+255)/256), 256, 0, stream>>>(ff2_w, w_ff22, 1024*512);
    mkcomb<<<dim3(544,4), 256, 0, stream>>>(m_wx, m_wdt, w_comb2);

    stats_kernel<<<dim3(BB*4), 256, 0, stream>>>(x_enc, mean, stdv);
    tok_kernel<<<dim3(BB*40), 256, 0, stream>>>(x_enc, x_mark, mean, stdv, tok2);

    gemm3<1,0,1,1,0><<<dim3(66*4), 256, 0, stream>>>(tok2, 1024, w_emb2, 1024,
        emb_b, h, DD, h2, DD, nullptr, MROWS, 512, 1024);

    for (int l = 0; l < 2; ++l) {
        for (int dir = 0; dir < 2; ++dir) {
            int li = l*2 + dir;
            gemm3<0,0,1,0,0><<<dim3(66*8), 256, 0, stream>>>(h2, 1024,
                w_win2 + (size_t)li*1024*1024, 1024, nullptr,
                xz, 2*DD, nullptr, 0, nullptr, MROWS, 1024, 1024);
            conv_silu<<<dim3((MROWS*DD)/256), 256, 0, stream>>>(
                xz, m_convw + (size_t)li*DD*2, m_convb + (size_t)li*DD,
                xc, xc2, dir);
            gemm3<0,0,0,0,1><<<dim3(66*5), 256, 0, stream>>>(xc2, 1024,
                w_comb2 + (size_t)li*544*1024, 1024, m_bdt + (size_t)li*DD,
                sp, 512, nullptr, 0, bc, MROWS, 544, 1024);
            const float* al = m_alog + (size_t)li*DD*SS;
            const float* dpp = m_dpar + (size_t)li*DD;
            scan_p1<<<dim3(256, NCHK-1), 256, 0, stream>>>(sp, xc, bc, al,
                hs, psb, dir);
            scan_comb<<<dim3(256), 256, 0, stream>>>(hs, psb, hin);
            scan_p2<<<dim3(256, NCHK), 256, 0, stream>>>(sp, xc, xz, bc, al,
                dpp, hin, y2, dir);
            gemm3<0,0,1,0,0><<<dim3(66*4), 256, 0, stream>>>(y2, 1024,
                w_wout2 + (size_t)li*512*1024, 1024, nullptr,
                (dir == 0) ? fbuf : rbuf, DD, nullptr, 0, nullptr,
                MROWS, 512, 1024);
        }
        ln_kernel<<<dim3(MROWS), 64, 0, stream>>>(h, h, fbuf, rbuf,
            ln1_g + l*DD, ln1_b + l*DD, h2);
        gemm3<1,1,0,1,0><<<dim3(66*4), 256, 0, stream>>>(h2, 1024,
            w_ff12 + (size_t)l*512*1024, 1024, ff1_b + l*DD,
            nullptr, 0, fft2, DD, nullptr, MROWS, 512, 1024);
        gemm3<1,0,1,0,0><<<dim3(66*4), 256, 0, stream>>>(fft2, 1024,
            w_ff22 + (size_t)l*512*1024, 1024, ff2_b + l*DD,
            xc, DD, nullptr, 0, nullptr, MROWS, 512, 1024);
        ln_kernel<<<dim3(MROWS), 64, 0, stream>>>(h, h, xc, nullptr,
            ln2_g + l*DD, ln2_b + l*DD, h2);
    }
    ln_kernel<<<dim3(MROWS), 64, 0, stream>>>(fbuf, h, nullptr, nullptr,
                                              lnf_g, lnf_b, nullptr);
    proj_kernel<<<dim3(BB*32), 128, 0, stream>>>(fbuf, proj_w, proj_b, mean, stdv, out);
}

// Round 17
// 1015.237 us; speedup vs baseline: 1.3836x; 1.0444x over previous
//
#include <hip/hip_runtime.h>
#include <hip/hip_bf16.h>
#include <math.h>
#include <stddef.h>

#define BB 32
#define TT 262
#define DD 512
#define SS 16
#define RR 32
#define SEQ 512
#define NV 256
#define PRED 96
#define MROWS (BB*TT)   // 8384
#define NCHK 8
#define CSZ 33          // 8*33 = 264 >= 262

typedef __attribute__((ext_vector_type(4))) float f32x4;
typedef __attribute__((ext_vector_type(8))) short s16x8;

// ---------------- bf16 helpers ----------------
__device__ inline ushort f2bu(float x) {
    __hip_bfloat16 h = __float2bfloat16(x);
    ushort u; __builtin_memcpy(&u, &h, 2); return u;
}
__device__ inline float bu2f(ushort u) {
    __hip_bfloat16 h; __builtin_memcpy(&h, &u, 2);
    return __bfloat162float(h);
}
// activation 2K pack: [hi | lo]
__device__ inline void pack_act(ushort* base, int col, int Kd, float v) {
    ushort hu = f2bu(v);
    float hf = bu2f(hu);
    ushort lu = f2bu(v - hf);
    base[col] = hu; base[Kd + col] = lu;
}

// async global->LDS, 16B per lane
__device__ inline void gload_lds16(const void* g, void* l) {
    __builtin_amdgcn_global_load_lds(
        (const __attribute__((address_space(1))) void*)g,
        (__attribute__((address_space(3))) void*)l, 16, 0, 0);
}

// ---------------------------------------------------------------------------
// weight 2K pack: [hi | hi], K=512 rows
// ---------------------------------------------------------------------------
__global__ __launch_bounds__(256)
void pack2w(const float* __restrict__ in, ushort* __restrict__ out, int total)
{
    int idx = blockIdx.x * 256 + threadIdx.x;
    if (idx >= total) return;
    int r = idx >> 9, k = idx & 511;
    float x = in[idx];
    ushort hu = f2bu(x);
    size_t b = (size_t)r * 1024;
    out[b + k] = hu; out[b + 512 + k] = hu;
}

// ---------------------------------------------------------------------------
// combined scan-projection weight (dt path folded through wdt), [hi|hi]
// ---------------------------------------------------------------------------
__global__ __launch_bounds__(256)
void mkcomb(const float* __restrict__ wx, const float* __restrict__ wdt,
            ushort* __restrict__ comb2)
{
    int n  = blockIdx.x;
    int li = blockIdx.y;
    const float* wxl = wx + (size_t)li*64*512;
    ushort* outb = comb2 + ((size_t)li*544 + n)*1024;
    if (n < 512) {
        __shared__ float wr[32];
        if (threadIdx.x < 32)
            wr[threadIdx.x] = wdt[(size_t)li*512*32 + (size_t)n*32 + threadIdx.x];
        __syncthreads();
        for (int kk = threadIdx.x; kk < 512; kk += 256) {
            float acc = 0.f;
            #pragma unroll
            for (int r = 0; r < 32; ++r)
                acc = fmaf(wr[r], wxl[r*512 + kk], acc);
            ushort hu = f2bu(acc);
            outb[kk] = hu; outb[512+kk] = hu;
        }
    } else {
        int s = n - 512;
        for (int kk = threadIdx.x; kk < 512; kk += 256) {
            float v = wxl[(32+s)*512 + kk];
            ushort hu = f2bu(v);
            outb[kk] = hu; outb[512+kk] = hu;
        }
    }
}

// ---------------------------------------------------------------------------
// per-(b,n) mean/std over SEQ. grid = BB*16, block 256 = 16n x 16tg.
// Fixed-trip unrolled loop, independent accumulators -> deep MLP.
// ---------------------------------------------------------------------------
__global__ __launch_bounds__(256)
void stats_kernel(const float* __restrict__ x_enc,
                  float* __restrict__ mean, float* __restrict__ stdv)
{
    int b  = blockIdx.x >> 4;
    int n0 = (blockIdx.x & 15) << 4;
    int nl = threadIdx.x & 15;
    int tg = threadIdx.x >> 4;
    int n = n0 + nl;
    const float* base = x_enc + (size_t)b*SEQ*NV + n;
    float s0 = 0.f, s1 = 0.f, q0 = 0.f, q1 = 0.f;
    #pragma unroll 8
    for (int i = 0; i < 16; ++i) {
        int t = tg + i*32;
        float v0 = base[(size_t)t*NV];
        float v1 = base[(size_t)(t+16)*NV];
        s0 += v0; q0 = fmaf(v0, v0, q0);
        s1 += v1; q1 = fmaf(v1, v1, q1);
    }
    float s = s0 + s1, q = q0 + q1;
    __shared__ float ls[16][17], lq[16][17];
    ls[tg][nl] = s; lq[tg][nl] = q;
    __syncthreads();
    if (tg < 8) { ls[tg][nl] += ls[tg+8][nl]; lq[tg][nl] += lq[tg+8][nl]; }
    __syncthreads();
    if (tg < 4) { ls[tg][nl] += ls[tg+4][nl]; lq[tg][nl] += lq[tg+4][nl]; }
    __syncthreads();
    if (tg < 2) { ls[tg][nl] += ls[tg+2][nl]; lq[tg][nl] += lq[tg+2][nl]; }
    __syncthreads();
    if (tg == 0) {
        s = ls[0][nl] + ls[1][nl];
        q = lq[0][nl] + lq[1][nl];
        float mu  = s * (1.f/SEQ);
        float var = q * (1.f/SEQ) - mu*mu;
        mean[b*NV + n] = mu;
        stdv[b*NV + n] = sqrtf(var + 1e-5f);
    }
}

// ---------------------------------------------------------------------------
// tok2: normalized transpose packed [hi|lo] over K=512
// ---------------------------------------------------------------------------
__global__ __launch_bounds__(256)
void tok_kernel(const float* __restrict__ x_enc, const float* __restrict__ x_mark,
                const float* __restrict__ mean, const float* __restrict__ stdv,
                ushort* __restrict__ tok2)
{
    int b  = blockIdx.x / 40;
    int r  = blockIdx.x % 40;
    int tt = r / 5;
    int vt = r % 5;
    int t0 = tt << 6, v0 = vt << 6;
    __shared__ float tile[64][65];
    int lv = threadIdx.x & 63;
    for (int i = threadIdx.x >> 6; i < 64; i += 4) {
        int t = t0 + i, v = v0 + lv;
        float val = 0.f;
        if (v < NV) {
            val = (x_enc[((size_t)b*SEQ + t)*NV + v] - mean[b*NV + v]) / stdv[b*NV + v];
        } else if (v < TT) {
            val = x_mark[((size_t)b*SEQ + t)*6 + (v - NV)];
        }
        tile[i][lv] = val;
    }
    __syncthreads();
    for (int i = threadIdx.x >> 6; i < 64; i += 4) {
        int v = v0 + i;
        if (v < TT) {
            size_t row = (size_t)b*TT + v;
            pack_act(tok2 + row*1024, t0 + lv, 512, tile[lv][i]);
        }
    }
}

// ---------------------------------------------------------------------------
// bf16 MFMA GEMM over packed 2K operands (NT; K2 multiple of 64).
// 1D grid, bijective XCD-aware swizzle (8 XCDs).
// ---------------------------------------------------------------------------
template<int HAS_BIAS, int RELU, int WF32, int W3, int SCANEP>
__global__ __launch_bounds__(256)
void gemm3(const ushort* __restrict__ A3, int lda3,
           const ushort* __restrict__ W3p, int ldw3,
           const float* __restrict__ bias,
           float* __restrict__ C, int ldc,
           ushort* __restrict__ C3, int N_out,
           float* __restrict__ bcbuf,
           int M, int Nn, int K3)
{
    __shared__ ushort lds[2][2][128*64];   // [buf][A=0/W=1] : 64 KB
    const int tid  = threadIdx.x;
    const int lane = tid & 63;
    const int wid  = tid >> 6;
    const int wr = wid >> 1, wc = wid & 1;

    // bijective XCD swizzle (m204)
    int nwg = gridDim.x;
    int q8 = nwg >> 3, r8 = nwg & 7;
    int xcd = blockIdx.x & 7;
    int idx = blockIdx.x >> 3;
    int swz = (xcd < r8 ? xcd*(q8+1) : r8*(q8+1) + (xcd-r8)*q8) + idx;
    const int m0 = (swz % 66) * 128;
    const int n0 = (swz / 66) * 128;

    const int l8 = lane >> 3;
    const int sl = lane & 7;
    const int ssl = sl ^ l8;

    int arow[4], wrow[4];
    #pragma unroll
    for (int qq = 0; qq < 4; ++qq) {
        int r = (wid*4 + qq)*8 + l8;
        int ar = m0 + r; if (ar > M-1) ar = M-1;
        arow[qq] = ar;
        int wrr = n0 + r; if (wrr > Nn-1) wrr = Nn-1;
        wrow[qq] = wrr;
    }

    f32x4 acc[4][4];
    #pragma unroll
    for (int i = 0; i < 4; ++i)
        #pragma unroll
        for (int j = 0; j < 4; ++j) acc[i][j] = (f32x4){0.f,0.f,0.f,0.f};

    const int nk = K3 >> 6;
    const int rl = lane & 15;
    const int kq = lane >> 4;

    auto stage = [&](int buf_, int kt_) {
        #pragma unroll
        for (int qq = 0; qq < 4; ++qq) {
            int c = wid*4 + qq;
            gload_lds16(A3 + (size_t)arow[qq]*lda3 + kt_*64 + ssl*8,
                        (void*)&lds[buf_][0][c*512]);
            gload_lds16(W3p + (size_t)wrow[qq]*ldw3 + kt_*64 + ssl*8,
                        (void*)&lds[buf_][1][c*512]);
        }
    };

    stage(0, 0);
    __syncthreads();

    for (int kt = 0; kt < nk; ++kt) {
        int cur = kt & 1;
        if (kt + 1 < nk) stage(cur ^ 1, kt + 1);
        #pragma unroll
        for (int kk = 0; kk < 2; ++kk) {
            s16x8 av[4], wv[4];
            #pragma unroll
            for (int mi = 0; mi < 4; ++mi) {
                int row = wr*64 + mi*16 + rl;
                int ck = (kk*4 + kq) ^ (row & 7);
                av[mi] = *(const s16x8*)&lds[cur][0][row*64 + (ck<<3)];
            }
            #pragma unroll
            for (int ni = 0; ni < 4; ++ni) {
                int row = wc*64 + ni*16 + rl;
                int ck = (kk*4 + kq) ^ (row & 7);
                wv[ni] = *(const s16x8*)&lds[cur][1][row*64 + (ck<<3)];
            }
            #pragma unroll
            for (int mi = 0; mi < 4; ++mi)
                #pragma unroll
                for (int ni = 0; ni < 4; ++ni)
                    acc[mi][ni] = __builtin_amdgcn_mfma_f32_16x16x32_bf16(
                        av[mi], wv[ni], acc[mi][ni], 0, 0, 0);
        }
        __syncthreads();
    }

    #pragma unroll
    for (int ni = 0; ni < 4; ++ni) {
        int n = n0 + wc*64 + ni*16 + rl;
        if (n >= Nn) continue;
        float bv = (HAS_BIAS && !SCANEP) ? bias[n] : 0.f;
        #pragma unroll
        for (int mi = 0; mi < 4; ++mi) {
            #pragma unroll
            for (int j = 0; j < 4; ++j) {
                int m = m0 + wr*64 + mi*16 + kq*4 + j;
                if (m >= M) continue;
                float v = acc[mi][ni][j];
                if (SCANEP) {
                    if (n < 512) {
                        v += bias[n];
                        v = fmaxf(v, 0.f) + log1pf(__expf(-fabsf(v)));
                        C[(size_t)m*ldc + n] = v;
                    } else {
                        bcbuf[(size_t)m*32 + (n - 512)] = v;
                    }
                } else {
                    if (HAS_BIAS) v += bv;
                    if (RELU) v = fmaxf(v, 0.f);
                    if (WF32) C[(size_t)m*ldc + n] = v;
                    if (W3)   pack_act(C3 + (size_t)m*(2*N_out), n, N_out, v);
                }
            }
        }
    }
}

// ---------------------------------------------------------------------------
// conv + SiLU (fp32 xc + packed xc2), in-place silu on z-half of xz
// ---------------------------------------------------------------------------
__global__ __launch_bounds__(256)
void conv_silu(float* __restrict__ xz, const float* __restrict__ cw,
               const float* __restrict__ cb, float* __restrict__ xc,
               ushort* __restrict__ xc2, int rev)
{
    int idx = blockIdx.x * 256 + threadIdx.x;
    int d  = idx & (DD-1);
    int bt = idx >> 9;
    int t  = bt % TT;
    float cur = xz[(size_t)bt*2*DD + d];
    int tn = rev ? t + 1 : t - 1;
    float prev = 0.f;
    if (tn >= 0 && tn < TT)
        prev = xz[((size_t)bt + (rev ? 1 : -1))*2*DD + d];
    float v = prev*cw[d*2] + cur*cw[d*2+1] + cb[d];
    float sv = v / (1.f + __expf(-v));
    xc[idx] = sv;
    pack_act(xc2 + (size_t)bt*1024, d, 512, sv);
    float z = xz[(size_t)bt*2*DD + DD + d];
    xz[(size_t)bt*2*DD + DD + d] = z / (1.f + __expf(-z));
}

// ---------------------------------------------------------------------------
// Chunked scan, pass 1: per-chunk local scan + decay product (no output).
// grid (256, NCHK-1), block 256 = 64d x 4sg. All t in-range for c < NCHK-1.
// ---------------------------------------------------------------------------
__global__ __launch_bounds__(256)
void scan_p1(const float* __restrict__ sp_g, const float* __restrict__ xc_g,
             const float* __restrict__ bc_g, const float* __restrict__ alog,
             float* __restrict__ hs, float* __restrict__ ps, int rev)
{
    int sblk = blockIdx.x;
    int c    = blockIdx.y;
    int b  = sblk >> 3;
    int d0 = (sblk & 7) << 6;
    int tid = threadIdx.x;
    int sg = tid & 3;
    int dl = tid >> 2;
    int d  = d0 + dl;

    float Ac[4];
    #pragma unroll
    for (int j = 0; j < 4; ++j)
        Ac[j] = -__expf(alog[d*SS + sg*4 + j]);
    float h0=0.f,h1=0.f,h2=0.f,h3=0.f;
    float p0=1.f,p1=1.f,p2=1.f,p3=1.f;
    size_t bbase = (size_t)b*TT;
    int t0 = c*CSZ;
    #pragma unroll 3
    for (int i = 0; i < CSZ; ++i) {
        int t = t0 + i;
        size_t p = bbase + (rev ? TT-1-t : t);
        float spv = sp_g[p*DD + d];
        float xcv = xc_g[p*DD + d];
        float4 Bv = *(const float4*)(bc_g + p*32 + sg*4);
        float dtxc = spv*xcv;
        float e0 = __expf(spv*Ac[0]);
        float e1 = __expf(spv*Ac[1]);
        float e2 = __expf(spv*Ac[2]);
        float e3 = __expf(spv*Ac[3]);
        h0 = fmaf(e0,h0,dtxc*Bv.x); p0 *= e0;
        h1 = fmaf(e1,h1,dtxc*Bv.y); p1 *= e1;
        h2 = fmaf(e2,h2,dtxc*Bv.z); p2 *= e2;
        h3 = fmaf(e3,h3,dtxc*Bv.w); p3 *= e3;
    }
    size_t o = ((size_t)c*256 + sblk)*256 + tid;
    float4 hv; hv.x=h0; hv.y=h1; hv.z=h2; hv.w=h3;
    float4 pv; pv.x=p0; pv.y=p1; pv.z=p2; pv.w=p3;
    ((float4*)hs)[o] = hv;
    ((float4*)ps)[o] = pv;
}

// ---------------------------------------------------------------------------
// Chunked scan, combine: prefix over chunks (elementwise, diagonal transfer).
// ---------------------------------------------------------------------------
__global__ __launch_bounds__(256)
void scan_comb(const float* __restrict__ hs, const float* __restrict__ ps,
               float* __restrict__ hin)
{
    size_t gid = (size_t)blockIdx.x*256 + threadIdx.x;   // 65536
    float4 h = {0.f,0.f,0.f,0.f};
    for (int c = 0; c < NCHK-1; ++c) {
        size_t o = (size_t)c*65536 + gid;
        float4 hl = ((const float4*)hs)[o];
        float4 pv = ((const float4*)ps)[o];
        h.x = fmaf(pv.x, h.x, hl.x);
        h.y = fmaf(pv.y, h.y, hl.y);
        h.z = fmaf(pv.z, h.z, hl.z);
        h.w = fmaf(pv.w, h.w, hl.w);
        ((float4*)hin)[o] = h;
    }
}

// ---------------------------------------------------------------------------
// Chunked scan, pass 2: replay chunk with known h_in, emit y. grid (256,NCHK).
// ---------------------------------------------------------------------------
__global__ __launch_bounds__(256)
void scan_p2(const float* __restrict__ sp_g, const float* __restrict__ xc_g,
             const float* __restrict__ xz_g, const float* __restrict__ bc_g,
             const float* __restrict__ alog, const float* __restrict__ dparam,
             const float* __restrict__ hin, ushort* __restrict__ y2, int rev)
{
    int sblk = blockIdx.x;
    int c    = blockIdx.y;
    int b  = sblk >> 3;
    int d0 = (sblk & 7) << 6;
    int tid = threadIdx.x;
    int sg = tid & 3;
    int dl = tid >> 2;
    int d  = d0 + dl;

    float Ac[4];
    #pragma unroll
    for (int j = 0; j < 4; ++j)
        Ac[j] = -__expf(alog[d*SS + sg*4 + j]);
    float dp = dparam[d];
    float h0=0.f,h1=0.f,h2=0.f,h3=0.f;
    if (c > 0) {
        float4 hv = ((const float4*)hin)[((size_t)(c-1)*256 + sblk)*256 + tid];
        h0=hv.x; h1=hv.y; h2=hv.z; h3=hv.w;
    }
    size_t bbase = (size_t)b*TT;
    int t0 = c*CSZ;
    #pragma unroll 3
    for (int i = 0; i < CSZ; ++i) {
        int t = t0 + i;
        int tc = t < TT ? t : TT-1;
        size_t p = bbase + (rev ? TT-1-tc : tc);
        float spv = sp_g[p*DD + d];
        float xcv = xc_g[p*DD + d];
        float zsv = xz_g[p*2*DD + DD + d];
        float4 Bv = *(const float4*)(bc_g + p*32 + sg*4);
        float4 Cv = *(const float4*)(bc_g + p*32 + 16 + sg*4);
        float dtxc = spv*xcv;
        float e0 = __expf(spv*Ac[0]);
        float e1 = __expf(spv*Ac[1]);
        float e2 = __expf(spv*Ac[2]);
        float e3 = __expf(spv*Ac[3]);
        h0 = fmaf(e0,h0,dtxc*Bv.x);
        h1 = fmaf(e1,h1,dtxc*Bv.y);
        h2 = fmaf(e2,h2,dtxc*Bv.z);
        h3 = fmaf(e3,h3,dtxc*Bv.w);
        float dot = h0*Cv.x + h1*Cv.y + h2*Cv.z + h3*Cv.w;
        dot += __shfl_xor(dot, 1);
        dot += __shfl_xor(dot, 2);
        if (sg == 0 && t < TT) {
            int tg = rev ? TT-1-t : t;
            float yv = (dot + dp*xcv) * zsv;
            pack_act(y2 + (bbase + tg)*1024, d, 512, yv);
        }
    }
}

// ---------------------------------------------------------------------------
// LayerNorm (up to 3 summed inputs), optional 2K-pack output
// ---------------------------------------------------------------------------
__global__ __launch_bounds__(64)
void ln_kernel(float* __restrict__ dst, const float* __restrict__ a,
               const float* __restrict__ b, const float* __restrict__ c,
               const float* __restrict__ g, const float* __restrict__ beta,
               ushort* __restrict__ out2)
{
    int row = blockIdx.x;
    int lane = threadIdx.x;
    size_t base = (size_t)row * DD;
    float x[8];
    #pragma unroll
    for (int j = 0; j < 2; ++j) {
        int e4 = j*64 + lane;
        float4 v = *(const float4*)(a + base + (size_t)e4*4);
        if (b) { float4 t = *(const float4*)(b + base + (size_t)e4*4); v.x+=t.x; v.y+=t.y; v.z+=t.z; v.w+=t.w; }
        if (c) { float4 t = *(const float4*)(c + base + (size_t)e4*4); v.x+=t.x; v.y+=t.y; v.z+=t.z; v.w+=t.w; }
        x[j*4+0]=v.x; x[j*4+1]=v.y; x[j*4+2]=v.z; x[j*4+3]=v.w;
    }
    float s = 0.f;
    #pragma unroll
    for (int i = 0; i < 8; ++i) s += x[i];
    #pragma unroll
    for (int m = 1; m < 64; m <<= 1) s += __shfl_xor(s, m);
    float mu = s * (1.f/DD);
    float vs = 0.f;
    #pragma unroll
    for (int i = 0; i < 8; ++i) { float dd = x[i]-mu; vs += dd*dd; }
    #pragma unroll
    for (int m = 1; m < 64; m <<= 1) vs += __shfl_xor(vs, m);
    float r = rsqrtf(vs*(1.f/DD) + 1e-5f);
    #pragma unroll
    for (int j = 0; j < 2; ++j) {
        int e4 = j*64 + lane;
        float4 gv = *(const float4*)(g    + (size_t)e4*4);
        float4 bv = *(const float4*)(beta + (size_t)e4*4);
        float4 o;
        o.x = (x[j*4+0]-mu)*r*gv.x + bv.x;
        o.y = (x[j*4+1]-mu)*r*gv.y + bv.y;
        o.z = (x[j*4+2]-mu)*r*gv.z + bv.z;
        o.w = (x[j*4+3]-mu)*r*gv.w + bv.w;
        *(float4*)(dst + base + (size_t)e4*4) = o;
        if (out2) {
            ushort* ob = out2 + (size_t)row*1024;
            pack_act(ob, e4*4+0, 512, o.x);
            pack_act(ob, e4*4+1, 512, o.y);
            pack_act(ob, e4*4+2, 512, o.z);
            pack_act(ob, e4*4+3, 512, o.w);
        }
    }
}

// ---------------------------------------------------------------------------
// projection + transpose + de-norm
// ---------------------------------------------------------------------------
__global__ __launch_bounds__(128)
void proj_kernel(const float* __restrict__ hf, const float* __restrict__ pw,
                 const float* __restrict__ pb, const float* __restrict__ mean,
                 const float* __restrict__ stdv, float* __restrict__ out)
{
    int b  = blockIdx.x >> 5;
    int n0 = (blockIdx.x & 31) << 3;
    __shared__ float rows[8][DD];
    for (int i = threadIdx.x; i < 8*128; i += 128) {
        int rj = i >> 7, c4 = i & 127;
        ((float4*)rows[rj])[c4] =
            *(const float4*)(hf + ((size_t)b*TT + n0 + rj)*DD + (size_t)c4*4);
    }
    __syncthreads();
    int p = threadIdx.x;
    if (p < PRED) {
        float acc[8];
        #pragma unroll
        for (int j = 0; j < 8; ++j) acc[j] = 0.f;
        for (int k4 = 0; k4 < 128; ++k4) {
            float4 w = *(const float4*)(pw + (size_t)p*DD + (size_t)k4*4);
            #pragma unroll
            for (int j = 0; j < 8; ++j) {
                float4 rv = ((const float4*)rows[j])[k4];
                acc[j] += w.x*rv.x + w.y*rv.y + w.z*rv.z + w.w*rv.w;
            }
        }
        float bias = pb[p];
        #pragma unroll
        for (int j = 0; j < 8; ++j) {
            int n = n0 + j;
            out[((size_t)b*PRED + p)*NV + n] =
                (acc[j] + bias)*stdv[b*NV + n] + mean[b*NV + n];
        }
    }
}

// ---------------------------------------------------------------------------
extern "C" void kernel_launch(void* const* d_in, const int* in_sizes, int n_in,
                              void* d_out, int out_size, void* d_ws, size_t ws_size,
                              hipStream_t stream)
{
    (void)in_sizes; (void)n_in; (void)out_size; (void)ws_size;
    const float* x_enc   = (const float*)d_in[0];
    const float* x_mark  = (const float*)d_in[1];
    const float* emb_w   = (const float*)d_in[2];
    const float* emb_b   = (const float*)d_in[3];
    const float* m_win   = (const float*)d_in[4];
    const float* m_convw = (const float*)d_in[5];
    const float* m_convb = (const float*)d_in[6];
    const float* m_wx    = (const float*)d_in[7];
    const float* m_wdt   = (const float*)d_in[8];
    const float* m_bdt   = (const float*)d_in[9];
    const float* m_alog  = (const float*)d_in[10];
    const float* m_dpar  = (const float*)d_in[11];
    const float* m_wout  = (const float*)d_in[12];
    const float* ln1_g   = (const float*)d_in[13];
    const float* ln1_b   = (const float*)d_in[14];
    const float* ff1_w   = (const float*)d_in[15];
    const float* ff1_b   = (const float*)d_in[16];
    const float* ff2_w   = (const float*)d_in[17];
    const float* ff2_b   = (const float*)d_in[18];
    const float* ln2_g   = (const float*)d_in[19];
    const float* ln2_b   = (const float*)d_in[20];
    const float* lnf_g   = (const float*)d_in[21];
    const float* lnf_b   = (const float*)d_in[22];
    const float* proj_w  = (const float*)d_in[23];
    const float* proj_b  = (const float*)d_in[24];
    float* out = (float*)d_out;

    float* ws = (float*)d_ws;
    const size_t NBT = (size_t)MROWS;
    size_t off = 0;
    float* mean = ws + off; off += 8192;
    float* stdv = ws + off; off += 8192;
    ushort* w_emb2  = (ushort*)(ws + off); off += 393216;
    ushort* w_win2  = (ushort*)(ws + off); off += 3145728;
    ushort* w_wout2 = (ushort*)(ws + off); off += 1572864;
    ushort* w_ff12  = (ushort*)(ws + off); off += 786432;
    ushort* w_ff22  = (ushort*)(ws + off); off += 786432;
    ushort* w_comb2 = (ushort*)(ws + off); off += 1671168;
    ushort* tok2 = (ushort*)(ws + off); off += NBT*768;      // aliased: xc2, y2
    ushort* xc2 = tok2;
    ushort* y2  = tok2;
    float* h   = ws + off; off += NBT*DD;
    ushort* h2 = (ushort*)(ws + off); off += NBT*768;
    float* xz  = ws + off; off += NBT*2*DD;
    ushort* fft2 = (ushort*)xz;                              // alias
    float* xc  = ws + off; off += NBT*DD;
    float* bc  = ws + off; off += NBT*32;
    float* sp  = ws + off; off += NBT*DD;
    float* fbuf = ws + off; off += NBT*DD;
    float* rbuf = ws + off; off += NBT*DD;
    float* hs  = ws + off; off += (NCHK-1)*65536*4;          // 1.84M f
    float* psb = ws + off; off += (NCHK-1)*65536*4;
    float* hin = ws + off; off += (NCHK-1)*65536*4;

    // ---- weight packing ----
    pack2w<<<dim3((512*512+255)/256),  256, 0, stream>>>(emb_w, w_emb2, 512*512);
    pack2w<<<dim3((4096*512+255)/256), 256, 0, stream>>>(m_win, w_win2, 4096*512);
    pack2w<<<dim3((2048*512+255)/256), 256, 0, stream>>>(m_wout, w_wout2, 2048*512);
    pack2w<<<dim3((1024*512+255)/256), 256, 0, stream>>>(ff1_w, w_ff12, 1024*512);
    pack2w<<<dim3((1024*512+255)/256), 256, 0, stream>>>(ff2_w, w_ff22, 1024*512);
    mkcomb<<<dim3(544,4), 256, 0, stream>>>(m_wx, m_wdt, w_comb2);

    stats_kernel<<<dim3(BB*16), 256, 0, stream>>>(x_enc, mean, stdv);
    tok_kernel<<<dim3(BB*40), 256, 0, stream>>>(x_enc, x_mark, mean, stdv, tok2);

    gemm3<1,0,1,1,0><<<dim3(66*4), 256, 0, stream>>>(tok2, 1024, w_emb2, 1024,
        emb_b, h, DD, h2, DD, nullptr, MROWS, 512, 1024);

    for (int l = 0; l < 2; ++l) {
        for (int dir = 0; dir < 2; ++dir) {
            int li = l*2 + dir;
            gemm3<0,0,1,0,0><<<dim3(66*8), 256, 0, stream>>>(h2, 1024,
                w_win2 + (size_t)li*1024*1024, 1024, nullptr,
                xz, 2*DD, nullptr, 0, nullptr, MROWS, 1024, 1024);
            conv_silu<<<dim3((MROWS*DD)/256), 256, 0, stream>>>(
                xz, m_convw + (size_t)li*DD*2, m_convb + (size_t)li*DD,
                xc, xc2, dir);
            gemm3<0,0,0,0,1><<<dim3(66*5), 256, 0, stream>>>(xc2, 1024,
                w_comb2 + (size_t)li*544*1024, 1024, m_bdt + (size_t)li*DD,
                sp, 512, nullptr, 0, bc, MROWS, 544, 1024);
            const float* al = m_alog + (size_t)li*DD*SS;
            const float* dpp = m_dpar + (size_t)li*DD;
            scan_p1<<<dim3(256, NCHK-1), 256, 0, stream>>>(sp, xc, bc, al,
                hs, psb, dir);
            scan_comb<<<dim3(256), 256, 0, stream>>>(hs, psb, hin);
            scan_p2<<<dim3(256, NCHK), 256, 0, stream>>>(sp, xc, xz, bc, al,
                dpp, hin, y2, dir);
            gemm3<0,0,1,0,0><<<dim3(66*4), 256, 0, stream>>>(y2, 1024,
                w_wout2 + (size_t)li*512*1024, 1024, nullptr,
                (dir == 0) ? fbuf : rbuf, DD, nullptr, 0, nullptr,
                MROWS, 512, 1024);
        }
        ln_kernel<<<dim3(MROWS), 64, 0, stream>>>(h, h, fbuf, rbuf,
            ln1_g + l*DD, ln1_b + l*DD, h2);
        gemm3<1,1,0,1,0><<<dim3(66*4), 256, 0, stream>>>(h2, 1024,
            w_ff12 + (size_t)l*512*1024, 1024, ff1_b + l*DD,
            nullptr, 0, fft2, DD, nullptr, MROWS, 512, 1024);
        gemm3<1,0,1,0,0><<<dim3(66*4), 256, 0, stream>>>(fft2, 1024,
            w_ff22 + (size_t)l*512*1024, 1024, ff2_b + l*DD,
            xc, DD, nullptr, 0, nullptr, MROWS, 512, 1024);
        ln_kernel<<<dim3(MROWS), 64, 0, stream>>>(h, h, xc, nullptr,
            ln2_g + l*DD, ln2_b + l*DD, h2);
    }
    ln_kernel<<<dim3(MROWS), 64, 0, stream>>>(fbuf, h, nullptr, nullptr,
                                              lnf_g, lnf_b, nullptr);
    proj_kernel<<<dim3(BB*32), 128, 0, stream>>>(fbuf, proj_w, proj_b, mean, stdv, out);
}

// Round 18
// 839.145 us; speedup vs baseline: 1.6740x; 1.2098x over previous
//
#include <hip/hip_runtime.h>
#include <hip/hip_bf16.h>
#include <math.h>
#include <stddef.h>

#define BB 32
#define TT 262
#define DD 512
#define SS 16
#define RR 32
#define SEQ 512
#define NV 256
#define PRED 96
#define MROWS (BB*TT)   // 8384
#define NCHK 8
#define CSZ 33          // 8*33 = 264 >= 262

typedef __attribute__((ext_vector_type(4))) float f32x4;
typedef __attribute__((ext_vector_type(8))) short s16x8;

// ---------------- bf16 helpers ----------------
__device__ inline ushort f2bu(float x) {
    __hip_bfloat16 h = __float2bfloat16(x);
    ushort u; __builtin_memcpy(&u, &h, 2); return u;
}
__device__ inline float bu2f(ushort u) {
    __hip_bfloat16 h; __builtin_memcpy(&h, &u, 2);
    return __bfloat162float(h);
}

// async global->LDS, 16B per lane
__device__ inline void gload_lds16(const void* g, void* l) {
    __builtin_amdgcn_global_load_lds(
        (const __attribute__((address_space(1))) void*)g,
        (__attribute__((address_space(3))) void*)l, 16, 0, 0);
}

// ---------------------------------------------------------------------------
// weight bf16 cast (row-major, any size)
// ---------------------------------------------------------------------------
__global__ __launch_bounds__(256)
void packw(const float* __restrict__ in, ushort* __restrict__ out, int total)
{
    int idx = blockIdx.x * 256 + threadIdx.x;
    if (idx >= total) return;
    out[idx] = f2bu(in[idx]);
}

// ---------------------------------------------------------------------------
// combined scan-projection weight (dt path folded through wdt), bf16
// ---------------------------------------------------------------------------
__global__ __launch_bounds__(256)
void mkcomb(const float* __restrict__ wx, const float* __restrict__ wdt,
            ushort* __restrict__ comb)
{
    int n  = blockIdx.x;
    int li = blockIdx.y;
    const float* wxl = wx + (size_t)li*64*512;
    ushort* outb = comb + ((size_t)li*544 + n)*512;
    if (n < 512) {
        __shared__ float wr[32];
        if (threadIdx.x < 32)
            wr[threadIdx.x] = wdt[(size_t)li*512*32 + (size_t)n*32 + threadIdx.x];
        __syncthreads();
        for (int kk = threadIdx.x; kk < 512; kk += 256) {
            float acc = 0.f;
            #pragma unroll
            for (int r = 0; r < 32; ++r)
                acc = fmaf(wr[r], wxl[r*512 + kk], acc);
            outb[kk] = f2bu(acc);
        }
    } else {
        int s = n - 512;
        for (int kk = threadIdx.x; kk < 512; kk += 256)
            outb[kk] = f2bu(wxl[(32+s)*512 + kk]);
    }
}

// ---------------------------------------------------------------------------
// per-(b,n) mean/std over SEQ. grid = BB*16, block 256 = 16n x 16tg.
// ---------------------------------------------------------------------------
__global__ __launch_bounds__(256)
void stats_kernel(const float* __restrict__ x_enc,
                  float* __restrict__ mean, float* __restrict__ stdv)
{
    int b  = blockIdx.x >> 4;
    int n0 = (blockIdx.x & 15) << 4;
    int nl = threadIdx.x & 15;
    int tg = threadIdx.x >> 4;
    int n = n0 + nl;
    const float* base = x_enc + (size_t)b*SEQ*NV + n;
    float s0 = 0.f, s1 = 0.f, q0 = 0.f, q1 = 0.f;
    #pragma unroll 8
    for (int i = 0; i < 16; ++i) {
        int t = tg + i*32;
        float v0 = base[(size_t)t*NV];
        float v1 = base[(size_t)(t+16)*NV];
        s0 += v0; q0 = fmaf(v0, v0, q0);
        s1 += v1; q1 = fmaf(v1, v1, q1);
    }
    float s = s0 + s1, q = q0 + q1;
    __shared__ float ls[16][17], lq[16][17];
    ls[tg][nl] = s; lq[tg][nl] = q;
    __syncthreads();
    if (tg < 8) { ls[tg][nl] += ls[tg+8][nl]; lq[tg][nl] += lq[tg+8][nl]; }
    __syncthreads();
    if (tg < 4) { ls[tg][nl] += ls[tg+4][nl]; lq[tg][nl] += lq[tg+4][nl]; }
    __syncthreads();
    if (tg < 2) { ls[tg][nl] += ls[tg+2][nl]; lq[tg][nl] += lq[tg+2][nl]; }
    __syncthreads();
    if (tg == 0) {
        s = ls[0][nl] + ls[1][nl];
        q = lq[0][nl] + lq[1][nl];
        float mu  = s * (1.f/SEQ);
        float var = q * (1.f/SEQ) - mu*mu;
        mean[b*NV + n] = mu;
        stdv[b*NV + n] = sqrtf(var + 1e-5f);
    }
}

// ---------------------------------------------------------------------------
// tok: normalized transpose, bf16 rows of 512
// ---------------------------------------------------------------------------
__global__ __launch_bounds__(256)
void tok_kernel(const float* __restrict__ x_enc, const float* __restrict__ x_mark,
                const float* __restrict__ mean, const float* __restrict__ stdv,
                ushort* __restrict__ tokb)
{
    int b  = blockIdx.x / 40;
    int r  = blockIdx.x % 40;
    int tt = r / 5;
    int vt = r % 5;
    int t0 = tt << 6, v0 = vt << 6;
    __shared__ float tile[64][65];
    int lv = threadIdx.x & 63;
    for (int i = threadIdx.x >> 6; i < 64; i += 4) {
        int t = t0 + i, v = v0 + lv;
        float val = 0.f;
        if (v < NV) {
            val = (x_enc[((size_t)b*SEQ + t)*NV + v] - mean[b*NV + v]) / stdv[b*NV + v];
        } else if (v < TT) {
            val = x_mark[((size_t)b*SEQ + t)*6 + (v - NV)];
        }
        tile[i][lv] = val;
    }
    __syncthreads();
    for (int i = threadIdx.x >> 6; i < 64; i += 4) {
        int v = v0 + i;
        if (v < TT) {
            size_t row = (size_t)b*TT + v;
            tokb[row*512 + t0 + lv] = f2bu(tile[lv][i]);
        }
    }
}

// ---------------------------------------------------------------------------
// bf16 MFMA GEMM (NT; K multiple of 64). 1D grid, n-fast tile order inside
// bijective XCD swizzle: consecutive swz share the A m-panel -> same-XCD L2.
// ---------------------------------------------------------------------------
template<int HAS_BIAS, int RELU, int WF32, int W3, int SCANEP>
__global__ __launch_bounds__(256)
void gemm3(const ushort* __restrict__ A3, int lda3,
           const ushort* __restrict__ W3p, int ldw3,
           const float* __restrict__ bias,
           float* __restrict__ C, int ldc,
           ushort* __restrict__ C3, int N_out,
           float* __restrict__ bcbuf,
           int M, int Nn, int K3)
{
    __shared__ ushort lds[2][2][128*64];   // [buf][A=0/W=1] : 64 KB
    const int tid  = threadIdx.x;
    const int lane = tid & 63;
    const int wid  = tid >> 6;
    const int wr = wid >> 1, wc = wid & 1;

    // bijective XCD swizzle (m204), then n-fast tile decode
    int nwg = gridDim.x;
    int q8 = nwg >> 3, r8 = nwg & 7;
    int xcd = blockIdx.x & 7;
    int idx = blockIdx.x >> 3;
    int swz = (xcd < r8 ? xcd*(q8+1) : r8*(q8+1) + (xcd-r8)*q8) + idx;
    int ntile = (Nn + 127) >> 7;
    const int m0 = (swz / ntile) * 128;
    const int n0 = (swz % ntile) * 128;

    const int l8 = lane >> 3;
    const int sl = lane & 7;
    const int ssl = sl ^ l8;

    int arow[4], wrow[4];
    #pragma unroll
    for (int qq = 0; qq < 4; ++qq) {
        int r = (wid*4 + qq)*8 + l8;
        int ar = m0 + r; if (ar > M-1) ar = M-1;
        arow[qq] = ar;
        int wrr = n0 + r; if (wrr > Nn-1) wrr = Nn-1;
        wrow[qq] = wrr;
    }

    f32x4 acc[4][4];
    #pragma unroll
    for (int i = 0; i < 4; ++i)
        #pragma unroll
        for (int j = 0; j < 4; ++j) acc[i][j] = (f32x4){0.f,0.f,0.f,0.f};

    const int nk = K3 >> 6;
    const int rl = lane & 15;
    const int kq = lane >> 4;

    auto stage = [&](int buf_, int kt_) {
        #pragma unroll
        for (int qq = 0; qq < 4; ++qq) {
            int c = wid*4 + qq;
            gload_lds16(A3 + (size_t)arow[qq]*lda3 + kt_*64 + ssl*8,
                        (void*)&lds[buf_][0][c*512]);
            gload_lds16(W3p + (size_t)wrow[qq]*ldw3 + kt_*64 + ssl*8,
                        (void*)&lds[buf_][1][c*512]);
        }
    };

    stage(0, 0);
    __syncthreads();

    for (int kt = 0; kt < nk; ++kt) {
        int cur = kt & 1;
        if (kt + 1 < nk) stage(cur ^ 1, kt + 1);
        #pragma unroll
        for (int kk = 0; kk < 2; ++kk) {
            s16x8 av[4], wv[4];
            #pragma unroll
            for (int mi = 0; mi < 4; ++mi) {
                int row = wr*64 + mi*16 + rl;
                int ck = (kk*4 + kq) ^ (row & 7);
                av[mi] = *(const s16x8*)&lds[cur][0][row*64 + (ck<<3)];
            }
            #pragma unroll
            for (int ni = 0; ni < 4; ++ni) {
                int row = wc*64 + ni*16 + rl;
                int ck = (kk*4 + kq) ^ (row & 7);
                wv[ni] = *(const s16x8*)&lds[cur][1][row*64 + (ck<<3)];
            }
            #pragma unroll
            for (int mi = 0; mi < 4; ++mi)
                #pragma unroll
                for (int ni = 0; ni < 4; ++ni)
                    acc[mi][ni] = __builtin_amdgcn_mfma_f32_16x16x32_bf16(
                        av[mi], wv[ni], acc[mi][ni], 0, 0, 0);
        }
        __syncthreads();
    }

    #pragma unroll
    for (int ni = 0; ni < 4; ++ni) {
        int n = n0 + wc*64 + ni*16 + rl;
        if (n >= Nn) continue;
        float bv = (HAS_BIAS && !SCANEP) ? bias[n] : 0.f;
        #pragma unroll
        for (int mi = 0; mi < 4; ++mi) {
            #pragma unroll
            for (int j = 0; j < 4; ++j) {
                int m = m0 + wr*64 + mi*16 + kq*4 + j;
                if (m >= M) continue;
                float v = acc[mi][ni][j];
                if (SCANEP) {
                    if (n < 512) {
                        v += bias[n];
                        v = fmaxf(v, 0.f) + log1pf(__expf(-fabsf(v)));
                        C[(size_t)m*ldc + n] = v;
                    } else {
                        bcbuf[(size_t)m*32 + (n - 512)] = v;
                    }
                } else {
                    if (HAS_BIAS) v += bv;
                    if (RELU) v = fmaxf(v, 0.f);
                    if (WF32) C[(size_t)m*ldc + n] = v;
                    if (W3)   C3[(size_t)m*N_out + n] = f2bu(v);
                }
            }
        }
    }
}

// ---------------------------------------------------------------------------
// conv + SiLU (fp32 xc + bf16 xcb), in-place silu on z-half of xz
// ---------------------------------------------------------------------------
__global__ __launch_bounds__(256)
void conv_silu(float* __restrict__ xz, const float* __restrict__ cw,
               const float* __restrict__ cb, float* __restrict__ xc,
               ushort* __restrict__ xcb, int rev)
{
    int idx = blockIdx.x * 256 + threadIdx.x;
    int d  = idx & (DD-1);
    int bt = idx >> 9;
    int t  = bt % TT;
    float cur = xz[(size_t)bt*2*DD + d];
    int tn = rev ? t + 1 : t - 1;
    float prev = 0.f;
    if (tn >= 0 && tn < TT)
        prev = xz[((size_t)bt + (rev ? 1 : -1))*2*DD + d];
    float v = prev*cw[d*2] + cur*cw[d*2+1] + cb[d];
    float sv = v / (1.f + __expf(-v));
    xc[idx] = sv;
    xcb[(size_t)bt*512 + d] = f2bu(sv);
    float z = xz[(size_t)bt*2*DD + DD + d];
    xz[(size_t)bt*2*DD + DD + d] = z / (1.f + __expf(-z));
}

// ---------------------------------------------------------------------------
// Chunked scan, pass 1: per-chunk local scan + decay product (no output).
// grid (256, NCHK-1), block 256 = 64d x 4sg.
// ---------------------------------------------------------------------------
__global__ __launch_bounds__(256)
void scan_p1(const float* __restrict__ sp_g, const float* __restrict__ xc_g,
             const float* __restrict__ bc_g, const float* __restrict__ alog,
             float* __restrict__ hs, float* __restrict__ ps, int rev)
{
    int sblk = blockIdx.x;
    int c    = blockIdx.y;
    int b  = sblk >> 3;
    int d0 = (sblk & 7) << 6;
    int tid = threadIdx.x;
    int sg = tid & 3;
    int dl = tid >> 2;
    int d  = d0 + dl;

    float Ac[4];
    #pragma unroll
    for (int j = 0; j < 4; ++j)
        Ac[j] = -__expf(alog[d*SS + sg*4 + j]);
    float h0=0.f,h1=0.f,h2=0.f,h3=0.f;
    float p0=1.f,p1=1.f,p2=1.f,p3=1.f;
    size_t bbase = (size_t)b*TT;
    int t0 = c*CSZ;
    #pragma unroll 3
    for (int i = 0; i < CSZ; ++i) {
        int t = t0 + i;
        size_t p = bbase + (rev ? TT-1-t : t);
        float spv = sp_g[p*DD + d];
        float xcv = xc_g[p*DD + d];
        float4 Bv = *(const float4*)(bc_g + p*32 + sg*4);
        float dtxc = spv*xcv;
        float e0 = __expf(spv*Ac[0]);
        float e1 = __expf(spv*Ac[1]);
        float e2 = __expf(spv*Ac[2]);
        float e3 = __expf(spv*Ac[3]);
        h0 = fmaf(e0,h0,dtxc*Bv.x); p0 *= e0;
        h1 = fmaf(e1,h1,dtxc*Bv.y); p1 *= e1;
        h2 = fmaf(e2,h2,dtxc*Bv.z); p2 *= e2;
        h3 = fmaf(e3,h3,dtxc*Bv.w); p3 *= e3;
    }
    size_t o = ((size_t)c*256 + sblk)*256 + tid;
    float4 hv; hv.x=h0; hv.y=h1; hv.z=h2; hv.w=h3;
    float4 pv; pv.x=p0; pv.y=p1; pv.z=p2; pv.w=p3;
    ((float4*)hs)[o] = hv;
    ((float4*)ps)[o] = pv;
}

// ---------------------------------------------------------------------------
// Chunked scan, combine: prefix over chunks (elementwise, diagonal transfer).
// ---------------------------------------------------------------------------
__global__ __launch_bounds__(256)
void scan_comb(const float* __restrict__ hs, const float* __restrict__ ps,
               float* __restrict__ hin)
{
    size_t gid = (size_t)blockIdx.x*256 + threadIdx.x;   // 65536
    float4 h = {0.f,0.f,0.f,0.f};
    for (int c = 0; c < NCHK-1; ++c) {
        size_t o = (size_t)c*65536 + gid;
        float4 hl = ((const float4*)hs)[o];
        float4 pv = ((const float4*)ps)[o];
        h.x = fmaf(pv.x, h.x, hl.x);
        h.y = fmaf(pv.y, h.y, hl.y);
        h.z = fmaf(pv.z, h.z, hl.z);
        h.w = fmaf(pv.w, h.w, hl.w);
        ((float4*)hin)[o] = h;
    }
}

// ---------------------------------------------------------------------------
// Chunked scan, pass 2: replay chunk with known h_in, emit y (bf16).
// ---------------------------------------------------------------------------
__global__ __launch_bounds__(256)
void scan_p2(const float* __restrict__ sp_g, const float* __restrict__ xc_g,
             const float* __restrict__ xz_g, const float* __restrict__ bc_g,
             const float* __restrict__ alog, const float* __restrict__ dparam,
             const float* __restrict__ hin, ushort* __restrict__ yb, int rev)
{
    int sblk = blockIdx.x;
    int c    = blockIdx.y;
    int b  = sblk >> 3;
    int d0 = (sblk & 7) << 6;
    int tid = threadIdx.x;
    int sg = tid & 3;
    int dl = tid >> 2;
    int d  = d0 + dl;

    float Ac[4];
    #pragma unroll
    for (int j = 0; j < 4; ++j)
        Ac[j] = -__expf(alog[d*SS + sg*4 + j]);
    float dp = dparam[d];
    float h0=0.f,h1=0.f,h2=0.f,h3=0.f;
    if (c > 0) {
        float4 hv = ((const float4*)hin)[((size_t)(c-1)*256 + sblk)*256 + tid];
        h0=hv.x; h1=hv.y; h2=hv.z; h3=hv.w;
    }
    size_t bbase = (size_t)b*TT;
    int t0 = c*CSZ;
    #pragma unroll 3
    for (int i = 0; i < CSZ; ++i) {
        int t = t0 + i;
        int tc = t < TT ? t : TT-1;
        size_t p = bbase + (rev ? TT-1-tc : tc);
        float spv = sp_g[p*DD + d];
        float xcv = xc_g[p*DD + d];
        float zsv = xz_g[p*2*DD + DD + d];
        float4 Bv = *(const float4*)(bc_g + p*32 + sg*4);
        float4 Cv = *(const float4*)(bc_g + p*32 + 16 + sg*4);
        float dtxc = spv*xcv;
        float e0 = __expf(spv*Ac[0]);
        float e1 = __expf(spv*Ac[1]);
        float e2 = __expf(spv*Ac[2]);
        float e3 = __expf(spv*Ac[3]);
        h0 = fmaf(e0,h0,dtxc*Bv.x);
        h1 = fmaf(e1,h1,dtxc*Bv.y);
        h2 = fmaf(e2,h2,dtxc*Bv.z);
        h3 = fmaf(e3,h3,dtxc*Bv.w);
        float dot = h0*Cv.x + h1*Cv.y + h2*Cv.z + h3*Cv.w;
        dot += __shfl_xor(dot, 1);
        dot += __shfl_xor(dot, 2);
        if (sg == 0 && t < TT) {
            int tg = rev ? TT-1-t : t;
            float yv = (dot + dp*xcv) * zsv;
            yb[(bbase + tg)*512 + d] = f2bu(yv);
        }
    }
}

// ---------------------------------------------------------------------------
// LayerNorm (up to 3 summed inputs), optional bf16 output
// ---------------------------------------------------------------------------
__global__ __launch_bounds__(64)
void ln_kernel(float* __restrict__ dst, const float* __restrict__ a,
               const float* __restrict__ b, const float* __restrict__ c,
               const float* __restrict__ g, const float* __restrict__ beta,
               ushort* __restrict__ outb)
{
    int row = blockIdx.x;
    int lane = threadIdx.x;
    size_t base = (size_t)row * DD;
    float x[8];
    #pragma unroll
    for (int j = 0; j < 2; ++j) {
        int e4 = j*64 + lane;
        float4 v = *(const float4*)(a + base + (size_t)e4*4);
        if (b) { float4 t = *(const float4*)(b + base + (size_t)e4*4); v.x+=t.x; v.y+=t.y; v.z+=t.z; v.w+=t.w; }
        if (c) { float4 t = *(const float4*)(c + base + (size_t)e4*4); v.x+=t.x; v.y+=t.y; v.z+=t.z; v.w+=t.w; }
        x[j*4+0]=v.x; x[j*4+1]=v.y; x[j*4+2]=v.z; x[j*4+3]=v.w;
    }
    float s = 0.f;
    #pragma unroll
    for (int i = 0; i < 8; ++i) s += x[i];
    #pragma unroll
    for (int m = 1; m < 64; m <<= 1) s += __shfl_xor(s, m);
    float mu = s * (1.f/DD);
    float vs = 0.f;
    #pragma unroll
    for (int i = 0; i < 8; ++i) { float dd = x[i]-mu; vs += dd*dd; }
    #pragma unroll
    for (int m = 1; m < 64; m <<= 1) vs += __shfl_xor(vs, m);
    float r = rsqrtf(vs*(1.f/DD) + 1e-5f);
    #pragma unroll
    for (int j = 0; j < 2; ++j) {
        int e4 = j*64 + lane;
        float4 gv = *(const float4*)(g    + (size_t)e4*4);
        float4 bv = *(const float4*)(beta + (size_t)e4*4);
        float4 o;
        o.x = (x[j*4+0]-mu)*r*gv.x + bv.x;
        o.y = (x[j*4+1]-mu)*r*gv.y + bv.y;
        o.z = (x[j*4+2]-mu)*r*gv.z + bv.z;
        o.w = (x[j*4+3]-mu)*r*gv.w + bv.w;
        *(float4*)(dst + base + (size_t)e4*4) = o;
        if (outb) {
            ushort* ob = outb + (size_t)row*512;
            ob[e4*4+0] = f2bu(o.x);
            ob[e4*4+1] = f2bu(o.y);
            ob[e4*4+2] = f2bu(o.z);
            ob[e4*4+3] = f2bu(o.w);
        }
    }
}

// ---------------------------------------------------------------------------
// projection + transpose + de-norm
// ---------------------------------------------------------------------------
__global__ __launch_bounds__(128)
void proj_kernel(const float* __restrict__ hf, const float* __restrict__ pw,
                 const float* __restrict__ pb, const float* __restrict__ mean,
                 const float* __restrict__ stdv, float* __restrict__ out)
{
    int b  = blockIdx.x >> 5;
    int n0 = (blockIdx.x & 31) << 3;
    __shared__ float rows[8][DD];
    for (int i = threadIdx.x; i < 8*128; i += 128) {
        int rj = i >> 7, c4 = i & 127;
        ((float4*)rows[rj])[c4] =
            *(const float4*)(hf + ((size_t)b*TT + n0 + rj)*DD + (size_t)c4*4);
    }
    __syncthreads();
    int p = threadIdx.x;
    if (p < PRED) {
        float acc[8];
        #pragma unroll
        for (int j = 0; j < 8; ++j) acc[j] = 0.f;
        for (int k4 = 0; k4 < 128; ++k4) {
            float4 w = *(const float4*)(pw + (size_t)p*DD + (size_t)k4*4);
            #pragma unroll
            for (int j = 0; j < 8; ++j) {
                float4 rv = ((const float4*)rows[j])[k4];
                acc[j] += w.x*rv.x + w.y*rv.y + w.z*rv.z + w.w*rv.w;
            }
        }
        float bias = pb[p];
        #pragma unroll
        for (int j = 0; j < 8; ++j) {
            int n = n0 + j;
            out[((size_t)b*PRED + p)*NV + n] =
                (acc[j] + bias)*stdv[b*NV + n] + mean[b*NV + n];
        }
    }
}

// ---------------------------------------------------------------------------
extern "C" void kernel_launch(void* const* d_in, const int* in_sizes, int n_in,
                              void* d_out, int out_size, void* d_ws, size_t ws_size,
                              hipStream_t stream)
{
    (void)in_sizes; (void)n_in; (void)out_size; (void)ws_size;
    const float* x_enc   = (const float*)d_in[0];
    const float* x_mark  = (const float*)d_in[1];
    const float* emb_w   = (const float*)d_in[2];
    const float* emb_b   = (const float*)d_in[3];
    const float* m_win   = (const float*)d_in[4];
    const float* m_convw = (const float*)d_in[5];
    const float* m_convb = (const float*)d_in[6];
    const float* m_wx    = (const float*)d_in[7];
    const float* m_wdt   = (const float*)d_in[8];
    const float* m_bdt   = (const float*)d_in[9];
    const float* m_alog  = (const float*)d_in[10];
    const float* m_dpar  = (const float*)d_in[11];
    const float* m_wout  = (const float*)d_in[12];
    const float* ln1_g   = (const float*)d_in[13];
    const float* ln1_b   = (const float*)d_in[14];
    const float* ff1_w   = (const float*)d_in[15];
    const float* ff1_b   = (const float*)d_in[16];
    const float* ff2_w   = (const float*)d_in[17];
    const float* ff2_b   = (const float*)d_in[18];
    const float* ln2_g   = (const float*)d_in[19];
    const float* ln2_b   = (const float*)d_in[20];
    const float* lnf_g   = (const float*)d_in[21];
    const float* lnf_b   = (const float*)d_in[22];
    const float* proj_w  = (const float*)d_in[23];
    const float* proj_b  = (const float*)d_in[24];
    float* out = (float*)d_out;

    float* ws = (float*)d_ws;
    const size_t NBT = (size_t)MROWS;
    size_t off = 0;
    float* mean = ws + off; off += 8192;
    float* stdv = ws + off; off += 8192;
    ushort* w_emb  = (ushort*)(ws + off); off += 393216;
    ushort* w_win  = (ushort*)(ws + off); off += 3145728;
    ushort* w_wout = (ushort*)(ws + off); off += 1572864;
    ushort* w_ff1  = (ushort*)(ws + off); off += 786432;
    ushort* w_ff2  = (ushort*)(ws + off); off += 786432;
    ushort* w_comb = (ushort*)(ws + off); off += 1671168;
    ushort* tokb = (ushort*)(ws + off); off += NBT*768;      // aliased: xcb, yb
    ushort* xcb = tokb;
    ushort* yb  = tokb;
    float* h   = ws + off; off += NBT*DD;
    ushort* hb = (ushort*)(ws + off); off += NBT*768;
    float* xz  = ws + off; off += NBT*2*DD;
    ushort* fftb = (ushort*)xz;                              // alias
    float* xc  = ws + off; off += NBT*DD;
    float* bc  = ws + off; off += NBT*32;
    float* sp  = ws + off; off += NBT*DD;
    float* fbuf = ws + off; off += NBT*DD;
    float* rbuf = ws + off; off += NBT*DD;
    float* hs  = ws + off; off += (NCHK-1)*65536*4;
    float* psb = ws + off; off += (NCHK-1)*65536*4;
    float* hin = ws + off; off += (NCHK-1)*65536*4;

    // ---- weight packing (bf16 cast) ----
    packw<<<dim3((512*512+255)/256),  256, 0, stream>>>(emb_w, w_emb, 512*512);
    packw<<<dim3((4096*512+255)/256), 256, 0, stream>>>(m_win, w_win, 4096*512);
    packw<<<dim3((2048*512+255)/256), 256, 0, stream>>>(m_wout, w_wout, 2048*512);
    packw<<<dim3((1024*512+255)/256), 256, 0, stream>>>(ff1_w, w_ff1, 1024*512);
    packw<<<dim3((1024*512+255)/256), 256, 0, stream>>>(ff2_w, w_ff2, 1024*512);
    mkcomb<<<dim3(544,4), 256, 0, stream>>>(m_wx, m_wdt, w_comb);

    stats_kernel<<<dim3(BB*16), 256, 0, stream>>>(x_enc, mean, stdv);
    tok_kernel<<<dim3(BB*40), 256, 0, stream>>>(x_enc, x_mark, mean, stdv, tokb);

    gemm3<1,0,1,1,0><<<dim3(66*4), 256, 0, stream>>>(tokb, 512, w_emb, 512,
        emb_b, h, DD, hb, 512, nullptr, MROWS, 512, 512);

    for (int l = 0; l < 2; ++l) {
        for (int dir = 0; dir < 2; ++dir) {
            int li = l*2 + dir;
            gemm3<0,0,1,0,0><<<dim3(66*8), 256, 0, stream>>>(hb, 512,
                w_win + (size_t)li*1024*512, 512, nullptr,
                xz, 2*DD, nullptr, 0, nullptr, MROWS, 1024, 512);
            conv_silu<<<dim3((MROWS*DD)/256), 256, 0, stream>>>(
                xz, m_convw + (size_t)li*DD*2, m_convb + (size_t)li*DD,
                xc, xcb, dir);
            gemm3<0,0,0,0,1><<<dim3(66*5), 256, 0, stream>>>(xcb, 512,
                w_comb + (size_t)li*544*512, 512, m_bdt + (size_t)li*DD,
                sp, 512, nullptr, 0, bc, MROWS, 544, 512);
            const float* al = m_alog + (size_t)li*DD*SS;
            const float* dpp = m_dpar + (size_t)li*DD;
            scan_p1<<<dim3(256, NCHK-1), 256, 0, stream>>>(sp, xc, bc, al,
                hs, psb, dir);
            scan_comb<<<dim3(256), 256, 0, stream>>>(hs, psb, hin);
            scan_p2<<<dim3(256, NCHK), 256, 0, stream>>>(sp, xc, xz, bc, al,
                dpp, hin, yb, dir);
            gemm3<0,0,1,0,0><<<dim3(66*4), 256, 0, stream>>>(yb, 512,
                w_wout + (size_t)li*512*512, 512, nullptr,
                (dir == 0) ? fbuf : rbuf, DD, nullptr, 0, nullptr,
                MROWS, 512, 512);
        }
        ln_kernel<<<dim3(MROWS), 64, 0, stream>>>(h, h, fbuf, rbuf,
            ln1_g + l*DD, ln1_b + l*DD, hb);
        gemm3<1,1,0,1,0><<<dim3(66*4), 256, 0, stream>>>(hb, 512,
            w_ff1 + (size_t)l*512*512, 512, ff1_b + l*DD,
            nullptr, 0, fftb, 512, nullptr, MROWS, 512, 512);
        gemm3<1,0,1,0,0><<<dim3(66*4), 256, 0, stream>>>(fftb, 512,
            w_ff2 + (size_t)l*512*512, 512, ff2_b + l*DD,
            xc, DD, nullptr, 0, nullptr, MROWS, 512, 512);
        ln_kernel<<<dim3(MROWS), 64, 0, stream>>>(h, h, xc, nullptr,
            ln2_g + l*DD, ln2_b + l*DD, hb);
    }
    ln_kernel<<<dim3(MROWS), 64, 0, stream>>>(fbuf, h, nullptr, nullptr,
                                              lnf_g, lnf_b, nullptr);
    proj_kernel<<<dim3(BB*32), 128, 0, stream>>>(fbuf, proj_w, proj_b, mean, stdv, out);
}

// Round 19
// 821.095 us; speedup vs baseline: 1.7107x; 1.0220x over previous
//
#include <hip/hip_runtime.h>
#include <hip/hip_bf16.h>
#include <math.h>
#include <stddef.h>

#define BB 32
#define TT 262
#define DD 512
#define SS 16
#define RR 32
#define SEQ 512
#define NV 256
#define PRED 96
#define MROWS (BB*TT)   // 8384
#define NCHK 8
#define CSZ 33          // 8*33 = 264 >= 262

typedef __attribute__((ext_vector_type(4))) float f32x4;
typedef __attribute__((ext_vector_type(8))) short s16x8;

// ---------------- bf16 helpers ----------------
__device__ inline ushort f2bu(float x) {
    __hip_bfloat16 h = __float2bfloat16(x);
    ushort u; __builtin_memcpy(&u, &h, 2); return u;
}
__device__ inline float bu2f(ushort u) {
    __hip_bfloat16 h; __builtin_memcpy(&h, &u, 2);
    return __bfloat162float(h);
}

// async global->LDS, 16B per lane
__device__ inline void gload_lds16(const void* g, void* l) {
    __builtin_amdgcn_global_load_lds(
        (const __attribute__((address_space(1))) void*)g,
        (__attribute__((address_space(3))) void*)l, 16, 0, 0);
}

// ---------------------------------------------------------------------------
// weight bf16 cast (row-major, any size)
// ---------------------------------------------------------------------------
__global__ __launch_bounds__(256)
void packw(const float* __restrict__ in, ushort* __restrict__ out, int total)
{
    int idx = blockIdx.x * 256 + threadIdx.x;
    if (idx >= total) return;
    out[idx] = f2bu(in[idx]);
}

// ---------------------------------------------------------------------------
// combined scan-projection weight (dt path folded through wdt), bf16
// ---------------------------------------------------------------------------
__global__ __launch_bounds__(256)
void mkcomb(const float* __restrict__ wx, const float* __restrict__ wdt,
            ushort* __restrict__ comb)
{
    int n  = blockIdx.x;
    int li = blockIdx.y;
    const float* wxl = wx + (size_t)li*64*512;
    ushort* outb = comb + ((size_t)li*544 + n)*512;
    if (n < 512) {
        __shared__ float wr[32];
        if (threadIdx.x < 32)
            wr[threadIdx.x] = wdt[(size_t)li*512*32 + (size_t)n*32 + threadIdx.x];
        __syncthreads();
        for (int kk = threadIdx.x; kk < 512; kk += 256) {
            float acc = 0.f;
            #pragma unroll
            for (int r = 0; r < 32; ++r)
                acc = fmaf(wr[r], wxl[r*512 + kk], acc);
            outb[kk] = f2bu(acc);
        }
    } else {
        int s = n - 512;
        for (int kk = threadIdx.x; kk < 512; kk += 256)
            outb[kk] = f2bu(wxl[(32+s)*512 + kk]);
    }
}

// ---------------------------------------------------------------------------
// per-(b,n) mean/std over SEQ. grid = BB*16, block 256 = 16n x 16tg.
// ---------------------------------------------------------------------------
__global__ __launch_bounds__(256)
void stats_kernel(const float* __restrict__ x_enc,
                  float* __restrict__ mean, float* __restrict__ stdv)
{
    int b  = blockIdx.x >> 4;
    int n0 = (blockIdx.x & 15) << 4;
    int nl = threadIdx.x & 15;
    int tg = threadIdx.x >> 4;
    int n = n0 + nl;
    const float* base = x_enc + (size_t)b*SEQ*NV + n;
    float s0 = 0.f, s1 = 0.f, q0 = 0.f, q1 = 0.f;
    #pragma unroll 8
    for (int i = 0; i < 16; ++i) {
        int t = tg + i*32;
        float v0 = base[(size_t)t*NV];
        float v1 = base[(size_t)(t+16)*NV];
        s0 += v0; q0 = fmaf(v0, v0, q0);
        s1 += v1; q1 = fmaf(v1, v1, q1);
    }
    float s = s0 + s1, q = q0 + q1;
    __shared__ float ls[16][17], lq[16][17];
    ls[tg][nl] = s; lq[tg][nl] = q;
    __syncthreads();
    if (tg < 8) { ls[tg][nl] += ls[tg+8][nl]; lq[tg][nl] += lq[tg+8][nl]; }
    __syncthreads();
    if (tg < 4) { ls[tg][nl] += ls[tg+4][nl]; lq[tg][nl] += lq[tg+4][nl]; }
    __syncthreads();
    if (tg < 2) { ls[tg][nl] += ls[tg+2][nl]; lq[tg][nl] += lq[tg+2][nl]; }
    __syncthreads();
    if (tg == 0) {
        s = ls[0][nl] + ls[1][nl];
        q = lq[0][nl] + lq[1][nl];
        float mu  = s * (1.f/SEQ);
        float var = q * (1.f/SEQ) - mu*mu;
        mean[b*NV + n] = mu;
        stdv[b*NV + n] = sqrtf(var + 1e-5f);
    }
}

// ---------------------------------------------------------------------------
// tok: normalized transpose, bf16 rows of 512
// ---------------------------------------------------------------------------
__global__ __launch_bounds__(256)
void tok_kernel(const float* __restrict__ x_enc, const float* __restrict__ x_mark,
                const float* __restrict__ mean, const float* __restrict__ stdv,
                ushort* __restrict__ tokb)
{
    int b  = blockIdx.x / 40;
    int r  = blockIdx.x % 40;
    int tt = r / 5;
    int vt = r % 5;
    int t0 = tt << 6, v0 = vt << 6;
    __shared__ float tile[64][65];
    int lv = threadIdx.x & 63;
    for (int i = threadIdx.x >> 6; i < 64; i += 4) {
        int t = t0 + i, v = v0 + lv;
        float val = 0.f;
        if (v < NV) {
            val = (x_enc[((size_t)b*SEQ + t)*NV + v] - mean[b*NV + v]) / stdv[b*NV + v];
        } else if (v < TT) {
            val = x_mark[((size_t)b*SEQ + t)*6 + (v - NV)];
        }
        tile[i][lv] = val;
    }
    __syncthreads();
    for (int i = threadIdx.x >> 6; i < 64; i += 4) {
        int v = v0 + i;
        if (v < TT) {
            size_t row = (size_t)b*TT + v;
            tokb[row*512 + t0 + lv] = f2bu(tile[lv][i]);
        }
    }
}

// ---------------------------------------------------------------------------
// bf16 MFMA GEMM (NT; K multiple of 64). 1D grid, n-fast tile order inside
// bijective XCD swizzle.
// ---------------------------------------------------------------------------
template<int HAS_BIAS, int RELU, int WF32, int W3, int SCANEP>
__global__ __launch_bounds__(256)
void gemm3(const ushort* __restrict__ A3, int lda3,
           const ushort* __restrict__ W3p, int ldw3,
           const float* __restrict__ bias,
           float* __restrict__ C, int ldc,
           ushort* __restrict__ C3, int N_out,
           float* __restrict__ bcbuf,
           int M, int Nn, int K3)
{
    __shared__ ushort lds[2][2][128*64];   // [buf][A=0/W=1] : 64 KB
    const int tid  = threadIdx.x;
    const int lane = tid & 63;
    const int wid  = tid >> 6;
    const int wr = wid >> 1, wc = wid & 1;

    // bijective XCD swizzle (m204), then n-fast tile decode
    int nwg = gridDim.x;
    int q8 = nwg >> 3, r8 = nwg & 7;
    int xcd = blockIdx.x & 7;
    int idx = blockIdx.x >> 3;
    int swz = (xcd < r8 ? xcd*(q8+1) : r8*(q8+1) + (xcd-r8)*q8) + idx;
    int ntile = (Nn + 127) >> 7;
    const int m0 = (swz / ntile) * 128;
    const int n0 = (swz % ntile) * 128;

    const int l8 = lane >> 3;
    const int sl = lane & 7;
    const int ssl = sl ^ l8;

    int arow[4], wrow[4];
    #pragma unroll
    for (int qq = 0; qq < 4; ++qq) {
        int r = (wid*4 + qq)*8 + l8;
        int ar = m0 + r; if (ar > M-1) ar = M-1;
        arow[qq] = ar;
        int wrr = n0 + r; if (wrr > Nn-1) wrr = Nn-1;
        wrow[qq] = wrr;
    }

    f32x4 acc[4][4];
    #pragma unroll
    for (int i = 0; i < 4; ++i)
        #pragma unroll
        for (int j = 0; j < 4; ++j) acc[i][j] = (f32x4){0.f,0.f,0.f,0.f};

    const int nk = K3 >> 6;
    const int rl = lane & 15;
    const int kq = lane >> 4;

    auto stage = [&](int buf_, int kt_) {
        #pragma unroll
        for (int qq = 0; qq < 4; ++qq) {
            int c = wid*4 + qq;
            gload_lds16(A3 + (size_t)arow[qq]*lda3 + kt_*64 + ssl*8,
                        (void*)&lds[buf_][0][c*512]);
            gload_lds16(W3p + (size_t)wrow[qq]*ldw3 + kt_*64 + ssl*8,
                        (void*)&lds[buf_][1][c*512]);
        }
    };

    stage(0, 0);
    __syncthreads();

    for (int kt = 0; kt < nk; ++kt) {
        int cur = kt & 1;
        if (kt + 1 < nk) stage(cur ^ 1, kt + 1);
        #pragma unroll
        for (int kk = 0; kk < 2; ++kk) {
            s16x8 av[4], wv[4];
            #pragma unroll
            for (int mi = 0; mi < 4; ++mi) {
                int row = wr*64 + mi*16 + rl;
                int ck = (kk*4 + kq) ^ (row & 7);
                av[mi] = *(const s16x8*)&lds[cur][0][row*64 + (ck<<3)];
            }
            #pragma unroll
            for (int ni = 0; ni < 4; ++ni) {
                int row = wc*64 + ni*16 + rl;
                int ck = (kk*4 + kq) ^ (row & 7);
                wv[ni] = *(const s16x8*)&lds[cur][1][row*64 + (ck<<3)];
            }
            #pragma unroll
            for (int mi = 0; mi < 4; ++mi)
                #pragma unroll
                for (int ni = 0; ni < 4; ++ni)
                    acc[mi][ni] = __builtin_amdgcn_mfma_f32_16x16x32_bf16(
                        av[mi], wv[ni], acc[mi][ni], 0, 0, 0);
        }
        __syncthreads();
    }

    #pragma unroll
    for (int ni = 0; ni < 4; ++ni) {
        int n = n0 + wc*64 + ni*16 + rl;
        if (n >= Nn) continue;
        float bv = (HAS_BIAS && !SCANEP) ? bias[n] : 0.f;
        #pragma unroll
        for (int mi = 0; mi < 4; ++mi) {
            #pragma unroll
            for (int j = 0; j < 4; ++j) {
                int m = m0 + wr*64 + mi*16 + kq*4 + j;
                if (m >= M) continue;
                float v = acc[mi][ni][j];
                if (SCANEP) {
                    if (n < 512) {
                        v += bias[n];
                        v = fmaxf(v, 0.f) + log1pf(__expf(-fabsf(v)));
                        C[(size_t)m*ldc + n] = v;
                    } else {
                        bcbuf[(size_t)m*32 + (n - 512)] = v;
                    }
                } else {
                    if (HAS_BIAS) v += bv;
                    if (RELU) v = fmaxf(v, 0.f);
                    if (WF32) C[(size_t)m*ldc + n] = v;
                    if (W3)   C3[(size_t)m*N_out + n] = f2bu(v);
                }
            }
        }
    }
}

// ---------------------------------------------------------------------------
// conv + SiLU (fp32 xc + bf16 xcb), in-place silu on z-half of xz
// ---------------------------------------------------------------------------
__global__ __launch_bounds__(256)
void conv_silu(float* __restrict__ xz, const float* __restrict__ cw,
               const float* __restrict__ cb, float* __restrict__ xc,
               ushort* __restrict__ xcb, int rev)
{
    int idx = blockIdx.x * 256 + threadIdx.x;
    int d  = idx & (DD-1);
    int bt = idx >> 9;
    int t  = bt % TT;
    float cur = xz[(size_t)bt*2*DD + d];
    int tn = rev ? t + 1 : t - 1;
    float prev = 0.f;
    if (tn >= 0 && tn < TT)
        prev = xz[((size_t)bt + (rev ? 1 : -1))*2*DD + d];
    float v = prev*cw[d*2] + cur*cw[d*2+1] + cb[d];
    float sv = v / (1.f + __expf(-v));
    xc[idx] = sv;
    xcb[(size_t)bt*512 + d] = f2bu(sv);
    float z = xz[(size_t)bt*2*DD + DD + d];
    xz[(size_t)bt*2*DD + DD + d] = z / (1.f + __expf(-z));
}

// ---------------------------------------------------------------------------
// Chunked scan, pass 1
// ---------------------------------------------------------------------------
__global__ __launch_bounds__(256)
void scan_p1(const float* __restrict__ sp_g, const float* __restrict__ xc_g,
             const float* __restrict__ bc_g, const float* __restrict__ alog,
             float* __restrict__ hs, float* __restrict__ ps, int rev)
{
    int sblk = blockIdx.x;
    int c    = blockIdx.y;
    int b  = sblk >> 3;
    int d0 = (sblk & 7) << 6;
    int tid = threadIdx.x;
    int sg = tid & 3;
    int dl = tid >> 2;
    int d  = d0 + dl;

    float Ac[4];
    #pragma unroll
    for (int j = 0; j < 4; ++j)
        Ac[j] = -__expf(alog[d*SS + sg*4 + j]);
    float h0=0.f,h1=0.f,h2=0.f,h3=0.f;
    float p0=1.f,p1=1.f,p2=1.f,p3=1.f;
    size_t bbase = (size_t)b*TT;
    int t0 = c*CSZ;
    #pragma unroll 3
    for (int i = 0; i < CSZ; ++i) {
        int t = t0 + i;
        size_t p = bbase + (rev ? TT-1-t : t);
        float spv = sp_g[p*DD + d];
        float xcv = xc_g[p*DD + d];
        float4 Bv = *(const float4*)(bc_g + p*32 + sg*4);
        float dtxc = spv*xcv;
        float e0 = __expf(spv*Ac[0]);
        float e1 = __expf(spv*Ac[1]);
        float e2 = __expf(spv*Ac[2]);
        float e3 = __expf(spv*Ac[3]);
        h0 = fmaf(e0,h0,dtxc*Bv.x); p0 *= e0;
        h1 = fmaf(e1,h1,dtxc*Bv.y); p1 *= e1;
        h2 = fmaf(e2,h2,dtxc*Bv.z); p2 *= e2;
        h3 = fmaf(e3,h3,dtxc*Bv.w); p3 *= e3;
    }
    size_t o = ((size_t)c*256 + sblk)*256 + tid;
    float4 hv; hv.x=h0; hv.y=h1; hv.z=h2; hv.w=h3;
    float4 pv; pv.x=p0; pv.y=p1; pv.z=p2; pv.w=p3;
    ((float4*)hs)[o] = hv;
    ((float4*)ps)[o] = pv;
}

// ---------------------------------------------------------------------------
// Chunked scan, combine
// ---------------------------------------------------------------------------
__global__ __launch_bounds__(256)
void scan_comb(const float* __restrict__ hs, const float* __restrict__ ps,
               float* __restrict__ hin)
{
    size_t gid = (size_t)blockIdx.x*256 + threadIdx.x;   // 65536
    float4 h = {0.f,0.f,0.f,0.f};
    for (int c = 0; c < NCHK-1; ++c) {
        size_t o = (size_t)c*65536 + gid;
        float4 hl = ((const float4*)hs)[o];
        float4 pv = ((const float4*)ps)[o];
        h.x = fmaf(pv.x, h.x, hl.x);
        h.y = fmaf(pv.y, h.y, hl.y);
        h.z = fmaf(pv.z, h.z, hl.z);
        h.w = fmaf(pv.w, h.w, hl.w);
        ((float4*)hin)[o] = h;
    }
}

// ---------------------------------------------------------------------------
// Chunked scan, pass 2
// ---------------------------------------------------------------------------
__global__ __launch_bounds__(256)
void scan_p2(const float* __restrict__ sp_g, const float* __restrict__ xc_g,
             const float* __restrict__ xz_g, const float* __restrict__ bc_g,
             const float* __restrict__ alog, const float* __restrict__ dparam,
             const float* __restrict__ hin, ushort* __restrict__ yb, int rev)
{
    int sblk = blockIdx.x;
    int c    = blockIdx.y;
    int b  = sblk >> 3;
    int d0 = (sblk & 7) << 6;
    int tid = threadIdx.x;
    int sg = tid & 3;
    int dl = tid >> 2;
    int d  = d0 + dl;

    float Ac[4];
    #pragma unroll
    for (int j = 0; j < 4; ++j)
        Ac[j] = -__expf(alog[d*SS + sg*4 + j]);
    float dp = dparam[d];
    float h0=0.f,h1=0.f,h2=0.f,h3=0.f;
    if (c > 0) {
        float4 hv = ((const float4*)hin)[((size_t)(c-1)*256 + sblk)*256 + tid];
        h0=hv.x; h1=hv.y; h2=hv.z; h3=hv.w;
    }
    size_t bbase = (size_t)b*TT;
    int t0 = c*CSZ;
    #pragma unroll 3
    for (int i = 0; i < CSZ; ++i) {
        int t = t0 + i;
        int tc = t < TT ? t : TT-1;
        size_t p = bbase + (rev ? TT-1-tc : tc);
        float spv = sp_g[p*DD + d];
        float xcv = xc_g[p*DD + d];
        float zsv = xz_g[p*2*DD + DD + d];
        float4 Bv = *(const float4*)(bc_g + p*32 + sg*4);
        float4 Cv = *(const float4*)(bc_g + p*32 + 16 + sg*4);
        float dtxc = spv*xcv;
        float e0 = __expf(spv*Ac[0]);
        float e1 = __expf(spv*Ac[1]);
        float e2 = __expf(spv*Ac[2]);
        float e3 = __expf(spv*Ac[3]);
        h0 = fmaf(e0,h0,dtxc*Bv.x);
        h1 = fmaf(e1,h1,dtxc*Bv.y);
        h2 = fmaf(e2,h2,dtxc*Bv.z);
        h3 = fmaf(e3,h3,dtxc*Bv.w);
        float dot = h0*Cv.x + h1*Cv.y + h2*Cv.z + h3*Cv.w;
        dot += __shfl_xor(dot, 1);
        dot += __shfl_xor(dot, 2);
        if (sg == 0 && t < TT) {
            int tg = rev ? TT-1-t : t;
            float yv = (dot + dp*xcv) * zsv;
            yb[(bbase + tg)*512 + d] = f2bu(yv);
        }
    }
}

// ---------------------------------------------------------------------------
// LayerNorm (up to 3 summed inputs), optional bf16 output
// ---------------------------------------------------------------------------
__global__ __launch_bounds__(64)
void ln_kernel(float* __restrict__ dst, const float* __restrict__ a,
               const float* __restrict__ b, const float* __restrict__ c,
               const float* __restrict__ g, const float* __restrict__ beta,
               ushort* __restrict__ outb)
{
    int row = blockIdx.x;
    int lane = threadIdx.x;
    size_t base = (size_t)row * DD;
    float x[8];
    #pragma unroll
    for (int j = 0; j < 2; ++j) {
        int e4 = j*64 + lane;
        float4 v = *(const float4*)(a + base + (size_t)e4*4);
        if (b) { float4 t = *(const float4*)(b + base + (size_t)e4*4); v.x+=t.x; v.y+=t.y; v.z+=t.z; v.w+=t.w; }
        if (c) { float4 t = *(const float4*)(c + base + (size_t)e4*4); v.x+=t.x; v.y+=t.y; v.z+=t.z; v.w+=t.w; }
        x[j*4+0]=v.x; x[j*4+1]=v.y; x[j*4+2]=v.z; x[j*4+3]=v.w;
    }
    float s = 0.f;
    #pragma unroll
    for (int i = 0; i < 8; ++i) s += x[i];
    #pragma unroll
    for (int m = 1; m < 64; m <<= 1) s += __shfl_xor(s, m);
    float mu = s * (1.f/DD);
    float vs = 0.f;
    #pragma unroll
    for (int i = 0; i < 8; ++i) { float dd = x[i]-mu; vs += dd*dd; }
    #pragma unroll
    for (int m = 1; m < 64; m <<= 1) vs += __shfl_xor(vs, m);
    float r = rsqrtf(vs*(1.f/DD) + 1e-5f);
    #pragma unroll
    for (int j = 0; j < 2; ++j) {
        int e4 = j*64 + lane;
        float4 gv = *(const float4*)(g    + (size_t)e4*4);
        float4 bv = *(const float4*)(beta + (size_t)e4*4);
        float4 o;
        o.x = (x[j*4+0]-mu)*r*gv.x + bv.x;
        o.y = (x[j*4+1]-mu)*r*gv.y + bv.y;
        o.z = (x[j*4+2]-mu)*r*gv.z + bv.z;
        o.w = (x[j*4+3]-mu)*r*gv.w + bv.w;
        *(float4*)(dst + base + (size_t)e4*4) = o;
        if (outb) {
            ushort* ob = outb + (size_t)row*512;
            ob[e4*4+0] = f2bu(o.x);
            ob[e4*4+1] = f2bu(o.y);
            ob[e4*4+2] = f2bu(o.z);
            ob[e4*4+3] = f2bu(o.w);
        }
    }
}

// ---------------------------------------------------------------------------
// proj finish: transpose [b*TT+n][96] -> out[b][p][n], de-normalize.
// grid BB*4 (b, 64-n group), block 256.
// ---------------------------------------------------------------------------
__global__ __launch_bounds__(256)
void proj_fin(const float* __restrict__ projtmp, const float* __restrict__ mean,
              const float* __restrict__ stdv, float* __restrict__ out)
{
    int b  = blockIdx.x >> 2;
    int n0 = (blockIdx.x & 3) << 6;
    __shared__ float tile[64][97];
    // load 64 rows x 96 cols, coalesced over cols
    for (int i = threadIdx.x; i < 64*96; i += 256) {
        int rj = i / 96, cp = i % 96;
        tile[rj][cp] = projtmp[((size_t)b*TT + n0 + rj)*96 + cp];
    }
    __syncthreads();
    int nl = threadIdx.x & 63;
    int pg = threadIdx.x >> 6;          // 0..3
    int n = n0 + nl;
    float sd = stdv[b*NV + n];
    float mu = mean[b*NV + n];
    #pragma unroll
    for (int i = 0; i < 24; ++i) {
        int p = pg*24 + i;
        out[((size_t)b*PRED + p)*NV + n] = tile[nl][p]*sd + mu;
    }
}

// ---------------------------------------------------------------------------
extern "C" void kernel_launch(void* const* d_in, const int* in_sizes, int n_in,
                              void* d_out, int out_size, void* d_ws, size_t ws_size,
                              hipStream_t stream)
{
    (void)in_sizes; (void)n_in; (void)out_size; (void)ws_size;
    const float* x_enc   = (const float*)d_in[0];
    const float* x_mark  = (const float*)d_in[1];
    const float* emb_w   = (const float*)d_in[2];
    const float* emb_b   = (const float*)d_in[3];
    const float* m_win   = (const float*)d_in[4];
    const float* m_convw = (const float*)d_in[5];
    const float* m_convb = (const float*)d_in[6];
    const float* m_wx    = (const float*)d_in[7];
    const float* m_wdt   = (const float*)d_in[8];
    const float* m_bdt   = (const float*)d_in[9];
    const float* m_alog  = (const float*)d_in[10];
    const float* m_dpar  = (const float*)d_in[11];
    const float* m_wout  = (const float*)d_in[12];
    const float* ln1_g   = (const float*)d_in[13];
    const float* ln1_b   = (const float*)d_in[14];
    const float* ff1_w   = (const float*)d_in[15];
    const float* ff1_b   = (const float*)d_in[16];
    const float* ff2_w   = (const float*)d_in[17];
    const float* ff2_b   = (const float*)d_in[18];
    const float* ln2_g   = (const float*)d_in[19];
    const float* ln2_b   = (const float*)d_in[20];
    const float* lnf_g   = (const float*)d_in[21];
    const float* lnf_b   = (const float*)d_in[22];
    const float* proj_w  = (const float*)d_in[23];
    const float* proj_b  = (const float*)d_in[24];
    float* out = (float*)d_out;

    float* ws = (float*)d_ws;
    const size_t NBT = (size_t)MROWS;
    size_t off = 0;
    float* mean = ws + off; off += 8192;
    float* stdv = ws + off; off += 8192;
    ushort* w_emb  = (ushort*)(ws + off); off += 393216;
    ushort* w_win  = (ushort*)(ws + off); off += 3145728;
    ushort* w_wout = (ushort*)(ws + off); off += 1572864;
    ushort* w_ff1  = (ushort*)(ws + off); off += 786432;
    ushort* w_ff2  = (ushort*)(ws + off); off += 786432;
    ushort* w_comb = (ushort*)(ws + off); off += 1671168;
    ushort* w_proj = (ushort*)(ws + off); off += 24576;      // 96*512 bf16
    ushort* tokb = (ushort*)(ws + off); off += NBT*768;      // aliased: xcb, yb
    ushort* xcb = tokb;
    ushort* yb  = tokb;
    float* h   = ws + off; off += NBT*DD;
    ushort* hb = (ushort*)(ws + off); off += NBT*768;
    float* xz  = ws + off; off += NBT*2*DD;
    ushort* fftb = (ushort*)xz;                              // alias
    float* xc  = ws + off; off += NBT*DD;
    float* bc  = ws + off; off += NBT*32;
    float* sp  = ws + off; off += NBT*DD;
    float* fbuf = ws + off; off += NBT*DD;
    float* rbuf = ws + off; off += NBT*DD;
    float* hs  = ws + off; off += (NCHK-1)*65536*4;
    float* psb = ws + off; off += (NCHK-1)*65536*4;
    float* hin = ws + off; off += (NCHK-1)*65536*4;
    float* projtmp = ws + off; off += NBT*96;

    // ---- weight packing (bf16 cast) ----
    packw<<<dim3((512*512+255)/256),  256, 0, stream>>>(emb_w, w_emb, 512*512);
    packw<<<dim3((4096*512+255)/256), 256, 0, stream>>>(m_win, w_win, 4096*512);
    packw<<<dim3((2048*512+255)/256), 256, 0, stream>>>(m_wout, w_wout, 2048*512);
    packw<<<dim3((1024*512+255)/256), 256, 0, stream>>>(ff1_w, w_ff1, 1024*512);
    packw<<<dim3((1024*512+255)/256), 256, 0, stream>>>(ff2_w, w_ff2, 1024*512);
    packw<<<dim3((96*512+255)/256),   256, 0, stream>>>(proj_w, w_proj, 96*512);
    mkcomb<<<dim3(544,4), 256, 0, stream>>>(m_wx, m_wdt, w_comb);

    stats_kernel<<<dim3(BB*16), 256, 0, stream>>>(x_enc, mean, stdv);
    tok_kernel<<<dim3(BB*40), 256, 0, stream>>>(x_enc, x_mark, mean, stdv, tokb);

    gemm3<1,0,1,1,0><<<dim3(66*4), 256, 0, stream>>>(tokb, 512, w_emb, 512,
        emb_b, h, DD, hb, 512, nullptr, MROWS, 512, 512);

    for (int l = 0; l < 2; ++l) {
        for (int dir = 0; dir < 2; ++dir) {
            int li = l*2 + dir;
            gemm3<0,0,1,0,0><<<dim3(66*8), 256, 0, stream>>>(hb, 512,
                w_win + (size_t)li*1024*512, 512, nullptr,
                xz, 2*DD, nullptr, 0, nullptr, MROWS, 1024, 512);
            conv_silu<<<dim3((MROWS*DD)/256), 256, 0, stream>>>(
                xz, m_convw + (size_t)li*DD*2, m_convb + (size_t)li*DD,
                xc, xcb, dir);
            gemm3<0,0,0,0,1><<<dim3(66*5), 256, 0, stream>>>(xcb, 512,
                w_comb + (size_t)li*544*512, 512, m_bdt + (size_t)li*DD,
                sp, 512, nullptr, 0, bc, MROWS, 544, 512);
            const float* al = m_alog + (size_t)li*DD*SS;
            const float* dpp = m_dpar + (size_t)li*DD;
            scan_p1<<<dim3(256, NCHK-1), 256, 0, stream>>>(sp, xc, bc, al,
                hs, psb, dir);
            scan_comb<<<dim3(256), 256, 0, stream>>>(hs, psb, hin);
            scan_p2<<<dim3(256, NCHK), 256, 0, stream>>>(sp, xc, xz, bc, al,
                dpp, hin, yb, dir);
            gemm3<0,0,1,0,0><<<dim3(66*4), 256, 0, stream>>>(yb, 512,
                w_wout + (size_t)li*512*512, 512, nullptr,
                (dir == 0) ? fbuf : rbuf, DD, nullptr, 0, nullptr,
                MROWS, 512, 512);
        }
        ln_kernel<<<dim3(MROWS), 64, 0, stream>>>(h, h, fbuf, rbuf,
            ln1_g + l*DD, ln1_b + l*DD, hb);
        gemm3<1,1,0,1,0><<<dim3(66*4), 256, 0, stream>>>(hb, 512,
            w_ff1 + (size_t)l*512*512, 512, ff1_b + l*DD,
            nullptr, 0, fftb, 512, nullptr, MROWS, 512, 512);
        gemm3<1,0,1,0,0><<<dim3(66*4), 256, 0, stream>>>(fftb, 512,
            w_ff2 + (size_t)l*512*512, 512, ff2_b + l*DD,
            xc, DD, nullptr, 0, nullptr, MROWS, 512, 512);
        ln_kernel<<<dim3(MROWS), 64, 0, stream>>>(h, h, xc, nullptr,
            ln2_g + l*DD, ln2_b + l*DD, hb);
    }
    ln_kernel<<<dim3(MROWS), 64, 0, stream>>>(fbuf, h, nullptr, nullptr,
                                              lnf_g, lnf_b, hb);
    // projection as MFMA GEMM + bias, then transpose/de-norm
    gemm3<1,0,1,0,0><<<dim3(66), 256, 0, stream>>>(hb, 512, w_proj, 512,
        proj_b, projtmp, 96, nullptr, 0, nullptr, MROWS, 96, 512);
    proj_fin<<<dim3(BB*4), 256, 0, stream>>>(projtmp, mean, stdv, out);
}

// Round 20
// 816.854 us; speedup vs baseline: 1.7196x; 1.0052x over previous
//
#include <hip/hip_runtime.h>
#include <hip/hip_bf16.h>
#include <math.h>
#include <stddef.h>

#define BB 32
#define TT 262
#define DD 512
#define SS 16
#define RR 32
#define SEQ 512
#define NV 256
#define PRED 96
#define MROWS (BB*TT)   // 8384
#define NCHK 8
#define CSZ 33          // 8*33 = 264 >= 262

typedef __attribute__((ext_vector_type(4))) float f32x4;
typedef __attribute__((ext_vector_type(8))) short s16x8;

// ---------------- bf16 helpers ----------------
__device__ inline ushort f2bu(float x) {
    __hip_bfloat16 h = __float2bfloat16(x);
    ushort u; __builtin_memcpy(&u, &h, 2); return u;
}
__device__ inline float bu2f(ushort u) {
    __hip_bfloat16 h; __builtin_memcpy(&h, &u, 2);
    return __bfloat162float(h);
}

// async global->LDS, 16B per lane
__device__ inline void gload_lds16(const void* g, void* l) {
    __builtin_amdgcn_global_load_lds(
        (const __attribute__((address_space(1))) void*)g,
        (__attribute__((address_space(3))) void*)l, 16, 0, 0);
}

// ---------------------------------------------------------------------------
// weight bf16 cast (row-major, any size)
// ---------------------------------------------------------------------------
__global__ __launch_bounds__(256)
void packw(const float* __restrict__ in, ushort* __restrict__ out, int total)
{
    int idx = blockIdx.x * 256 + threadIdx.x;
    if (idx >= total) return;
    out[idx] = f2bu(in[idx]);
}

// ---------------------------------------------------------------------------
// combined scan-projection weight (dt path folded through wdt), bf16
// ---------------------------------------------------------------------------
__global__ __launch_bounds__(256)
void mkcomb(const float* __restrict__ wx, const float* __restrict__ wdt,
            ushort* __restrict__ comb)
{
    int n  = blockIdx.x;
    int li = blockIdx.y;
    const float* wxl = wx + (size_t)li*64*512;
    ushort* outb = comb + ((size_t)li*544 + n)*512;
    if (n < 512) {
        __shared__ float wr[32];
        if (threadIdx.x < 32)
            wr[threadIdx.x] = wdt[(size_t)li*512*32 + (size_t)n*32 + threadIdx.x];
        __syncthreads();
        for (int kk = threadIdx.x; kk < 512; kk += 256) {
            float acc = 0.f;
            #pragma unroll
            for (int r = 0; r < 32; ++r)
                acc = fmaf(wr[r], wxl[r*512 + kk], acc);
            outb[kk] = f2bu(acc);
        }
    } else {
        int s = n - 512;
        for (int kk = threadIdx.x; kk < 512; kk += 256)
            outb[kk] = f2bu(wxl[(32+s)*512 + kk]);
    }
}

// ---------------------------------------------------------------------------
// per-(b,n) mean/std over SEQ. grid = BB*16, block 256 = 16n x 16tg.
// ---------------------------------------------------------------------------
__global__ __launch_bounds__(256)
void stats_kernel(const float* __restrict__ x_enc,
                  float* __restrict__ mean, float* __restrict__ stdv)
{
    int b  = blockIdx.x >> 4;
    int n0 = (blockIdx.x & 15) << 4;
    int nl = threadIdx.x & 15;
    int tg = threadIdx.x >> 4;
    int n = n0 + nl;
    const float* base = x_enc + (size_t)b*SEQ*NV + n;
    float s0 = 0.f, s1 = 0.f, q0 = 0.f, q1 = 0.f;
    #pragma unroll 8
    for (int i = 0; i < 16; ++i) {
        int t = tg + i*32;
        float v0 = base[(size_t)t*NV];
        float v1 = base[(size_t)(t+16)*NV];
        s0 += v0; q0 = fmaf(v0, v0, q0);
        s1 += v1; q1 = fmaf(v1, v1, q1);
    }
    float s = s0 + s1, q = q0 + q1;
    __shared__ float ls[16][17], lq[16][17];
    ls[tg][nl] = s; lq[tg][nl] = q;
    __syncthreads();
    if (tg < 8) { ls[tg][nl] += ls[tg+8][nl]; lq[tg][nl] += lq[tg+8][nl]; }
    __syncthreads();
    if (tg < 4) { ls[tg][nl] += ls[tg+4][nl]; lq[tg][nl] += lq[tg+4][nl]; }
    __syncthreads();
    if (tg < 2) { ls[tg][nl] += ls[tg+2][nl]; lq[tg][nl] += lq[tg+2][nl]; }
    __syncthreads();
    if (tg == 0) {
        s = ls[0][nl] + ls[1][nl];
        q = lq[0][nl] + lq[1][nl];
        float mu  = s * (1.f/SEQ);
        float var = q * (1.f/SEQ) - mu*mu;
        mean[b*NV + n] = mu;
        stdv[b*NV + n] = sqrtf(var + 1e-5f);
    }
}

// ---------------------------------------------------------------------------
// tok: normalized transpose, bf16 rows of 512
// ---------------------------------------------------------------------------
__global__ __launch_bounds__(256)
void tok_kernel(const float* __restrict__ x_enc, const float* __restrict__ x_mark,
                const float* __restrict__ mean, const float* __restrict__ stdv,
                ushort* __restrict__ tokb)
{
    int b  = blockIdx.x / 40;
    int r  = blockIdx.x % 40;
    int tt = r / 5;
    int vt = r % 5;
    int t0 = tt << 6, v0 = vt << 6;
    __shared__ float tile[64][65];
    int lv = threadIdx.x & 63;
    for (int i = threadIdx.x >> 6; i < 64; i += 4) {
        int t = t0 + i, v = v0 + lv;
        float val = 0.f;
        if (v < NV) {
            val = (x_enc[((size_t)b*SEQ + t)*NV + v] - mean[b*NV + v]) / stdv[b*NV + v];
        } else if (v < TT) {
            val = x_mark[((size_t)b*SEQ + t)*6 + (v - NV)];
        }
        tile[i][lv] = val;
    }
    __syncthreads();
    for (int i = threadIdx.x >> 6; i < 64; i += 4) {
        int v = v0 + i;
        if (v < TT) {
            size_t row = (size_t)b*TT + v;
            tokb[row*512 + t0 + lv] = f2bu(tile[lv][i]);
        }
    }
}

// ---------------------------------------------------------------------------
// bf16 MFMA GEMM (NT; K multiple of 64). SINGLE-buffer LDS (32KB) ->
// 4 blocks/CU; cross-block TLP hides per-step load latency.
// 1D grid, n-fast tile order inside bijective XCD swizzle.
// ---------------------------------------------------------------------------
template<int HAS_BIAS, int RELU, int WF32, int W3, int SCANEP>
__global__ __launch_bounds__(256)
void gemm3(const ushort* __restrict__ A3, int lda3,
           const ushort* __restrict__ W3p, int ldw3,
           const float* __restrict__ bias,
           float* __restrict__ C, int ldc,
           ushort* __restrict__ C3, int N_out,
           float* __restrict__ bcbuf,
           int M, int Nn, int K3)
{
    __shared__ ushort lds[2][128*64];   // [A=0/W=1] : 32 KB (single buffer)
    const int tid  = threadIdx.x;
    const int lane = tid & 63;
    const int wid  = tid >> 6;
    const int wr = wid >> 1, wc = wid & 1;

    // bijective XCD swizzle (m204), then n-fast tile decode
    int nwg = gridDim.x;
    int q8 = nwg >> 3, r8 = nwg & 7;
    int xcd = blockIdx.x & 7;
    int idx = blockIdx.x >> 3;
    int swz = (xcd < r8 ? xcd*(q8+1) : r8*(q8+1) + (xcd-r8)*q8) + idx;
    int ntile = (Nn + 127) >> 7;
    const int m0 = (swz / ntile) * 128;
    const int n0 = (swz % ntile) * 128;

    const int l8 = lane >> 3;
    const int sl = lane & 7;
    const int ssl = sl ^ l8;

    int arow[4], wrow[4];
    #pragma unroll
    for (int qq = 0; qq < 4; ++qq) {
        int r = (wid*4 + qq)*8 + l8;
        int ar = m0 + r; if (ar > M-1) ar = M-1;
        arow[qq] = ar;
        int wrr = n0 + r; if (wrr > Nn-1) wrr = Nn-1;
        wrow[qq] = wrr;
    }

    f32x4 acc[4][4];
    #pragma unroll
    for (int i = 0; i < 4; ++i)
        #pragma unroll
        for (int j = 0; j < 4; ++j) acc[i][j] = (f32x4){0.f,0.f,0.f,0.f};

    const int nk = K3 >> 6;
    const int rl = lane & 15;
    const int kq = lane >> 4;

    for (int kt = 0; kt < nk; ++kt) {
        #pragma unroll
        for (int qq = 0; qq < 4; ++qq) {
            int c = wid*4 + qq;
            gload_lds16(A3 + (size_t)arow[qq]*lda3 + kt*64 + ssl*8,
                        (void*)&lds[0][c*512]);
            gload_lds16(W3p + (size_t)wrow[qq]*ldw3 + kt*64 + ssl*8,
                        (void*)&lds[1][c*512]);
        }
        __syncthreads();
        #pragma unroll
        for (int kk = 0; kk < 2; ++kk) {
            s16x8 av[4], wv[4];
            #pragma unroll
            for (int mi = 0; mi < 4; ++mi) {
                int row = wr*64 + mi*16 + rl;
                int ck = (kk*4 + kq) ^ (row & 7);
                av[mi] = *(const s16x8*)&lds[0][row*64 + (ck<<3)];
            }
            #pragma unroll
            for (int ni = 0; ni < 4; ++ni) {
                int row = wc*64 + ni*16 + rl;
                int ck = (kk*4 + kq) ^ (row & 7);
                wv[ni] = *(const s16x8*)&lds[1][row*64 + (ck<<3)];
            }
            #pragma unroll
            for (int mi = 0; mi < 4; ++mi)
                #pragma unroll
                for (int ni = 0; ni < 4; ++ni)
                    acc[mi][ni] = __builtin_amdgcn_mfma_f32_16x16x32_bf16(
                        av[mi], wv[ni], acc[mi][ni], 0, 0, 0);
        }
        __syncthreads();
    }

    #pragma unroll
    for (int ni = 0; ni < 4; ++ni) {
        int n = n0 + wc*64 + ni*16 + rl;
        if (n >= Nn) continue;
        float bv = (HAS_BIAS && !SCANEP) ? bias[n] : 0.f;
        #pragma unroll
        for (int mi = 0; mi < 4; ++mi) {
            #pragma unroll
            for (int j = 0; j < 4; ++j) {
                int m = m0 + wr*64 + mi*16 + kq*4 + j;
                if (m >= M) continue;
                float v = acc[mi][ni][j];
                if (SCANEP) {
                    if (n < 512) {
                        v += bias[n];
                        v = fmaxf(v, 0.f) + log1pf(__expf(-fabsf(v)));
                        C[(size_t)m*ldc + n] = v;
                    } else {
                        bcbuf[(size_t)m*32 + (n - 512)] = v;
                    }
                } else {
                    if (HAS_BIAS) v += bv;
                    if (RELU) v = fmaxf(v, 0.f);
                    if (WF32) C[(size_t)m*ldc + n] = v;
                    if (W3)   C3[(size_t)m*N_out + n] = f2bu(v);
                }
            }
        }
    }
}

// ---------------------------------------------------------------------------
// conv + SiLU (fp32 xc + bf16 xcb), in-place silu on z-half of xz
// ---------------------------------------------------------------------------
__global__ __launch_bounds__(256)
void conv_silu(float* __restrict__ xz, const float* __restrict__ cw,
               const float* __restrict__ cb, float* __restrict__ xc,
               ushort* __restrict__ xcb, int rev)
{
    int idx = blockIdx.x * 256 + threadIdx.x;
    int d  = idx & (DD-1);
    int bt = idx >> 9;
    int t  = bt % TT;
    float cur = xz[(size_t)bt*2*DD + d];
    int tn = rev ? t + 1 : t - 1;
    float prev = 0.f;
    if (tn >= 0 && tn < TT)
        prev = xz[((size_t)bt + (rev ? 1 : -1))*2*DD + d];
    float v = prev*cw[d*2] + cur*cw[d*2+1] + cb[d];
    float sv = v / (1.f + __expf(-v));
    xc[idx] = sv;
    xcb[(size_t)bt*512 + d] = f2bu(sv);
    float z = xz[(size_t)bt*2*DD + DD + d];
    xz[(size_t)bt*2*DD + DD + d] = z / (1.f + __expf(-z));
}

// ---------------------------------------------------------------------------
// Chunked scan, pass 1
// ---------------------------------------------------------------------------
__global__ __launch_bounds__(256)
void scan_p1(const float* __restrict__ sp_g, const float* __restrict__ xc_g,
             const float* __restrict__ bc_g, const float* __restrict__ alog,
             float* __restrict__ hs, float* __restrict__ ps, int rev)
{
    int sblk = blockIdx.x;
    int c    = blockIdx.y;
    int b  = sblk >> 3;
    int d0 = (sblk & 7) << 6;
    int tid = threadIdx.x;
    int sg = tid & 3;
    int dl = tid >> 2;
    int d  = d0 + dl;

    float Ac[4];
    #pragma unroll
    for (int j = 0; j < 4; ++j)
        Ac[j] = -__expf(alog[d*SS + sg*4 + j]);
    float h0=0.f,h1=0.f,h2=0.f,h3=0.f;
    float p0=1.f,p1=1.f,p2=1.f,p3=1.f;
    size_t bbase = (size_t)b*TT;
    int t0 = c*CSZ;
    #pragma unroll 3
    for (int i = 0; i < CSZ; ++i) {
        int t = t0 + i;
        size_t p = bbase + (rev ? TT-1-t : t);
        float spv = sp_g[p*DD + d];
        float xcv = xc_g[p*DD + d];
        float4 Bv = *(const float4*)(bc_g + p*32 + sg*4);
        float dtxc = spv*xcv;
        float e0 = __expf(spv*Ac[0]);
        float e1 = __expf(spv*Ac[1]);
        float e2 = __expf(spv*Ac[2]);
        float e3 = __expf(spv*Ac[3]);
        h0 = fmaf(e0,h0,dtxc*Bv.x); p0 *= e0;
        h1 = fmaf(e1,h1,dtxc*Bv.y); p1 *= e1;
        h2 = fmaf(e2,h2,dtxc*Bv.z); p2 *= e2;
        h3 = fmaf(e3,h3,dtxc*Bv.w); p3 *= e3;
    }
    size_t o = ((size_t)c*256 + sblk)*256 + tid;
    float4 hv; hv.x=h0; hv.y=h1; hv.z=h2; hv.w=h3;
    float4 pv; pv.x=p0; pv.y=p1; pv.z=p2; pv.w=p3;
    ((float4*)hs)[o] = hv;
    ((float4*)ps)[o] = pv;
}

// ---------------------------------------------------------------------------
// Chunked scan, combine
// ---------------------------------------------------------------------------
__global__ __launch_bounds__(256)
void scan_comb(const float* __restrict__ hs, const float* __restrict__ ps,
               float* __restrict__ hin)
{
    size_t gid = (size_t)blockIdx.x*256 + threadIdx.x;   // 65536
    float4 h = {0.f,0.f,0.f,0.f};
    for (int c = 0; c < NCHK-1; ++c) {
        size_t o = (size_t)c*65536 + gid;
        float4 hl = ((const float4*)hs)[o];
        float4 pv = ((const float4*)ps)[o];
        h.x = fmaf(pv.x, h.x, hl.x);
        h.y = fmaf(pv.y, h.y, hl.y);
        h.z = fmaf(pv.z, h.z, hl.z);
        h.w = fmaf(pv.w, h.w, hl.w);
        ((float4*)hin)[o] = h;
    }
}

// ---------------------------------------------------------------------------
// Chunked scan, pass 2
// ---------------------------------------------------------------------------
__global__ __launch_bounds__(256)
void scan_p2(const float* __restrict__ sp_g, const float* __restrict__ xc_g,
             const float* __restrict__ xz_g, const float* __restrict__ bc_g,
             const float* __restrict__ alog, const float* __restrict__ dparam,
             const float* __restrict__ hin, ushort* __restrict__ yb, int rev)
{
    int sblk = blockIdx.x;
    int c    = blockIdx.y;
    int b  = sblk >> 3;
    int d0 = (sblk & 7) << 6;
    int tid = threadIdx.x;
    int sg = tid & 3;
    int dl = tid >> 2;
    int d  = d0 + dl;

    float Ac[4];
    #pragma unroll
    for (int j = 0; j < 4; ++j)
        Ac[j] = -__expf(alog[d*SS + sg*4 + j]);
    float dp = dparam[d];
    float h0=0.f,h1=0.f,h2=0.f,h3=0.f;
    if (c > 0) {
        float4 hv = ((const float4*)hin)[((size_t)(c-1)*256 + sblk)*256 + tid];
        h0=hv.x; h1=hv.y; h2=hv.z; h3=hv.w;
    }
    size_t bbase = (size_t)b*TT;
    int t0 = c*CSZ;
    #pragma unroll 3
    for (int i = 0; i < CSZ; ++i) {
        int t = t0 + i;
        int tc = t < TT ? t : TT-1;
        size_t p = bbase + (rev ? TT-1-tc : tc);
        float spv = sp_g[p*DD + d];
        float xcv = xc_g[p*DD + d];
        float zsv = xz_g[p*2*DD + DD + d];
        float4 Bv = *(const float4*)(bc_g + p*32 + sg*4);
        float4 Cv = *(const float4*)(bc_g + p*32 + 16 + sg*4);
        float dtxc = spv*xcv;
        float e0 = __expf(spv*Ac[0]);
        float e1 = __expf(spv*Ac[1]);
        float e2 = __expf(spv*Ac[2]);
        float e3 = __expf(spv*Ac[3]);
        h0 = fmaf(e0,h0,dtxc*Bv.x);
        h1 = fmaf(e1,h1,dtxc*Bv.y);
        h2 = fmaf(e2,h2,dtxc*Bv.z);
        h3 = fmaf(e3,h3,dtxc*Bv.w);
        float dot = h0*Cv.x + h1*Cv.y + h2*Cv.z + h3*Cv.w;
        dot += __shfl_xor(dot, 1);
        dot += __shfl_xor(dot, 2);
        if (sg == 0 && t < TT) {
            int tg = rev ? TT-1-t : t;
            float yv = (dot + dp*xcv) * zsv;
            yb[(bbase + tg)*512 + d] = f2bu(yv);
        }
    }
}

// ---------------------------------------------------------------------------
// LayerNorm (up to 3 summed inputs), optional bf16 output
// ---------------------------------------------------------------------------
__global__ __launch_bounds__(64)
void ln_kernel(float* __restrict__ dst, const float* __restrict__ a,
               const float* __restrict__ b, const float* __restrict__ c,
               const float* __restrict__ g, const float* __restrict__ beta,
               ushort* __restrict__ outb)
{
    int row = blockIdx.x;
    int lane = threadIdx.x;
    size_t base = (size_t)row * DD;
    float x[8];
    #pragma unroll
    for (int j = 0; j < 2; ++j) {
        int e4 = j*64 + lane;
        float4 v = *(const float4*)(a + base + (size_t)e4*4);
        if (b) { float4 t = *(const float4*)(b + base + (size_t)e4*4); v.x+=t.x; v.y+=t.y; v.z+=t.z; v.w+=t.w; }
        if (c) { float4 t = *(const float4*)(c + base + (size_t)e4*4); v.x+=t.x; v.y+=t.y; v.z+=t.z; v.w+=t.w; }
        x[j*4+0]=v.x; x[j*4+1]=v.y; x[j*4+2]=v.z; x[j*4+3]=v.w;
    }
    float s = 0.f;
    #pragma unroll
    for (int i = 0; i < 8; ++i) s += x[i];
    #pragma unroll
    for (int m = 1; m < 64; m <<= 1) s += __shfl_xor(s, m);
    float mu = s * (1.f/DD);
    float vs = 0.f;
    #pragma unroll
    for (int i = 0; i < 8; ++i) { float dd = x[i]-mu; vs += dd*dd; }
    #pragma unroll
    for (int m = 1; m < 64; m <<= 1) vs += __shfl_xor(vs, m);
    float r = rsqrtf(vs*(1.f/DD) + 1e-5f);
    #pragma unroll
    for (int j = 0; j < 2; ++j) {
        int e4 = j*64 + lane;
        float4 gv = *(const float4*)(g    + (size_t)e4*4);
        float4 bv = *(const float4*)(beta + (size_t)e4*4);
        float4 o;
        o.x = (x[j*4+0]-mu)*r*gv.x + bv.x;
        o.y = (x[j*4+1]-mu)*r*gv.y + bv.y;
        o.z = (x[j*4+2]-mu)*r*gv.z + bv.z;
        o.w = (x[j*4+3]-mu)*r*gv.w + bv.w;
        *(float4*)(dst + base + (size_t)e4*4) = o;
        if (outb) {
            ushort* ob = outb + (size_t)row*512;
            ob[e4*4+0] = f2bu(o.x);
            ob[e4*4+1] = f2bu(o.y);
            ob[e4*4+2] = f2bu(o.z);
            ob[e4*4+3] = f2bu(o.w);
        }
    }
}

// ---------------------------------------------------------------------------
// proj finish: transpose [b*TT+n][96] -> out[b][p][n], de-normalize.
// ---------------------------------------------------------------------------
__global__ __launch_bounds__(256)
void proj_fin(const float* __restrict__ projtmp, const float* __restrict__ mean,
              const float* __restrict__ stdv, float* __restrict__ out)
{
    int b  = blockIdx.x >> 2;
    int n0 = (blockIdx.x & 3) << 6;
    __shared__ float tile[64][97];
    for (int i = threadIdx.x; i < 64*96; i += 256) {
        int rj = i / 96, cp = i % 96;
        tile[rj][cp] = projtmp[((size_t)b*TT + n0 + rj)*96 + cp];
    }
    __syncthreads();
    int nl = threadIdx.x & 63;
    int pg = threadIdx.x >> 6;          // 0..3
    int n = n0 + nl;
    float sd = stdv[b*NV + n];
    float mu = mean[b*NV + n];
    #pragma unroll
    for (int i = 0; i < 24; ++i) {
        int p = pg*24 + i;
        out[((size_t)b*PRED + p)*NV + n] = tile[nl][p]*sd + mu;
    }
}

// ---------------------------------------------------------------------------
extern "C" void kernel_launch(void* const* d_in, const int* in_sizes, int n_in,
                              void* d_out, int out_size, void* d_ws, size_t ws_size,
                              hipStream_t stream)
{
    (void)in_sizes; (void)n_in; (void)out_size; (void)ws_size;
    const float* x_enc   = (const float*)d_in[0];
    const float* x_mark  = (const float*)d_in[1];
    const float* emb_w   = (const float*)d_in[2];
    const float* emb_b   = (const float*)d_in[3];
    const float* m_win   = (const float*)d_in[4];
    const float* m_convw = (const float*)d_in[5];
    const float* m_convb = (const float*)d_in[6];
    const float* m_wx    = (const float*)d_in[7];
    const float* m_wdt   = (const float*)d_in[8];
    const float* m_bdt   = (const float*)d_in[9];
    const float* m_alog  = (const float*)d_in[10];
    const float* m_dpar  = (const float*)d_in[11];
    const float* m_wout  = (const float*)d_in[12];
    const float* ln1_g   = (const float*)d_in[13];
    const float* ln1_b   = (const float*)d_in[14];
    const float* ff1_w   = (const float*)d_in[15];
    const float* ff1_b   = (const float*)d_in[16];
    const float* ff2_w   = (const float*)d_in[17];
    const float* ff2_b   = (const float*)d_in[18];
    const float* ln2_g   = (const float*)d_in[19];
    const float* ln2_b   = (const float*)d_in[20];
    const float* lnf_g   = (const float*)d_in[21];
    const float* lnf_b   = (const float*)d_in[22];
    const float* proj_w  = (const float*)d_in[23];
    const float* proj_b  = (const float*)d_in[24];
    float* out = (float*)d_out;

    float* ws = (float*)d_ws;
    const size_t NBT = (size_t)MROWS;
    size_t off = 0;
    float* mean = ws + off; off += 8192;
    float* stdv = ws + off; off += 8192;
    ushort* w_emb  = (ushort*)(ws + off); off += 393216;
    ushort* w_win  = (ushort*)(ws + off); off += 3145728;
    ushort* w_wout = (ushort*)(ws + off); off += 1572864;
    ushort* w_ff1  = (ushort*)(ws + off); off += 786432;
    ushort* w_ff2  = (ushort*)(ws + off); off += 786432;
    ushort* w_comb = (ushort*)(ws + off); off += 1671168;
    ushort* w_proj = (ushort*)(ws + off); off += 24576;      // 96*512 bf16
    ushort* tokb = (ushort*)(ws + off); off += NBT*768;      // aliased: xcb, yb
    ushort* xcb = tokb;
    ushort* yb  = tokb;
    float* h   = ws + off; off += NBT*DD;
    ushort* hb = (ushort*)(ws + off); off += NBT*768;
    float* xz  = ws + off; off += NBT*2*DD;
    ushort* fftb = (ushort*)xz;                              // alias
    float* xc  = ws + off; off += NBT*DD;
    float* bc  = ws + off; off += NBT*32;
    float* sp  = ws + off; off += NBT*DD;
    float* fbuf = ws + off; off += NBT*DD;
    float* rbuf = ws + off; off += NBT*DD;
    float* hs  = ws + off; off += (NCHK-1)*65536*4;
    float* psb = ws + off; off += (NCHK-1)*65536*4;
    float* hin = ws + off; off += (NCHK-1)*65536*4;
    float* projtmp = ws + off; off += NBT*96;

    // ---- weight packing (bf16 cast) ----
    packw<<<dim3((512*512+255)/256),  256, 0, stream>>>(emb_w, w_emb, 512*512);
    packw<<<dim3((4096*512+255)/256), 256, 0, stream>>>(m_win, w_win, 4096*512);
    packw<<<dim3((2048*512+255)/256), 256, 0, stream>>>(m_wout, w_wout, 2048*512);
    packw<<<dim3((1024*512+255)/256), 256, 0, stream>>>(ff1_w, w_ff1, 1024*512);
    packw<<<dim3((1024*512+255)/256), 256, 0, stream>>>(ff2_w, w_ff2, 1024*512);
    packw<<<dim3((96*512+255)/256),   256, 0, stream>>>(proj_w, w_proj, 96*512);
    mkcomb<<<dim3(544,4), 256, 0, stream>>>(m_wx, m_wdt, w_comb);

    stats_kernel<<<dim3(BB*16), 256, 0, stream>>>(x_enc, mean, stdv);
    tok_kernel<<<dim3(BB*40), 256, 0, stream>>>(x_enc, x_mark, mean, stdv, tokb);

    gemm3<1,0,1,1,0><<<dim3(66*4), 256, 0, stream>>>(tokb, 512, w_emb, 512,
        emb_b, h, DD, hb, 512, nullptr, MROWS, 512, 512);

    for (int l = 0; l < 2; ++l) {
        for (int dir = 0; dir < 2; ++dir) {
            int li = l*2 + dir;
            gemm3<0,0,1,0,0><<<dim3(66*8), 256, 0, stream>>>(hb, 512,
                w_win + (size_t)li*1024*512, 512, nullptr,
                xz, 2*DD, nullptr, 0, nullptr, MROWS, 1024, 512);
            conv_silu<<<dim3((MROWS*DD)/256), 256, 0, stream>>>(
                xz, m_convw + (size_t)li*DD*2, m_convb + (size_t)li*DD,
                xc, xcb, dir);
            gemm3<0,0,0,0,1><<<dim3(66*5), 256, 0, stream>>>(xcb, 512,
                w_comb + (size_t)li*544*512, 512, m_bdt + (size_t)li*DD,
                sp, 512, nullptr, 0, bc, MROWS, 544, 512);
            const float* al = m_alog + (size_t)li*DD*SS;
            const float* dpp = m_dpar + (size_t)li*DD;
            scan_p1<<<dim3(256, NCHK-1), 256, 0, stream>>>(sp, xc, bc, al,
                hs, psb, dir);
            scan_comb<<<dim3(256), 256, 0, stream>>>(hs, psb, hin);
            scan_p2<<<dim3(256, NCHK), 256, 0, stream>>>(sp, xc, xz, bc, al,
                dpp, hin, yb, dir);
            gemm3<0,0,1,0,0><<<dim3(66*4), 256, 0, stream>>>(yb, 512,
                w_wout + (size_t)li*512*512, 512, nullptr,
                (dir == 0) ? fbuf : rbuf, DD, nullptr, 0, nullptr,
                MROWS, 512, 512);
        }
        ln_kernel<<<dim3(MROWS), 64, 0, stream>>>(h, h, fbuf, rbuf,
            ln1_g + l*DD, ln1_b + l*DD, hb);
        gemm3<1,1,0,1,0><<<dim3(66*4), 256, 0, stream>>>(hb, 512,
            w_ff1 + (size_t)l*512*512, 512, ff1_b + l*DD,
            nullptr, 0, fftb, 512, nullptr, MROWS, 512, 512);
        gemm3<1,0,1,0,0><<<dim3(66*4), 256, 0, stream>>>(fftb, 512,
            w_ff2 + (size_t)l*512*512, 512, ff2_b + l*DD,
            xc, DD, nullptr, 0, nullptr, MROWS, 512, 512);
        ln_kernel<<<dim3(MROWS), 64, 0, stream>>>(h, h, xc, nullptr,
            ln2_g + l*DD, ln2_b + l*DD, hb);
    }
    ln_kernel<<<dim3(MROWS), 64, 0, stream>>>(fbuf, h, nullptr, nullptr,
                                              lnf_g, lnf_b, hb);
    // projection as MFMA GEMM + bias, then transpose/de-norm
    gemm3<1,0,1,0,0><<<dim3(66), 256, 0, stream>>>(hb, 512, w_proj, 512,
        proj_b, projtmp, 96, nullptr, 0, nullptr, MROWS, 96, 512);
    proj_fin<<<dim3(BB*4), 256, 0, stream>>>(projtmp, mean, stdv, out);
}

// Round 21
// 736.433 us; speedup vs baseline: 1.9074x; 1.1092x over previous
//
#include <hip/hip_runtime.h>
#include <hip/hip_bf16.h>
#include <math.h>
#include <stddef.h>

#define BB 32
#define TT 262
#define DD 512
#define SS 16
#define RR 32
#define SEQ 512
#define NV 256
#define PRED 96
#define MROWS (BB*TT)   // 8384
#define NCHK 8
#define CSZ 33          // 8*33 = 264 >= 262

typedef __attribute__((ext_vector_type(4))) float f32x4;
typedef __attribute__((ext_vector_type(8))) short s16x8;

// ---------------- bf16 helpers ----------------
__device__ inline ushort f2bu(float x) {
    __hip_bfloat16 h = __float2bfloat16(x);
    ushort u; __builtin_memcpy(&u, &h, 2); return u;
}
__device__ inline float bu2f(ushort u) {
    __hip_bfloat16 h; __builtin_memcpy(&h, &u, 2);
    return __bfloat162float(h);
}

// async global->LDS, 16B per lane
__device__ inline void gload_lds16(const void* g, void* l) {
    __builtin_amdgcn_global_load_lds(
        (const __attribute__((address_space(1))) void*)g,
        (__attribute__((address_space(3))) void*)l, 16, 0, 0);
}

// ---------------------------------------------------------------------------
// weight bf16 cast (row-major, any size)
// ---------------------------------------------------------------------------
__global__ __launch_bounds__(256)
void packw(const float* __restrict__ in, ushort* __restrict__ out, int total)
{
    int idx = blockIdx.x * 256 + threadIdx.x;
    if (idx >= total) return;
    out[idx] = f2bu(in[idx]);
}

// ---------------------------------------------------------------------------
// combined scan-projection weight (dt path folded through wdt), bf16
// ---------------------------------------------------------------------------
__global__ __launch_bounds__(256)
void mkcomb(const float* __restrict__ wx, const float* __restrict__ wdt,
            ushort* __restrict__ comb)
{
    int n  = blockIdx.x;
    int li = blockIdx.y;
    const float* wxl = wx + (size_t)li*64*512;
    ushort* outb = comb + ((size_t)li*544 + n)*512;
    if (n < 512) {
        __shared__ float wr[32];
        if (threadIdx.x < 32)
            wr[threadIdx.x] = wdt[(size_t)li*512*32 + (size_t)n*32 + threadIdx.x];
        __syncthreads();
        for (int kk = threadIdx.x; kk < 512; kk += 256) {
            float acc = 0.f;
            #pragma unroll
            for (int r = 0; r < 32; ++r)
                acc = fmaf(wr[r], wxl[r*512 + kk], acc);
            outb[kk] = f2bu(acc);
        }
    } else {
        int s = n - 512;
        for (int kk = threadIdx.x; kk < 512; kk += 256)
            outb[kk] = f2bu(wxl[(32+s)*512 + kk]);
    }
}

// ---------------------------------------------------------------------------
// per-(b,n) mean/std over SEQ. grid = BB*16, block 256 = 16n x 16tg.
// ---------------------------------------------------------------------------
__global__ __launch_bounds__(256)
void stats_kernel(const float* __restrict__ x_enc,
                  float* __restrict__ mean, float* __restrict__ stdv)
{
    int b  = blockIdx.x >> 4;
    int n0 = (blockIdx.x & 15) << 4;
    int nl = threadIdx.x & 15;
    int tg = threadIdx.x >> 4;
    int n = n0 + nl;
    const float* base = x_enc + (size_t)b*SEQ*NV + n;
    float s0 = 0.f, s1 = 0.f, q0 = 0.f, q1 = 0.f;
    #pragma unroll 8
    for (int i = 0; i < 16; ++i) {
        int t = tg + i*32;
        float v0 = base[(size_t)t*NV];
        float v1 = base[(size_t)(t+16)*NV];
        s0 += v0; q0 = fmaf(v0, v0, q0);
        s1 += v1; q1 = fmaf(v1, v1, q1);
    }
    float s = s0 + s1, q = q0 + q1;
    __shared__ float ls[16][17], lq[16][17];
    ls[tg][nl] = s; lq[tg][nl] = q;
    __syncthreads();
    if (tg < 8) { ls[tg][nl] += ls[tg+8][nl]; lq[tg][nl] += lq[tg+8][nl]; }
    __syncthreads();
    if (tg < 4) { ls[tg][nl] += ls[tg+4][nl]; lq[tg][nl] += lq[tg+4][nl]; }
    __syncthreads();
    if (tg < 2) { ls[tg][nl] += ls[tg+2][nl]; lq[tg][nl] += lq[tg+2][nl]; }
    __syncthreads();
    if (tg == 0) {
        s = ls[0][nl] + ls[1][nl];
        q = lq[0][nl] + lq[1][nl];
        float mu  = s * (1.f/SEQ);
        float var = q * (1.f/SEQ) - mu*mu;
        mean[b*NV + n] = mu;
        stdv[b*NV + n] = sqrtf(var + 1e-5f);
    }
}

// ---------------------------------------------------------------------------
// tok: normalized transpose, bf16 rows of 512
// ---------------------------------------------------------------------------
__global__ __launch_bounds__(256)
void tok_kernel(const float* __restrict__ x_enc, const float* __restrict__ x_mark,
                const float* __restrict__ mean, const float* __restrict__ stdv,
                ushort* __restrict__ tokb)
{
    int b  = blockIdx.x / 40;
    int r  = blockIdx.x % 40;
    int tt = r / 5;
    int vt = r % 5;
    int t0 = tt << 6, v0 = vt << 6;
    __shared__ float tile[64][65];
    int lv = threadIdx.x & 63;
    for (int i = threadIdx.x >> 6; i < 64; i += 4) {
        int t = t0 + i, v = v0 + lv;
        float val = 0.f;
        if (v < NV) {
            val = (x_enc[((size_t)b*SEQ + t)*NV + v] - mean[b*NV + v]) / stdv[b*NV + v];
        } else if (v < TT) {
            val = x_mark[((size_t)b*SEQ + t)*6 + (v - NV)];
        }
        tile[i][lv] = val;
    }
    __syncthreads();
    for (int i = threadIdx.x >> 6; i < 64; i += 4) {
        int v = v0 + i;
        if (v < TT) {
            size_t row = (size_t)b*TT + v;
            tokb[row*512 + t0 + lv] = f2bu(tile[lv][i]);
        }
    }
}

// ---------------------------------------------------------------------------
// bf16 MFMA GEMM (NT; K multiple of 64). 64x64 tile, 4 waves (2x2 of 32x32),
// double-buffered 32KB LDS. grid = 131 * ntile(Nn), n-fast + XCD swizzle.
// ---------------------------------------------------------------------------
template<int HAS_BIAS, int RELU, int WF32, int W3, int SCANEP>
__global__ __launch_bounds__(256)
void gemm3(const ushort* __restrict__ A3, int lda3,
           const ushort* __restrict__ W3p, int ldw3,
           const float* __restrict__ bias,
           float* __restrict__ C, int ldc,
           ushort* __restrict__ C3, int N_out,
           float* __restrict__ bcbuf,
           int M, int Nn, int K3)
{
    __shared__ ushort lds[2][2][64*64];   // [buf][A=0/W=1] : 32 KB total
    const int tid  = threadIdx.x;
    const int lane = tid & 63;
    const int wid  = tid >> 6;
    const int wr = wid >> 1, wc = wid & 1;

    // bijective XCD swizzle (m204), then n-fast tile decode
    int nwg = gridDim.x;
    int q8 = nwg >> 3, r8 = nwg & 7;
    int xcd = blockIdx.x & 7;
    int idx = blockIdx.x >> 3;
    int swz = (xcd < r8 ? xcd*(q8+1) : r8*(q8+1) + (xcd-r8)*q8) + idx;
    int ntile = (Nn + 63) >> 6;
    const int m0 = (swz / ntile) * 64;
    const int n0 = (swz % ntile) * 64;

    const int l8 = lane >> 3;
    const int sl = lane & 7;
    const int ssl = sl ^ l8;

    int arow[2], wrow[2];
    #pragma unroll
    for (int qq = 0; qq < 2; ++qq) {
        int r = (wid*2 + qq)*8 + l8;
        int ar = m0 + r; if (ar > M-1) ar = M-1;
        arow[qq] = ar;
        int wrr = n0 + r; if (wrr > Nn-1) wrr = Nn-1;
        wrow[qq] = wrr;
    }

    f32x4 acc[2][2];
    #pragma unroll
    for (int i = 0; i < 2; ++i)
        #pragma unroll
        for (int j = 0; j < 2; ++j) acc[i][j] = (f32x4){0.f,0.f,0.f,0.f};

    const int nk = K3 >> 6;
    const int rl = lane & 15;
    const int kq = lane >> 4;

    auto stage = [&](int buf_, int kt_) {
        #pragma unroll
        for (int qq = 0; qq < 2; ++qq) {
            int c = wid*2 + qq;
            gload_lds16(A3 + (size_t)arow[qq]*lda3 + kt_*64 + ssl*8,
                        (void*)&lds[buf_][0][c*512]);
            gload_lds16(W3p + (size_t)wrow[qq]*ldw3 + kt_*64 + ssl*8,
                        (void*)&lds[buf_][1][c*512]);
        }
    };

    stage(0, 0);
    __syncthreads();

    for (int kt = 0; kt < nk; ++kt) {
        int cur = kt & 1;
        if (kt + 1 < nk) stage(cur ^ 1, kt + 1);
        #pragma unroll
        for (int kk = 0; kk < 2; ++kk) {
            s16x8 av[2], wv[2];
            #pragma unroll
            for (int mi = 0; mi < 2; ++mi) {
                int row = wr*32 + mi*16 + rl;
                int ck = (kk*4 + kq) ^ (row & 7);
                av[mi] = *(const s16x8*)&lds[cur][0][row*64 + (ck<<3)];
            }
            #pragma unroll
            for (int ni = 0; ni < 2; ++ni) {
                int row = wc*32 + ni*16 + rl;
                int ck = (kk*4 + kq) ^ (row & 7);
                wv[ni] = *(const s16x8*)&lds[cur][1][row*64 + (ck<<3)];
            }
            #pragma unroll
            for (int mi = 0; mi < 2; ++mi)
                #pragma unroll
                for (int ni = 0; ni < 2; ++ni)
                    acc[mi][ni] = __builtin_amdgcn_mfma_f32_16x16x32_bf16(
                        av[mi], wv[ni], acc[mi][ni], 0, 0, 0);
        }
        __syncthreads();
    }

    #pragma unroll
    for (int ni = 0; ni < 2; ++ni) {
        int n = n0 + wc*32 + ni*16 + rl;
        if (n >= Nn) continue;
        float bv = (HAS_BIAS && !SCANEP) ? bias[n] : 0.f;
        #pragma unroll
        for (int mi = 0; mi < 2; ++mi) {
            #pragma unroll
            for (int j = 0; j < 4; ++j) {
                int m = m0 + wr*32 + mi*16 + kq*4 + j;
                if (m >= M) continue;
                float v = acc[mi][ni][j];
                if (SCANEP) {
                    if (n < 512) {
                        v += bias[n];
                        v = fmaxf(v, 0.f) + log1pf(__expf(-fabsf(v)));
                        C[(size_t)m*ldc + n] = v;
                    } else {
                        bcbuf[(size_t)m*32 + (n - 512)] = v;
                    }
                } else {
                    if (HAS_BIAS) v += bv;
                    if (RELU) v = fmaxf(v, 0.f);
                    if (WF32) C[(size_t)m*ldc + n] = v;
                    if (W3)   C3[(size_t)m*N_out + n] = f2bu(v);
                }
            }
        }
    }
}

// ---------------------------------------------------------------------------
// conv + SiLU (fp32 xc + bf16 xcb), in-place silu on z-half of xz
// ---------------------------------------------------------------------------
__global__ __launch_bounds__(256)
void conv_silu(float* __restrict__ xz, const float* __restrict__ cw,
               const float* __restrict__ cb, float* __restrict__ xc,
               ushort* __restrict__ xcb, int rev)
{
    int idx = blockIdx.x * 256 + threadIdx.x;
    int d  = idx & (DD-1);
    int bt = idx >> 9;
    int t  = bt % TT;
    float cur = xz[(size_t)bt*2*DD + d];
    int tn = rev ? t + 1 : t - 1;
    float prev = 0.f;
    if (tn >= 0 && tn < TT)
        prev = xz[((size_t)bt + (rev ? 1 : -1))*2*DD + d];
    float v = prev*cw[d*2] + cur*cw[d*2+1] + cb[d];
    float sv = v / (1.f + __expf(-v));
    xc[idx] = sv;
    xcb[(size_t)bt*512 + d] = f2bu(sv);
    float z = xz[(size_t)bt*2*DD + DD + d];
    xz[(size_t)bt*2*DD + DD + d] = z / (1.f + __expf(-z));
}

// ---------------------------------------------------------------------------
// Chunked scan, pass 1
// ---------------------------------------------------------------------------
__global__ __launch_bounds__(256)
void scan_p1(const float* __restrict__ sp_g, const float* __restrict__ xc_g,
             const float* __restrict__ bc_g, const float* __restrict__ alog,
             float* __restrict__ hs, float* __restrict__ ps, int rev)
{
    int sblk = blockIdx.x;
    int c    = blockIdx.y;
    int b  = sblk >> 3;
    int d0 = (sblk & 7) << 6;
    int tid = threadIdx.x;
    int sg = tid & 3;
    int dl = tid >> 2;
    int d  = d0 + dl;

    float Ac[4];
    #pragma unroll
    for (int j = 0; j < 4; ++j)
        Ac[j] = -__expf(alog[d*SS + sg*4 + j]);
    float h0=0.f,h1=0.f,h2=0.f,h3=0.f;
    float p0=1.f,p1=1.f,p2=1.f,p3=1.f;
    size_t bbase = (size_t)b*TT;
    int t0 = c*CSZ;
    #pragma unroll 3
    for (int i = 0; i < CSZ; ++i) {
        int t = t0 + i;
        size_t p = bbase + (rev ? TT-1-t : t);
        float spv = sp_g[p*DD + d];
        float xcv = xc_g[p*DD + d];
        float4 Bv = *(const float4*)(bc_g + p*32 + sg*4);
        float dtxc = spv*xcv;
        float e0 = __expf(spv*Ac[0]);
        float e1 = __expf(spv*Ac[1]);
        float e2 = __expf(spv*Ac[2]);
        float e3 = __expf(spv*Ac[3]);
        h0 = fmaf(e0,h0,dtxc*Bv.x); p0 *= e0;
        h1 = fmaf(e1,h1,dtxc*Bv.y); p1 *= e1;
        h2 = fmaf(e2,h2,dtxc*Bv.z); p2 *= e2;
        h3 = fmaf(e3,h3,dtxc*Bv.w); p3 *= e3;
    }
    size_t o = ((size_t)c*256 + sblk)*256 + tid;
    float4 hv; hv.x=h0; hv.y=h1; hv.z=h2; hv.w=h3;
    float4 pv; pv.x=p0; pv.y=p1; pv.z=p2; pv.w=p3;
    ((float4*)hs)[o] = hv;
    ((float4*)ps)[o] = pv;
}

// ---------------------------------------------------------------------------
// Chunked scan, combine
// ---------------------------------------------------------------------------
__global__ __launch_bounds__(256)
void scan_comb(const float* __restrict__ hs, const float* __restrict__ ps,
               float* __restrict__ hin)
{
    size_t gid = (size_t)blockIdx.x*256 + threadIdx.x;   // 65536
    float4 h = {0.f,0.f,0.f,0.f};
    for (int c = 0; c < NCHK-1; ++c) {
        size_t o = (size_t)c*65536 + gid;
        float4 hl = ((const float4*)hs)[o];
        float4 pv = ((const float4*)ps)[o];
        h.x = fmaf(pv.x, h.x, hl.x);
        h.y = fmaf(pv.y, h.y, hl.y);
        h.z = fmaf(pv.z, h.z, hl.z);
        h.w = fmaf(pv.w, h.w, hl.w);
        ((float4*)hin)[o] = h;
    }
}

// ---------------------------------------------------------------------------
// Chunked scan, pass 2
// ---------------------------------------------------------------------------
__global__ __launch_bounds__(256)
void scan_p2(const float* __restrict__ sp_g, const float* __restrict__ xc_g,
             const float* __restrict__ xz_g, const float* __restrict__ bc_g,
             const float* __restrict__ alog, const float* __restrict__ dparam,
             const float* __restrict__ hin, ushort* __restrict__ yb, int rev)
{
    int sblk = blockIdx.x;
    int c    = blockIdx.y;
    int b  = sblk >> 3;
    int d0 = (sblk & 7) << 6;
    int tid = threadIdx.x;
    int sg = tid & 3;
    int dl = tid >> 2;
    int d  = d0 + dl;

    float Ac[4];
    #pragma unroll
    for (int j = 0; j < 4; ++j)
        Ac[j] = -__expf(alog[d*SS + sg*4 + j]);
    float dp = dparam[d];
    float h0=0.f,h1=0.f,h2=0.f,h3=0.f;
    if (c > 0) {
        float4 hv = ((const float4*)hin)[((size_t)(c-1)*256 + sblk)*256 + tid];
        h0=hv.x; h1=hv.y; h2=hv.z; h3=hv.w;
    }
    size_t bbase = (size_t)b*TT;
    int t0 = c*CSZ;
    #pragma unroll 3
    for (int i = 0; i < CSZ; ++i) {
        int t = t0 + i;
        int tc = t < TT ? t : TT-1;
        size_t p = bbase + (rev ? TT-1-tc : tc);
        float spv = sp_g[p*DD + d];
        float xcv = xc_g[p*DD + d];
        float zsv = xz_g[p*2*DD + DD + d];
        float4 Bv = *(const float4*)(bc_g + p*32 + sg*4);
        float4 Cv = *(const float4*)(bc_g + p*32 + 16 + sg*4);
        float dtxc = spv*xcv;
        float e0 = __expf(spv*Ac[0]);
        float e1 = __expf(spv*Ac[1]);
        float e2 = __expf(spv*Ac[2]);
        float e3 = __expf(spv*Ac[3]);
        h0 = fmaf(e0,h0,dtxc*Bv.x);
        h1 = fmaf(e1,h1,dtxc*Bv.y);
        h2 = fmaf(e2,h2,dtxc*Bv.z);
        h3 = fmaf(e3,h3,dtxc*Bv.w);
        float dot = h0*Cv.x + h1*Cv.y + h2*Cv.z + h3*Cv.w;
        dot += __shfl_xor(dot, 1);
        dot += __shfl_xor(dot, 2);
        if (sg == 0 && t < TT) {
            int tg = rev ? TT-1-t : t;
            float yv = (dot + dp*xcv) * zsv;
            yb[(bbase + tg)*512 + d] = f2bu(yv);
        }
    }
}

// ---------------------------------------------------------------------------
// LayerNorm (up to 3 summed inputs), optional bf16 output
// ---------------------------------------------------------------------------
__global__ __launch_bounds__(64)
void ln_kernel(float* __restrict__ dst, const float* __restrict__ a,
               const float* __restrict__ b, const float* __restrict__ c,
               const float* __restrict__ g, const float* __restrict__ beta,
               ushort* __restrict__ outb)
{
    int row = blockIdx.x;
    int lane = threadIdx.x;
    size_t base = (size_t)row * DD;
    float x[8];
    #pragma unroll
    for (int j = 0; j < 2; ++j) {
        int e4 = j*64 + lane;
        float4 v = *(const float4*)(a + base + (size_t)e4*4);
        if (b) { float4 t = *(const float4*)(b + base + (size_t)e4*4); v.x+=t.x; v.y+=t.y; v.z+=t.z; v.w+=t.w; }
        if (c) { float4 t = *(const float4*)(c + base + (size_t)e4*4); v.x+=t.x; v.y+=t.y; v.z+=t.z; v.w+=t.w; }
        x[j*4+0]=v.x; x[j*4+1]=v.y; x[j*4+2]=v.z; x[j*4+3]=v.w;
    }
    float s = 0.f;
    #pragma unroll
    for (int i = 0; i < 8; ++i) s += x[i];
    #pragma unroll
    for (int m = 1; m < 64; m <<= 1) s += __shfl_xor(s, m);
    float mu = s * (1.f/DD);
    float vs = 0.f;
    #pragma unroll
    for (int i = 0; i < 8; ++i) { float dd = x[i]-mu; vs += dd*dd; }
    #pragma unroll
    for (int m = 1; m < 64; m <<= 1) vs += __shfl_xor(vs, m);
    float r = rsqrtf(vs*(1.f/DD) + 1e-5f);
    #pragma unroll
    for (int j = 0; j < 2; ++j) {
        int e4 = j*64 + lane;
        float4 gv = *(const float4*)(g    + (size_t)e4*4);
        float4 bv = *(const float4*)(beta + (size_t)e4*4);
        float4 o;
        o.x = (x[j*4+0]-mu)*r*gv.x + bv.x;
        o.y = (x[j*4+1]-mu)*r*gv.y + bv.y;
        o.z = (x[j*4+2]-mu)*r*gv.z + bv.z;
        o.w = (x[j*4+3]-mu)*r*gv.w + bv.w;
        *(float4*)(dst + base + (size_t)e4*4) = o;
        if (outb) {
            ushort* ob = outb + (size_t)row*512;
            ob[e4*4+0] = f2bu(o.x);
            ob[e4*4+1] = f2bu(o.y);
            ob[e4*4+2] = f2bu(o.z);
            ob[e4*4+3] = f2bu(o.w);
        }
    }
}

// ---------------------------------------------------------------------------
// proj finish: transpose [b*TT+n][96] -> out[b][p][n], de-normalize.
// ---------------------------------------------------------------------------
__global__ __launch_bounds__(256)
void proj_fin(const float* __restrict__ projtmp, const float* __restrict__ mean,
              const float* __restrict__ stdv, float* __restrict__ out)
{
    int b  = blockIdx.x >> 2;
    int n0 = (blockIdx.x & 3) << 6;
    __shared__ float tile[64][97];
    for (int i = threadIdx.x; i < 64*96; i += 256) {
        int rj = i / 96, cp = i % 96;
        tile[rj][cp] = projtmp[((size_t)b*TT + n0 + rj)*96 + cp];
    }
    __syncthreads();
    int nl = threadIdx.x & 63;
    int pg = threadIdx.x >> 6;          // 0..3
    int n = n0 + nl;
    float sd = stdv[b*NV + n];
    float mu = mean[b*NV + n];
    #pragma unroll
    for (int i = 0; i < 24; ++i) {
        int p = pg*24 + i;
        out[((size_t)b*PRED + p)*NV + n] = tile[nl][p]*sd + mu;
    }
}

// ---------------------------------------------------------------------------
extern "C" void kernel_launch(void* const* d_in, const int* in_sizes, int n_in,
                              void* d_out, int out_size, void* d_ws, size_t ws_size,
                              hipStream_t stream)
{
    (void)in_sizes; (void)n_in; (void)out_size; (void)ws_size;
    const float* x_enc   = (const float*)d_in[0];
    const float* x_mark  = (const float*)d_in[1];
    const float* emb_w   = (const float*)d_in[2];
    const float* emb_b   = (const float*)d_in[3];
    const float* m_win   = (const float*)d_in[4];
    const float* m_convw = (const float*)d_in[5];
    const float* m_convb = (const float*)d_in[6];
    const float* m_wx    = (const float*)d_in[7];
    const float* m_wdt   = (const float*)d_in[8];
    const float* m_bdt   = (const float*)d_in[9];
    const float* m_alog  = (const float*)d_in[10];
    const float* m_dpar  = (const float*)d_in[11];
    const float* m_wout  = (const float*)d_in[12];
    const float* ln1_g   = (const float*)d_in[13];
    const float* ln1_b   = (const float*)d_in[14];
    const float* ff1_w   = (const float*)d_in[15];
    const float* ff1_b   = (const float*)d_in[16];
    const float* ff2_w   = (const float*)d_in[17];
    const float* ff2_b   = (const float*)d_in[18];
    const float* ln2_g   = (const float*)d_in[19];
    const float* ln2_b   = (const float*)d_in[20];
    const float* lnf_g   = (const float*)d_in[21];
    const float* lnf_b   = (const float*)d_in[22];
    const float* proj_w  = (const float*)d_in[23];
    const float* proj_b  = (const float*)d_in[24];
    float* out = (float*)d_out;

    float* ws = (float*)d_ws;
    const size_t NBT = (size_t)MROWS;
    size_t off = 0;
    float* mean = ws + off; off += 8192;
    float* stdv = ws + off; off += 8192;
    ushort* w_emb  = (ushort*)(ws + off); off += 393216;
    ushort* w_win  = (ushort*)(ws + off); off += 3145728;
    ushort* w_wout = (ushort*)(ws + off); off += 1572864;
    ushort* w_ff1  = (ushort*)(ws + off); off += 786432;
    ushort* w_ff2  = (ushort*)(ws + off); off += 786432;
    ushort* w_comb = (ushort*)(ws + off); off += 1671168;
    ushort* w_proj = (ushort*)(ws + off); off += 24576;      // 96*512 bf16
    ushort* tokb = (ushort*)(ws + off); off += NBT*768;      // aliased: xcb, yb
    ushort* xcb = tokb;
    ushort* yb  = tokb;
    float* h   = ws + off; off += NBT*DD;
    ushort* hb = (ushort*)(ws + off); off += NBT*768;
    float* xz  = ws + off; off += NBT*2*DD;
    ushort* fftb = (ushort*)xz;                              // alias
    float* xc  = ws + off; off += NBT*DD;
    float* bc  = ws + off; off += NBT*32;
    float* sp  = ws + off; off += NBT*DD;
    float* fbuf = ws + off; off += NBT*DD;
    float* rbuf = ws + off; off += NBT*DD;
    float* hs  = ws + off; off += (NCHK-1)*65536*4;
    float* psb = ws + off; off += (NCHK-1)*65536*4;
    float* hin = ws + off; off += (NCHK-1)*65536*4;
    float* projtmp = ws + off; off += NBT*96;

    // ---- weight packing (bf16 cast) ----
    packw<<<dim3((512*512+255)/256),  256, 0, stream>>>(emb_w, w_emb, 512*512);
    packw<<<dim3((4096*512+255)/256), 256, 0, stream>>>(m_win, w_win, 4096*512);
    packw<<<dim3((2048*512+255)/256), 256, 0, stream>>>(m_wout, w_wout, 2048*512);
    packw<<<dim3((1024*512+255)/256), 256, 0, stream>>>(ff1_w, w_ff1, 1024*512);
    packw<<<dim3((1024*512+255)/256), 256, 0, stream>>>(ff2_w, w_ff2, 1024*512);
    packw<<<dim3((96*512+255)/256),   256, 0, stream>>>(proj_w, w_proj, 96*512);
    mkcomb<<<dim3(544,4), 256, 0, stream>>>(m_wx, m_wdt, w_comb);

    stats_kernel<<<dim3(BB*16), 256, 0, stream>>>(x_enc, mean, stdv);
    tok_kernel<<<dim3(BB*40), 256, 0, stream>>>(x_enc, x_mark, mean, stdv, tokb);

    // grids: 131 m-tiles x ntile((N+63)/64)
    gemm3<1,0,1,1,0><<<dim3(131*8), 256, 0, stream>>>(tokb, 512, w_emb, 512,
        emb_b, h, DD, hb, 512, nullptr, MROWS, 512, 512);

    for (int l = 0; l < 2; ++l) {
        for (int dir = 0; dir < 2; ++dir) {
            int li = l*2 + dir;
            gemm3<0,0,1,0,0><<<dim3(131*16), 256, 0, stream>>>(hb, 512,
                w_win + (size_t)li*1024*512, 512, nullptr,
                xz, 2*DD, nullptr, 0, nullptr, MROWS, 1024, 512);
            conv_silu<<<dim3((MROWS*DD)/256), 256, 0, stream>>>(
                xz, m_convw + (size_t)li*DD*2, m_convb + (size_t)li*DD,
                xc, xcb, dir);
            gemm3<0,0,0,0,1><<<dim3(131*9), 256, 0, stream>>>(xcb, 512,
                w_comb + (size_t)li*544*512, 512, m_bdt + (size_t)li*DD,
                sp, 512, nullptr, 0, bc, MROWS, 544, 512);
            const float* al = m_alog + (size_t)li*DD*SS;
            const float* dpp = m_dpar + (size_t)li*DD;
            scan_p1<<<dim3(256, NCHK-1), 256, 0, stream>>>(sp, xc, bc, al,
                hs, psb, dir);
            scan_comb<<<dim3(256), 256, 0, stream>>>(hs, psb, hin);
            scan_p2<<<dim3(256, NCHK), 256, 0, stream>>>(sp, xc, xz, bc, al,
                dpp, hin, yb, dir);
            gemm3<0,0,1,0,0><<<dim3(131*8), 256, 0, stream>>>(yb, 512,
                w_wout + (size_t)li*512*512, 512, nullptr,
                (dir == 0) ? fbuf : rbuf, DD, nullptr, 0, nullptr,
                MROWS, 512, 512);
        }
        ln_kernel<<<dim3(MROWS), 64, 0, stream>>>(h, h, fbuf, rbuf,
            ln1_g + l*DD, ln1_b + l*DD, hb);
        gemm3<1,1,0,1,0><<<dim3(131*8), 256, 0, stream>>>(hb, 512,
            w_ff1 + (size_t)l*512*512, 512, ff1_b + l*DD,
            nullptr, 0, fftb, 512, nullptr, MROWS, 512, 512);
        gemm3<1,0,1,0,0><<<dim3(131*8), 256, 0, stream>>>(fftb, 512,
            w_ff2 + (size_t)l*512*512, 512, ff2_b + l*DD,
            xc, DD, nullptr, 0, nullptr, MROWS, 512, 512);
        ln_kernel<<<dim3(MROWS), 64, 0, stream>>>(h, h, xc, nullptr,
            ln2_g + l*DD, ln2_b + l*DD, hb);
    }
    ln_kernel<<<dim3(MROWS), 64, 0, stream>>>(fbuf, h, nullptr, nullptr,
                                              lnf_g, lnf_b, hb);
    // projection as MFMA GEMM + bias, then transpose/de-norm
    gemm3<1,0,1,0,0><<<dim3(131*2), 256, 0, stream>>>(hb, 512, w_proj, 512,
        proj_b, projtmp, 96, nullptr, 0, nullptr, MROWS, 96, 512);
    proj_fin<<<dim3(BB*4), 256, 0, stream>>>(projtmp, mean, stdv, out);
}

// Round 22
// 723.366 us; speedup vs baseline: 1.9419x; 1.0181x over previous
//
#include <hip/hip_runtime.h>
#include <hip/hip_bf16.h>
#include <math.h>
#include <stddef.h>

#define BB 32
#define TT 262
#define DD 512
#define SS 16
#define RR 32
#define SEQ 512
#define NV 256
#define PRED 96
#define MROWS (BB*TT)   // 8384
#define NCHK 8
#define CSZ 33          // 8*33 = 264 >= 262

typedef __attribute__((ext_vector_type(4))) float f32x4;
typedef __attribute__((ext_vector_type(8))) short s16x8;

// ---------------- bf16 helpers ----------------
__device__ inline ushort f2bu(float x) {
    __hip_bfloat16 h = __float2bfloat16(x);
    ushort u; __builtin_memcpy(&u, &h, 2); return u;
}
__device__ inline float bu2f(ushort u) {
    __hip_bfloat16 h; __builtin_memcpy(&h, &u, 2);
    return __bfloat162float(h);
}

// async global->LDS, 16B per lane
__device__ inline void gload_lds16(const void* g, void* l) {
    __builtin_amdgcn_global_load_lds(
        (const __attribute__((address_space(1))) void*)g,
        (__attribute__((address_space(3))) void*)l, 16, 0, 0);
}

// ---------------------------------------------------------------------------
// weight bf16 cast (row-major, any size)
// ---------------------------------------------------------------------------
__global__ __launch_bounds__(256)
void packw(const float* __restrict__ in, ushort* __restrict__ out, int total)
{
    int idx = blockIdx.x * 256 + threadIdx.x;
    if (idx >= total) return;
    out[idx] = f2bu(in[idx]);
}

// ---------------------------------------------------------------------------
// combined scan-projection weight (dt path folded through wdt), bf16
// ---------------------------------------------------------------------------
__global__ __launch_bounds__(256)
void mkcomb(const float* __restrict__ wx, const float* __restrict__ wdt,
            ushort* __restrict__ comb)
{
    int n  = blockIdx.x;
    int li = blockIdx.y;
    const float* wxl = wx + (size_t)li*64*512;
    ushort* outb = comb + ((size_t)li*544 + n)*512;
    if (n < 512) {
        __shared__ float wr[32];
        if (threadIdx.x < 32)
            wr[threadIdx.x] = wdt[(size_t)li*512*32 + (size_t)n*32 + threadIdx.x];
        __syncthreads();
        for (int kk = threadIdx.x; kk < 512; kk += 256) {
            float acc = 0.f;
            #pragma unroll
            for (int r = 0; r < 32; ++r)
                acc = fmaf(wr[r], wxl[r*512 + kk], acc);
            outb[kk] = f2bu(acc);
        }
    } else {
        int s = n - 512;
        for (int kk = threadIdx.x; kk < 512; kk += 256)
            outb[kk] = f2bu(wxl[(32+s)*512 + kk]);
    }
}

// ---------------------------------------------------------------------------
// per-(b,n) mean/std over SEQ. grid = BB*16, block 256 = 16n x 16tg.
// ---------------------------------------------------------------------------
__global__ __launch_bounds__(256)
void stats_kernel(const float* __restrict__ x_enc,
                  float* __restrict__ mean, float* __restrict__ stdv)
{
    int b  = blockIdx.x >> 4;
    int n0 = (blockIdx.x & 15) << 4;
    int nl = threadIdx.x & 15;
    int tg = threadIdx.x >> 4;
    int n = n0 + nl;
    const float* base = x_enc + (size_t)b*SEQ*NV + n;
    float s0 = 0.f, s1 = 0.f, q0 = 0.f, q1 = 0.f;
    #pragma unroll 8
    for (int i = 0; i < 16; ++i) {
        int t = tg + i*32;
        float v0 = base[(size_t)t*NV];
        float v1 = base[(size_t)(t+16)*NV];
        s0 += v0; q0 = fmaf(v0, v0, q0);
        s1 += v1; q1 = fmaf(v1, v1, q1);
    }
    float s = s0 + s1, q = q0 + q1;
    __shared__ float ls[16][17], lq[16][17];
    ls[tg][nl] = s; lq[tg][nl] = q;
    __syncthreads();
    if (tg < 8) { ls[tg][nl] += ls[tg+8][nl]; lq[tg][nl] += lq[tg+8][nl]; }
    __syncthreads();
    if (tg < 4) { ls[tg][nl] += ls[tg+4][nl]; lq[tg][nl] += lq[tg+4][nl]; }
    __syncthreads();
    if (tg < 2) { ls[tg][nl] += ls[tg+2][nl]; lq[tg][nl] += lq[tg+2][nl]; }
    __syncthreads();
    if (tg == 0) {
        s = ls[0][nl] + ls[1][nl];
        q = lq[0][nl] + lq[1][nl];
        float mu  = s * (1.f/SEQ);
        float var = q * (1.f/SEQ) - mu*mu;
        mean[b*NV + n] = mu;
        stdv[b*NV + n] = sqrtf(var + 1e-5f);
    }
}

// ---------------------------------------------------------------------------
// tok: normalized transpose, bf16 rows of 512
// ---------------------------------------------------------------------------
__global__ __launch_bounds__(256)
void tok_kernel(const float* __restrict__ x_enc, const float* __restrict__ x_mark,
                const float* __restrict__ mean, const float* __restrict__ stdv,
                ushort* __restrict__ tokb)
{
    int b  = blockIdx.x / 40;
    int r  = blockIdx.x % 40;
    int tt = r / 5;
    int vt = r % 5;
    int t0 = tt << 6, v0 = vt << 6;
    __shared__ float tile[64][65];
    int lv = threadIdx.x & 63;
    for (int i = threadIdx.x >> 6; i < 64; i += 4) {
        int t = t0 + i, v = v0 + lv;
        float val = 0.f;
        if (v < NV) {
            val = (x_enc[((size_t)b*SEQ + t)*NV + v] - mean[b*NV + v]) / stdv[b*NV + v];
        } else if (v < TT) {
            val = x_mark[((size_t)b*SEQ + t)*6 + (v - NV)];
        }
        tile[i][lv] = val;
    }
    __syncthreads();
    for (int i = threadIdx.x >> 6; i < 64; i += 4) {
        int v = v0 + i;
        if (v < TT) {
            size_t row = (size_t)b*TT + v;
            tokb[row*512 + t0 + lv] = f2bu(tile[lv][i]);
        }
    }
}

// ---------------------------------------------------------------------------
// bf16 MFMA GEMM (NT; K multiple of 64). 128x64 tile, 4 waves (2M x 2N of
// 64x32), double-buffered 48KB LDS, 6 ds_read : 8 MFMA per kk.
// grid = 66 m-tiles * ntile(Nn), n-fast + XCD swizzle.
// ---------------------------------------------------------------------------
template<int HAS_BIAS, int RELU, int WF32, int W3, int SCANEP>
__global__ __launch_bounds__(256)
void gemm3(const ushort* __restrict__ A3, int lda3,
           const ushort* __restrict__ W3p, int ldw3,
           const float* __restrict__ bias,
           float* __restrict__ C, int ldc,
           ushort* __restrict__ C3, int N_out,
           float* __restrict__ bcbuf,
           int M, int Nn, int K3)
{
    __shared__ ushort lds[2][192*64];   // [buf][A(128x64) | W(64x64)] : 48 KB
    const int tid  = threadIdx.x;
    const int lane = tid & 63;
    const int wid  = tid >> 6;
    const int wr = wid >> 1, wc = wid & 1;

    // bijective XCD swizzle (m204), then n-fast tile decode
    int nwg = gridDim.x;
    int q8 = nwg >> 3, r8 = nwg & 7;
    int xcd = blockIdx.x & 7;
    int idx = blockIdx.x >> 3;
    int swz = (xcd < r8 ? xcd*(q8+1) : r8*(q8+1) + (xcd-r8)*q8) + idx;
    int ntile = (Nn + 63) >> 6;
    const int m0 = (swz / ntile) * 128;
    const int n0 = (swz % ntile) * 64;

    const int l8 = lane >> 3;
    const int sl = lane & 7;
    const int ssl = sl ^ l8;

    int arow[4], wrow[2];
    #pragma unroll
    for (int qq = 0; qq < 4; ++qq) {
        int r = (wid*4 + qq)*8 + l8;
        int ar = m0 + r; if (ar > M-1) ar = M-1;
        arow[qq] = ar;
    }
    #pragma unroll
    for (int qq = 0; qq < 2; ++qq) {
        int r = (wid*2 + qq)*8 + l8;
        int wrr = n0 + r; if (wrr > Nn-1) wrr = Nn-1;
        wrow[qq] = wrr;
    }

    f32x4 acc[4][2];
    #pragma unroll
    for (int i = 0; i < 4; ++i)
        #pragma unroll
        for (int j = 0; j < 2; ++j) acc[i][j] = (f32x4){0.f,0.f,0.f,0.f};

    const int nk = K3 >> 6;
    const int rl = lane & 15;
    const int kq = lane >> 4;

    auto stage = [&](int buf_, int kt_) {
        #pragma unroll
        for (int qq = 0; qq < 4; ++qq) {
            int c = wid*4 + qq;
            gload_lds16(A3 + (size_t)arow[qq]*lda3 + kt_*64 + ssl*8,
                        (void*)&lds[buf_][c*512]);
        }
        #pragma unroll
        for (int qq = 0; qq < 2; ++qq) {
            int c = wid*2 + qq;
            gload_lds16(W3p + (size_t)wrow[qq]*ldw3 + kt_*64 + ssl*8,
                        (void*)&lds[buf_][8192 + c*512]);
        }
    };

    stage(0, 0);
    __syncthreads();

    for (int kt = 0; kt < nk; ++kt) {
        int cur = kt & 1;
        if (kt + 1 < nk) stage(cur ^ 1, kt + 1);
        #pragma unroll
        for (int kk = 0; kk < 2; ++kk) {
            s16x8 av[4], wv[2];
            #pragma unroll
            for (int mi = 0; mi < 4; ++mi) {
                int row = wr*64 + mi*16 + rl;
                int ck = (kk*4 + kq) ^ (row & 7);
                av[mi] = *(const s16x8*)&lds[cur][row*64 + (ck<<3)];
            }
            #pragma unroll
            for (int ni = 0; ni < 2; ++ni) {
                int row = wc*32 + ni*16 + rl;
                int ck = (kk*4 + kq) ^ (row & 7);
                wv[ni] = *(const s16x8*)&lds[cur][8192 + row*64 + (ck<<3)];
            }
            #pragma unroll
            for (int mi = 0; mi < 4; ++mi)
                #pragma unroll
                for (int ni = 0; ni < 2; ++ni)
                    acc[mi][ni] = __builtin_amdgcn_mfma_f32_16x16x32_bf16(
                        av[mi], wv[ni], acc[mi][ni], 0, 0, 0);
        }
        __syncthreads();
    }

    #pragma unroll
    for (int ni = 0; ni < 2; ++ni) {
        int n = n0 + wc*32 + ni*16 + rl;
        if (n >= Nn) continue;
        float bv = (HAS_BIAS && !SCANEP) ? bias[n] : 0.f;
        #pragma unroll
        for (int mi = 0; mi < 4; ++mi) {
            #pragma unroll
            for (int j = 0; j < 4; ++j) {
                int m = m0 + wr*64 + mi*16 + kq*4 + j;
                if (m >= M) continue;
                float v = acc[mi][ni][j];
                if (SCANEP) {
                    if (n < 512) {
                        v += bias[n];
                        v = fmaxf(v, 0.f) + log1pf(__expf(-fabsf(v)));
                        C[(size_t)m*ldc + n] = v;
                    } else {
                        bcbuf[(size_t)m*32 + (n - 512)] = v;
                    }
                } else {
                    if (HAS_BIAS) v += bv;
                    if (RELU) v = fmaxf(v, 0.f);
                    if (WF32) C[(size_t)m*ldc + n] = v;
                    if (W3)   C3[(size_t)m*N_out + n] = f2bu(v);
                }
            }
        }
    }
}

// ---------------------------------------------------------------------------
// conv + SiLU (fp32 xc + bf16 xcb), in-place silu on z-half of xz
// ---------------------------------------------------------------------------
__global__ __launch_bounds__(256)
void conv_silu(float* __restrict__ xz, const float* __restrict__ cw,
               const float* __restrict__ cb, float* __restrict__ xc,
               ushort* __restrict__ xcb, int rev)
{
    int idx = blockIdx.x * 256 + threadIdx.x;
    int d  = idx & (DD-1);
    int bt = idx >> 9;
    int t  = bt % TT;
    float cur = xz[(size_t)bt*2*DD + d];
    int tn = rev ? t + 1 : t - 1;
    float prev = 0.f;
    if (tn >= 0 && tn < TT)
        prev = xz[((size_t)bt + (rev ? 1 : -1))*2*DD + d];
    float v = prev*cw[d*2] + cur*cw[d*2+1] + cb[d];
    float sv = v / (1.f + __expf(-v));
    xc[idx] = sv;
    xcb[(size_t)bt*512 + d] = f2bu(sv);
    float z = xz[(size_t)bt*2*DD + DD + d];
    xz[(size_t)bt*2*DD + DD + d] = z / (1.f + __expf(-z));
}

// ---------------------------------------------------------------------------
// Chunked scan, pass 1
// ---------------------------------------------------------------------------
__global__ __launch_bounds__(256)
void scan_p1(const float* __restrict__ sp_g, const float* __restrict__ xc_g,
             const float* __restrict__ bc_g, const float* __restrict__ alog,
             float* __restrict__ hs, float* __restrict__ ps, int rev)
{
    int sblk = blockIdx.x;
    int c    = blockIdx.y;
    int b  = sblk >> 3;
    int d0 = (sblk & 7) << 6;
    int tid = threadIdx.x;
    int sg = tid & 3;
    int dl = tid >> 2;
    int d  = d0 + dl;

    float Ac[4];
    #pragma unroll
    for (int j = 0; j < 4; ++j)
        Ac[j] = -__expf(alog[d*SS + sg*4 + j]);
    float h0=0.f,h1=0.f,h2=0.f,h3=0.f;
    float p0=1.f,p1=1.f,p2=1.f,p3=1.f;
    size_t bbase = (size_t)b*TT;
    int t0 = c*CSZ;
    #pragma unroll 3
    for (int i = 0; i < CSZ; ++i) {
        int t = t0 + i;
        size_t p = bbase + (rev ? TT-1-t : t);
        float spv = sp_g[p*DD + d];
        float xcv = xc_g[p*DD + d];
        float4 Bv = *(const float4*)(bc_g + p*32 + sg*4);
        float dtxc = spv*xcv;
        float e0 = __expf(spv*Ac[0]);
        float e1 = __expf(spv*Ac[1]);
        float e2 = __expf(spv*Ac[2]);
        float e3 = __expf(spv*Ac[3]);
        h0 = fmaf(e0,h0,dtxc*Bv.x); p0 *= e0;
        h1 = fmaf(e1,h1,dtxc*Bv.y); p1 *= e1;
        h2 = fmaf(e2,h2,dtxc*Bv.z); p2 *= e2;
        h3 = fmaf(e3,h3,dtxc*Bv.w); p3 *= e3;
    }
    size_t o = ((size_t)c*256 + sblk)*256 + tid;
    float4 hv; hv.x=h0; hv.y=h1; hv.z=h2; hv.w=h3;
    float4 pv; pv.x=p0; pv.y=p1; pv.z=p2; pv.w=p3;
    ((float4*)hs)[o] = hv;
    ((float4*)ps)[o] = pv;
}

// ---------------------------------------------------------------------------
// Chunked scan, combine
// ---------------------------------------------------------------------------
__global__ __launch_bounds__(256)
void scan_comb(const float* __restrict__ hs, const float* __restrict__ ps,
               float* __restrict__ hin)
{
    size_t gid = (size_t)blockIdx.x*256 + threadIdx.x;   // 65536
    float4 h = {0.f,0.f,0.f,0.f};
    for (int c = 0; c < NCHK-1; ++c) {
        size_t o = (size_t)c*65536 + gid;
        float4 hl = ((const float4*)hs)[o];
        float4 pv = ((const float4*)ps)[o];
        h.x = fmaf(pv.x, h.x, hl.x);
        h.y = fmaf(pv.y, h.y, hl.y);
        h.z = fmaf(pv.z, h.z, hl.z);
        h.w = fmaf(pv.w, h.w, hl.w);
        ((float4*)hin)[o] = h;
    }
}

// ---------------------------------------------------------------------------
// Chunked scan, pass 2
// ---------------------------------------------------------------------------
__global__ __launch_bounds__(256)
void scan_p2(const float* __restrict__ sp_g, const float* __restrict__ xc_g,
             const float* __restrict__ xz_g, const float* __restrict__ bc_g,
             const float* __restrict__ alog, const float* __restrict__ dparam,
             const float* __restrict__ hin, ushort* __restrict__ yb, int rev)
{
    int sblk = blockIdx.x;
    int c    = blockIdx.y;
    int b  = sblk >> 3;
    int d0 = (sblk & 7) << 6;
    int tid = threadIdx.x;
    int sg = tid & 3;
    int dl = tid >> 2;
    int d  = d0 + dl;

    float Ac[4];
    #pragma unroll
    for (int j = 0; j < 4; ++j)
        Ac[j] = -__expf(alog[d*SS + sg*4 + j]);
    float dp = dparam[d];
    float h0=0.f,h1=0.f,h2=0.f,h3=0.f;
    if (c > 0) {
        float4 hv = ((const float4*)hin)[((size_t)(c-1)*256 + sblk)*256 + tid];
        h0=hv.x; h1=hv.y; h2=hv.z; h3=hv.w;
    }
    size_t bbase = (size_t)b*TT;
    int t0 = c*CSZ;
    #pragma unroll 3
    for (int i = 0; i < CSZ; ++i) {
        int t = t0 + i;
        int tc = t < TT ? t : TT-1;
        size_t p = bbase + (rev ? TT-1-tc : tc);
        float spv = sp_g[p*DD + d];
        float xcv = xc_g[p*DD + d];
        float zsv = xz_g[p*2*DD + DD + d];
        float4 Bv = *(const float4*)(bc_g + p*32 + sg*4);
        float4 Cv = *(const float4*)(bc_g + p*32 + 16 + sg*4);
        float dtxc = spv*xcv;
        float e0 = __expf(spv*Ac[0]);
        float e1 = __expf(spv*Ac[1]);
        float e2 = __expf(spv*Ac[2]);
        float e3 = __expf(spv*Ac[3]);
        h0 = fmaf(e0,h0,dtxc*Bv.x);
        h1 = fmaf(e1,h1,dtxc*Bv.y);
        h2 = fmaf(e2,h2,dtxc*Bv.z);
        h3 = fmaf(e3,h3,dtxc*Bv.w);
        float dot = h0*Cv.x + h1*Cv.y + h2*Cv.z + h3*Cv.w;
        dot += __shfl_xor(dot, 1);
        dot += __shfl_xor(dot, 2);
        if (sg == 0 && t < TT) {
            int tg = rev ? TT-1-t : t;
            float yv = (dot + dp*xcv) * zsv;
            yb[(bbase + tg)*512 + d] = f2bu(yv);
        }
    }
}

// ---------------------------------------------------------------------------
// LayerNorm (up to 3 summed inputs), optional bf16 output
// ---------------------------------------------------------------------------
__global__ __launch_bounds__(64)
void ln_kernel(float* __restrict__ dst, const float* __restrict__ a,
               const float* __restrict__ b, const float* __restrict__ c,
               const float* __restrict__ g, const float* __restrict__ beta,
               ushort* __restrict__ outb)
{
    int row = blockIdx.x;
    int lane = threadIdx.x;
    size_t base = (size_t)row * DD;
    float x[8];
    #pragma unroll
    for (int j = 0; j < 2; ++j) {
        int e4 = j*64 + lane;
        float4 v = *(const float4*)(a + base + (size_t)e4*4);
        if (b) { float4 t = *(const float4*)(b + base + (size_t)e4*4); v.x+=t.x; v.y+=t.y; v.z+=t.z; v.w+=t.w; }
        if (c) { float4 t = *(const float4*)(c + base + (size_t)e4*4); v.x+=t.x; v.y+=t.y; v.z+=t.z; v.w+=t.w; }
        x[j*4+0]=v.x; x[j*4+1]=v.y; x[j*4+2]=v.z; x[j*4+3]=v.w;
    }
    float s = 0.f;
    #pragma unroll
    for (int i = 0; i < 8; ++i) s += x[i];
    #pragma unroll
    for (int m = 1; m < 64; m <<= 1) s += __shfl_xor(s, m);
    float mu = s * (1.f/DD);
    float vs = 0.f;
    #pragma unroll
    for (int i = 0; i < 8; ++i) { float dd = x[i]-mu; vs += dd*dd; }
    #pragma unroll
    for (int m = 1; m < 64; m <<= 1) vs += __shfl_xor(vs, m);
    float r = rsqrtf(vs*(1.f/DD) + 1e-5f);
    #pragma unroll
    for (int j = 0; j < 2; ++j) {
        int e4 = j*64 + lane;
        float4 gv = *(const float4*)(g    + (size_t)e4*4);
        float4 bv = *(const float4*)(beta + (size_t)e4*4);
        float4 o;
        o.x = (x[j*4+0]-mu)*r*gv.x + bv.x;
        o.y = (x[j*4+1]-mu)*r*gv.y + bv.y;
        o.z = (x[j*4+2]-mu)*r*gv.z + bv.z;
        o.w = (x[j*4+3]-mu)*r*gv.w + bv.w;
        *(float4*)(dst + base + (size_t)e4*4) = o;
        if (outb) {
            ushort* ob = outb + (size_t)row*512;
            ob[e4*4+0] = f2bu(o.x);
            ob[e4*4+1] = f2bu(o.y);
            ob[e4*4+2] = f2bu(o.z);
            ob[e4*4+3] = f2bu(o.w);
        }
    }
}

// ---------------------------------------------------------------------------
// proj finish: transpose [b*TT+n][96] -> out[b][p][n], de-normalize.
// ---------------------------------------------------------------------------
__global__ __launch_bounds__(256)
void proj_fin(const float* __restrict__ projtmp, const float* __restrict__ mean,
              const float* __restrict__ stdv, float* __restrict__ out)
{
    int b  = blockIdx.x >> 2;
    int n0 = (blockIdx.x & 3) << 6;
    __shared__ float tile[64][97];
    for (int i = threadIdx.x; i < 64*96; i += 256) {
        int rj = i / 96, cp = i % 96;
        tile[rj][cp] = projtmp[((size_t)b*TT + n0 + rj)*96 + cp];
    }
    __syncthreads();
    int nl = threadIdx.x & 63;
    int pg = threadIdx.x >> 6;          // 0..3
    int n = n0 + nl;
    float sd = stdv[b*NV + n];
    float mu = mean[b*NV + n];
    #pragma unroll
    for (int i = 0; i < 24; ++i) {
        int p = pg*24 + i;
        out[((size_t)b*PRED + p)*NV + n] = tile[nl][p]*sd + mu;
    }
}

// ---------------------------------------------------------------------------
extern "C" void kernel_launch(void* const* d_in, const int* in_sizes, int n_in,
                              void* d_out, int out_size, void* d_ws, size_t ws_size,
                              hipStream_t stream)
{
    (void)in_sizes; (void)n_in; (void)out_size; (void)ws_size;
    const float* x_enc   = (const float*)d_in[0];
    const float* x_mark  = (const float*)d_in[1];
    const float* emb_w   = (const float*)d_in[2];
    const float* emb_b   = (const float*)d_in[3];
    const float* m_win   = (const float*)d_in[4];
    const float* m_convw = (const float*)d_in[5];
    const float* m_convb = (const float*)d_in[6];
    const float* m_wx    = (const float*)d_in[7];
    const float* m_wdt   = (const float*)d_in[8];
    const float* m_bdt   = (const float*)d_in[9];
    const float* m_alog  = (const float*)d_in[10];
    const float* m_dpar  = (const float*)d_in[11];
    const float* m_wout  = (const float*)d_in[12];
    const float* ln1_g   = (const float*)d_in[13];
    const float* ln1_b   = (const float*)d_in[14];
    const float* ff1_w   = (const float*)d_in[15];
    const float* ff1_b   = (const float*)d_in[16];
    const float* ff2_w   = (const float*)d_in[17];
    const float* ff2_b   = (const float*)d_in[18];
    const float* ln2_g   = (const float*)d_in[19];
    const float* ln2_b   = (const float*)d_in[20];
    const float* lnf_g   = (const float*)d_in[21];
    const float* lnf_b   = (const float*)d_in[22];
    const float* proj_w  = (const float*)d_in[23];
    const float* proj_b  = (const float*)d_in[24];
    float* out = (float*)d_out;

    float* ws = (float*)d_ws;
    const size_t NBT = (size_t)MROWS;
    size_t off = 0;
    float* mean = ws + off; off += 8192;
    float* stdv = ws + off; off += 8192;
    ushort* w_emb  = (ushort*)(ws + off); off += 393216;
    ushort* w_win  = (ushort*)(ws + off); off += 3145728;
    ushort* w_wout = (ushort*)(ws + off); off += 1572864;
    ushort* w_ff1  = (ushort*)(ws + off); off += 786432;
    ushort* w_ff2  = (ushort*)(ws + off); off += 786432;
    ushort* w_comb = (ushort*)(ws + off); off += 1671168;
    ushort* w_proj = (ushort*)(ws + off); off += 24576;      // 96*512 bf16
    ushort* tokb = (ushort*)(ws + off); off += NBT*768;      // aliased: xcb, yb
    ushort* xcb = tokb;
    ushort* yb  = tokb;
    float* h   = ws + off; off += NBT*DD;
    ushort* hb = (ushort*)(ws + off); off += NBT*768;
    float* xz  = ws + off; off += NBT*2*DD;
    ushort* fftb = (ushort*)xz;                              // alias
    float* xc  = ws + off; off += NBT*DD;
    float* bc  = ws + off; off += NBT*32;
    float* sp  = ws + off; off += NBT*DD;
    float* fbuf = ws + off; off += NBT*DD;
    float* rbuf = ws + off; off += NBT*DD;
    float* hs  = ws + off; off += (NCHK-1)*65536*4;
    float* psb = ws + off; off += (NCHK-1)*65536*4;
    float* hin = ws + off; off += (NCHK-1)*65536*4;
    float* projtmp = ws + off; off += NBT*96;

    // ---- weight packing (bf16 cast) ----
    packw<<<dim3((512*512+255)/256),  256, 0, stream>>>(emb_w, w_emb, 512*512);
    packw<<<dim3((4096*512+255)/256), 256, 0, stream>>>(m_win, w_win, 4096*512);
    packw<<<dim3((2048*512+255)/256), 256, 0, stream>>>(m_wout, w_wout, 2048*512);
    packw<<<dim3((1024*512+255)/256), 256, 0, stream>>>(ff1_w, w_ff1, 1024*512);
    packw<<<dim3((1024*512+255)/256), 256, 0, stream>>>(ff2_w, w_ff2, 1024*512);
    packw<<<dim3((96*512+255)/256),   256, 0, stream>>>(proj_w, w_proj, 96*512);
    mkcomb<<<dim3(544,4), 256, 0, stream>>>(m_wx, m_wdt, w_comb);

    stats_kernel<<<dim3(BB*16), 256, 0, stream>>>(x_enc, mean, stdv);
    tok_kernel<<<dim3(BB*40), 256, 0, stream>>>(x_enc, x_mark, mean, stdv, tokb);

    // grids: 66 m-tiles x ntile((N+63)/64)
    gemm3<1,0,1,1,0><<<dim3(66*8), 256, 0, stream>>>(tokb, 512, w_emb, 512,
        emb_b, h, DD, hb, 512, nullptr, MROWS, 512, 512);

    for (int l = 0; l < 2; ++l) {
        for (int dir = 0; dir < 2; ++dir) {
            int li = l*2 + dir;
            gemm3<0,0,1,0,0><<<dim3(66*16), 256, 0, stream>>>(hb, 512,
                w_win + (size_t)li*1024*512, 512, nullptr,
                xz, 2*DD, nullptr, 0, nullptr, MROWS, 1024, 512);
            conv_silu<<<dim3((MROWS*DD)/256), 256, 0, stream>>>(
                xz, m_convw + (size_t)li*DD*2, m_convb + (size_t)li*DD,
                xc, xcb, dir);
            gemm3<0,0,0,0,1><<<dim3(66*9), 256, 0, stream>>>(xcb, 512,
                w_comb + (size_t)li*544*512, 512, m_bdt + (size_t)li*DD,
                sp, 512, nullptr, 0, bc, MROWS, 544, 512);
            const float* al = m_alog + (size_t)li*DD*SS;
            const float* dpp = m_dpar + (size_t)li*DD;
            scan_p1<<<dim3(256, NCHK-1), 256, 0, stream>>>(sp, xc, bc, al,
                hs, psb, dir);
            scan_comb<<<dim3(256), 256, 0, stream>>>(hs, psb, hin);
            scan_p2<<<dim3(256, NCHK), 256, 0, stream>>>(sp, xc, xz, bc, al,
                dpp, hin, yb, dir);
            gemm3<0,0,1,0,0><<<dim3(66*8), 256, 0, stream>>>(yb, 512,
                w_wout + (size_t)li*512*512, 512, nullptr,
                (dir == 0) ? fbuf : rbuf, DD, nullptr, 0, nullptr,
                MROWS, 512, 512);
        }
        ln_kernel<<<dim3(MROWS), 64, 0, stream>>>(h, h, fbuf, rbuf,
            ln1_g + l*DD, ln1_b + l*DD, hb);
        gemm3<1,1,0,1,0><<<dim3(66*8), 256, 0, stream>>>(hb, 512,
            w_ff1 + (size_t)l*512*512, 512, ff1_b + l*DD,
            nullptr, 0, fftb, 512, nullptr, MROWS, 512, 512);
        gemm3<1,0,1,0,0><<<dim3(66*8), 256, 0, stream>>>(fftb, 512,
            w_ff2 + (size_t)l*512*512, 512, ff2_b + l*DD,
            xc, DD, nullptr, 0, nullptr, MROWS, 512, 512);
        ln_kernel<<<dim3(MROWS), 64, 0, stream>>>(h, h, xc, nullptr,
            ln2_g + l*DD, ln2_b + l*DD, hb);
    }
    ln_kernel<<<dim3(MROWS), 64, 0, stream>>>(fbuf, h, nullptr, nullptr,
                                              lnf_g, lnf_b, hb);
    // projection as MFMA GEMM + bias, then transpose/de-norm
    gemm3<1,0,1,0,0><<<dim3(66*2), 256, 0, stream>>>(hb, 512, w_proj, 512,
        proj_b, projtmp, 96, nullptr, 0, nullptr, MROWS, 96, 512);
    proj_fin<<<dim3(BB*4), 256, 0, stream>>>(projtmp, mean, stdv, out);
}

// Round 24
// 702.196 us; speedup vs baseline: 2.0004x; 1.0301x over previous
//
#include <hip/hip_runtime.h>
#include <hip/hip_bf16.h>
#include <math.h>
#include <stddef.h>

#define BB 32
#define TT 262
#define DD 512
#define SS 16
#define RR 32
#define SEQ 512
#define NV 256
#define PRED 96
#define MROWS (BB*TT)   // 8384
#define NCHK 8
#define CSZ 33          // 8*33 = 264 >= 262

typedef __attribute__((ext_vector_type(4))) float f32x4;
typedef __attribute__((ext_vector_type(8))) short s16x8;

// ---------------- bf16 helpers ----------------
__device__ inline ushort f2bu(float x) {
    __hip_bfloat16 h = __float2bfloat16(x);
    ushort u; __builtin_memcpy(&u, &h, 2); return u;
}
__device__ inline float bu2f(ushort u) {
    __hip_bfloat16 h; __builtin_memcpy(&h, &u, 2);
    return __bfloat162float(h);
}

// async global->LDS, 16B per lane
__device__ inline void gload_lds16(const void* g, void* l) {
    __builtin_amdgcn_global_load_lds(
        (const __attribute__((address_space(1))) void*)g,
        (__attribute__((address_space(3))) void*)l, 16, 0, 0);
}

// ---------------------------------------------------------------------------
// weight bf16 cast (row-major, any size)
// ---------------------------------------------------------------------------
__global__ __launch_bounds__(256)
void packw(const float* __restrict__ in, ushort* __restrict__ out, int total)
{
    int idx = blockIdx.x * 256 + threadIdx.x;
    if (idx >= total) return;
    out[idx] = f2bu(in[idx]);
}

// ---------------------------------------------------------------------------
// combined scan-projection weight (dt path folded through wdt), bf16
// ---------------------------------------------------------------------------
__global__ __launch_bounds__(256)
void mkcomb(const float* __restrict__ wx, const float* __restrict__ wdt,
            ushort* __restrict__ comb)
{
    int n  = blockIdx.x;
    int li = blockIdx.y;
    const float* wxl = wx + (size_t)li*64*512;
    ushort* outb = comb + ((size_t)li*544 + n)*512;
    if (n < 512) {
        __shared__ float wr[32];
        if (threadIdx.x < 32)
            wr[threadIdx.x] = wdt[(size_t)li*512*32 + (size_t)n*32 + threadIdx.x];
        __syncthreads();
        for (int kk = threadIdx.x; kk < 512; kk += 256) {
            float acc = 0.f;
            #pragma unroll
            for (int r = 0; r < 32; ++r)
                acc = fmaf(wr[r], wxl[r*512 + kk], acc);
            outb[kk] = f2bu(acc);
        }
    } else {
        int s = n - 512;
        for (int kk = threadIdx.x; kk < 512; kk += 256)
            outb[kk] = f2bu(wxl[(32+s)*512 + kk]);
    }
}

// ---------------------------------------------------------------------------
// per-(b,n) mean/std over SEQ. grid = BB*16, block 256 = 16n x 16tg.
// ---------------------------------------------------------------------------
__global__ __launch_bounds__(256)
void stats_kernel(const float* __restrict__ x_enc,
                  float* __restrict__ mean, float* __restrict__ stdv)
{
    int b  = blockIdx.x >> 4;
    int n0 = (blockIdx.x & 15) << 4;
    int nl = threadIdx.x & 15;
    int tg = threadIdx.x >> 4;
    int n = n0 + nl;
    const float* base = x_enc + (size_t)b*SEQ*NV + n;
    float s0 = 0.f, s1 = 0.f, q0 = 0.f, q1 = 0.f;
    #pragma unroll 8
    for (int i = 0; i < 16; ++i) {
        int t = tg + i*32;
        float v0 = base[(size_t)t*NV];
        float v1 = base[(size_t)(t+16)*NV];
        s0 += v0; q0 = fmaf(v0, v0, q0);
        s1 += v1; q1 = fmaf(v1, v1, q1);
    }
    float s = s0 + s1, q = q0 + q1;
    __shared__ float ls[16][17], lq[16][17];
    ls[tg][nl] = s; lq[tg][nl] = q;
    __syncthreads();
    if (tg < 8) { ls[tg][nl] += ls[tg+8][nl]; lq[tg][nl] += lq[tg+8][nl]; }
    __syncthreads();
    if (tg < 4) { ls[tg][nl] += ls[tg+4][nl]; lq[tg][nl] += lq[tg+4][nl]; }
    __syncthreads();
    if (tg < 2) { ls[tg][nl] += ls[tg+2][nl]; lq[tg][nl] += lq[tg+2][nl]; }
    __syncthreads();
    if (tg == 0) {
        s = ls[0][nl] + ls[1][nl];
        q = lq[0][nl] + lq[1][nl];
        float mu  = s * (1.f/SEQ);
        float var = q * (1.f/SEQ) - mu*mu;
        mean[b*NV + n] = mu;
        stdv[b*NV + n] = sqrtf(var + 1e-5f);
    }
}

// ---------------------------------------------------------------------------
// tok: normalized transpose, bf16 rows of 512
// ---------------------------------------------------------------------------
__global__ __launch_bounds__(256)
void tok_kernel(const float* __restrict__ x_enc, const float* __restrict__ x_mark,
                const float* __restrict__ mean, const float* __restrict__ stdv,
                ushort* __restrict__ tokb)
{
    int b  = blockIdx.x / 40;
    int r  = blockIdx.x % 40;
    int tt = r / 5;
    int vt = r % 5;
    int t0 = tt << 6, v0 = vt << 6;
    __shared__ float tile[64][65];
    int lv = threadIdx.x & 63;
    for (int i = threadIdx.x >> 6; i < 64; i += 4) {
        int t = t0 + i, v = v0 + lv;
        float val = 0.f;
        if (v < NV) {
            val = (x_enc[((size_t)b*SEQ + t)*NV + v] - mean[b*NV + v]) / stdv[b*NV + v];
        } else if (v < TT) {
            val = x_mark[((size_t)b*SEQ + t)*6 + (v - NV)];
        }
        tile[i][lv] = val;
    }
    __syncthreads();
    for (int i = threadIdx.x >> 6; i < 64; i += 4) {
        int v = v0 + i;
        if (v < TT) {
            size_t row = (size_t)b*TT + v;
            tokb[row*512 + t0 + lv] = f2bu(tile[lv][i]);
        }
    }
}

// ---------------------------------------------------------------------------
// bf16 MFMA GEMM (NT; K multiple of 64). 128x64 tile, 4 waves (2M x 2N of
// 64x32), double-buffered 48KB LDS. grid = 66 * ntile(Nn), n-fast + XCD swz.
// SCANEP: n<512 -> softplus into C (ldc); n>=512 -> bcbuf[m*N_out + n-512].
// ---------------------------------------------------------------------------
template<int HAS_BIAS, int RELU, int WF32, int W3, int SCANEP>
__global__ __launch_bounds__(256)
void gemm3(const ushort* __restrict__ A3, int lda3,
           const ushort* __restrict__ W3p, int ldw3,
           const float* __restrict__ bias,
           float* __restrict__ C, int ldc,
           ushort* __restrict__ C3, int N_out,
           float* __restrict__ bcbuf,
           int M, int Nn, int K3)
{
    __shared__ ushort lds[2][192*64];   // [buf][A(128x64) | W(64x64)] : 48 KB
    const int tid  = threadIdx.x;
    const int lane = tid & 63;
    const int wid  = tid >> 6;
    const int wr = wid >> 1, wc = wid & 1;

    int nwg = gridDim.x;
    int q8 = nwg >> 3, r8 = nwg & 7;
    int xcd = blockIdx.x & 7;
    int idx = blockIdx.x >> 3;
    int swz = (xcd < r8 ? xcd*(q8+1) : r8*(q8+1) + (xcd-r8)*q8) + idx;
    int ntile = (Nn + 63) >> 6;
    const int m0 = (swz / ntile) * 128;
    const int n0 = (swz % ntile) * 64;

    const int l8 = lane >> 3;
    const int sl = lane & 7;
    const int ssl = sl ^ l8;

    int arow[4], wrow[2];
    #pragma unroll
    for (int qq = 0; qq < 4; ++qq) {
        int r = (wid*4 + qq)*8 + l8;
        int ar = m0 + r; if (ar > M-1) ar = M-1;
        arow[qq] = ar;
    }
    #pragma unroll
    for (int qq = 0; qq < 2; ++qq) {
        int r = (wid*2 + qq)*8 + l8;
        int wrr = n0 + r; if (wrr > Nn-1) wrr = Nn-1;
        wrow[qq] = wrr;
    }

    f32x4 acc[4][2];
    #pragma unroll
    for (int i = 0; i < 4; ++i)
        #pragma unroll
        for (int j = 0; j < 2; ++j) acc[i][j] = (f32x4){0.f,0.f,0.f,0.f};

    const int nk = K3 >> 6;
    const int rl = lane & 15;
    const int kq = lane >> 4;

    auto stage = [&](int buf_, int kt_) {
        #pragma unroll
        for (int qq = 0; qq < 4; ++qq) {
            int c = wid*4 + qq;
            gload_lds16(A3 + (size_t)arow[qq]*lda3 + kt_*64 + ssl*8,
                        (void*)&lds[buf_][c*512]);
        }
        #pragma unroll
        for (int qq = 0; qq < 2; ++qq) {
            int c = wid*2 + qq;
            gload_lds16(W3p + (size_t)wrow[qq]*ldw3 + kt_*64 + ssl*8,
                        (void*)&lds[buf_][8192 + c*512]);
        }
    };

    stage(0, 0);
    __syncthreads();

    for (int kt = 0; kt < nk; ++kt) {
        int cur = kt & 1;
        if (kt + 1 < nk) stage(cur ^ 1, kt + 1);
        #pragma unroll
        for (int kk = 0; kk < 2; ++kk) {
            s16x8 av[4], wv[2];
            #pragma unroll
            for (int mi = 0; mi < 4; ++mi) {
                int row = wr*64 + mi*16 + rl;
                int ck = (kk*4 + kq) ^ (row & 7);
                av[mi] = *(const s16x8*)&lds[cur][row*64 + (ck<<3)];
            }
            #pragma unroll
            for (int ni = 0; ni < 2; ++ni) {
                int row = wc*32 + ni*16 + rl;
                int ck = (kk*4 + kq) ^ (row & 7);
                wv[ni] = *(const s16x8*)&lds[cur][8192 + row*64 + (ck<<3)];
            }
            #pragma unroll
            for (int mi = 0; mi < 4; ++mi)
                #pragma unroll
                for (int ni = 0; ni < 2; ++ni)
                    acc[mi][ni] = __builtin_amdgcn_mfma_f32_16x16x32_bf16(
                        av[mi], wv[ni], acc[mi][ni], 0, 0, 0);
        }
        __syncthreads();
    }

    #pragma unroll
    for (int ni = 0; ni < 2; ++ni) {
        int n = n0 + wc*32 + ni*16 + rl;
        if (n >= Nn) continue;
        float bv = (HAS_BIAS && !SCANEP) ? bias[n] : 0.f;
        #pragma unroll
        for (int mi = 0; mi < 4; ++mi) {
            #pragma unroll
            for (int j = 0; j < 4; ++j) {
                int m = m0 + wr*64 + mi*16 + kq*4 + j;
                if (m >= M) continue;
                float v = acc[mi][ni][j];
                if (SCANEP) {
                    if (n < 512) {
                        v += bias[n];
                        v = fmaxf(v, 0.f) + log1pf(__expf(-fabsf(v)));
                        C[(size_t)m*ldc + n] = v;
                    } else {
                        bcbuf[(size_t)m*N_out + (n - 512)] = v;
                    }
                } else {
                    if (HAS_BIAS) v += bv;
                    if (RELU) v = fmaxf(v, 0.f);
                    if (WF32) C[(size_t)m*ldc + n] = v;
                    if (W3)   C3[(size_t)m*N_out + n] = f2bu(v);
                }
            }
        }
    }
}

// ---------------------------------------------------------------------------
// conv2: both dirs in one launch. xzb bf16 [M][2048]; writes merged xc fp32
// [M][1024], xcb bf16 [M][1024]; silu(z) in place (bf16).
// ---------------------------------------------------------------------------
__global__ __launch_bounds__(256)
void conv2(ushort* __restrict__ xzb, const float* __restrict__ cwB,
           const float* __restrict__ cbB, float* __restrict__ xc,
           ushort* __restrict__ xcb)
{
    int gid = blockIdx.x * 256 + threadIdx.x;   // 2*M*512 exact
    int d = gid & 511;
    int r = gid >> 9;
    int dir = (r >= MROWS) ? 1 : 0;
    int bt = r - dir*MROWS;
    int t = bt % TT;
    const float* cw = cwB + dir*DD*2;
    const float* cb = cbB + dir*DD;
    size_t base = (size_t)bt*2048 + (size_t)dir*1024;
    float cur = bu2f(xzb[base + d]);
    int tn = dir ? t + 1 : t - 1;
    float prev = 0.f;
    if (tn >= 0 && tn < TT)
        prev = bu2f(xzb[base + (dir ? 2048 : -2048) + d]);
    float v = prev*cw[d*2] + cur*cw[d*2+1] + cb[d];
    float sv = v / (1.f + __expf(-v));
    size_t o = (size_t)bt*1024 + dir*512 + d;
    xc[o] = sv;
    xcb[o] = f2bu(sv);
    float z = bu2f(xzb[base + 512 + d]);
    xzb[base + 512 + d] = f2bu(z / (1.f + __expf(-z)));
}

// ---------------------------------------------------------------------------
// Chunked scan, pass 1. sp/xc row stride 1024, bc row stride 64.
// ---------------------------------------------------------------------------
__global__ __launch_bounds__(256)
void scan_p1(const float* __restrict__ sp_g, const float* __restrict__ xc_g,
             const float* __restrict__ bc_g, const float* __restrict__ alog,
             float* __restrict__ hs, float* __restrict__ ps, int rev)
{
    int sblk = blockIdx.x;
    int c    = blockIdx.y;
    int b  = sblk >> 3;
    int d0 = (sblk & 7) << 6;
    int tid = threadIdx.x;
    int sg = tid & 3;
    int dl = tid >> 2;
    int d  = d0 + dl;

    float Ac[4];
    #pragma unroll
    for (int j = 0; j < 4; ++j)
        Ac[j] = -__expf(alog[d*SS + sg*4 + j]);
    float h0=0.f,h1=0.f,h2=0.f,h3=0.f;
    float p0=1.f,p1=1.f,p2=1.f,p3=1.f;
    size_t bbase = (size_t)b*TT;
    int t0 = c*CSZ;
    #pragma unroll 3
    for (int i = 0; i < CSZ; ++i) {
        int t = t0 + i;
        size_t p = bbase + (rev ? TT-1-t : t);
        float spv = sp_g[p*1024 + d];
        float xcv = xc_g[p*1024 + d];
        float4 Bv = *(const float4*)(bc_g + p*64 + sg*4);
        float dtxc = spv*xcv;
        float e0 = __expf(spv*Ac[0]);
        float e1 = __expf(spv*Ac[1]);
        float e2 = __expf(spv*Ac[2]);
        float e3 = __expf(spv*Ac[3]);
        h0 = fmaf(e0,h0,dtxc*Bv.x); p0 *= e0;
        h1 = fmaf(e1,h1,dtxc*Bv.y); p1 *= e1;
        h2 = fmaf(e2,h2,dtxc*Bv.z); p2 *= e2;
        h3 = fmaf(e3,h3,dtxc*Bv.w); p3 *= e3;
    }
    size_t o = ((size_t)c*256 + sblk)*256 + tid;
    float4 hv; hv.x=h0; hv.y=h1; hv.z=h2; hv.w=h3;
    float4 pv; pv.x=p0; pv.y=p1; pv.z=p2; pv.w=p3;
    ((float4*)hs)[o] = hv;
    ((float4*)ps)[o] = pv;
}

// ---------------------------------------------------------------------------
// Chunked scan, combine
// ---------------------------------------------------------------------------
__global__ __launch_bounds__(256)
void scan_comb(const float* __restrict__ hs, const float* __restrict__ ps,
               float* __restrict__ hin)
{
    size_t gid = (size_t)blockIdx.x*256 + threadIdx.x;   // 65536
    float4 h = {0.f,0.f,0.f,0.f};
    for (int c = 0; c < NCHK-1; ++c) {
        size_t o = (size_t)c*65536 + gid;
        float4 hl = ((const float4*)hs)[o];
        float4 pv = ((const float4*)ps)[o];
        h.x = fmaf(pv.x, h.x, hl.x);
        h.y = fmaf(pv.y, h.y, hl.y);
        h.z = fmaf(pv.z, h.z, hl.z);
        h.w = fmaf(pv.w, h.w, hl.w);
        ((float4*)hin)[o] = h;
    }
}

// ---------------------------------------------------------------------------
// Chunked scan, pass 2. z read bf16 from xzb (row stride 2048, +512 offset).
// ---------------------------------------------------------------------------
__global__ __launch_bounds__(256)
void scan_p2(const float* __restrict__ sp_g, const float* __restrict__ xc_g,
             const ushort* __restrict__ xz_u, const float* __restrict__ bc_g,
             const float* __restrict__ alog, const float* __restrict__ dparam,
             const float* __restrict__ hin, ushort* __restrict__ yb, int rev)
{
    int sblk = blockIdx.x;
    int c    = blockIdx.y;
    int b  = sblk >> 3;
    int d0 = (sblk & 7) << 6;
    int tid = threadIdx.x;
    int sg = tid & 3;
    int dl = tid >> 2;
    int d  = d0 + dl;

    float Ac[4];
    #pragma unroll
    for (int j = 0; j < 4; ++j)
        Ac[j] = -__expf(alog[d*SS + sg*4 + j]);
    float dp = dparam[d];
    float h0=0.f,h1=0.f,h2=0.f,h3=0.f;
    if (c > 0) {
        float4 hv = ((const float4*)hin)[((size_t)(c-1)*256 + sblk)*256 + tid];
        h0=hv.x; h1=hv.y; h2=hv.z; h3=hv.w;
    }
    size_t bbase = (size_t)b*TT;
    int t0 = c*CSZ;
    #pragma unroll 3
    for (int i = 0; i < CSZ; ++i) {
        int t = t0 + i;
        int tc = t < TT ? t : TT-1;
        size_t p = bbase + (rev ? TT-1-tc : tc);
        float spv = sp_g[p*1024 + d];
        float xcv = xc_g[p*1024 + d];
        float zsv = bu2f(xz_u[p*2048 + 512 + d]);
        float4 Bv = *(const float4*)(bc_g + p*64 + sg*4);
        float4 Cv = *(const float4*)(bc_g + p*64 + 16 + sg*4);
        float dtxc = spv*xcv;
        float e0 = __expf(spv*Ac[0]);
        float e1 = __expf(spv*Ac[1]);
        float e2 = __expf(spv*Ac[2]);
        float e3 = __expf(spv*Ac[3]);
        h0 = fmaf(e0,h0,dtxc*Bv.x);
        h1 = fmaf(e1,h1,dtxc*Bv.y);
        h2 = fmaf(e2,h2,dtxc*Bv.z);
        h3 = fmaf(e3,h3,dtxc*Bv.w);
        float dot = h0*Cv.x + h1*Cv.y + h2*Cv.z + h3*Cv.w;
        dot += __shfl_xor(dot, 1);
        dot += __shfl_xor(dot, 2);
        if (sg == 0 && t < TT) {
            int tg = rev ? TT-1-t : t;
            float yv = (dot + dp*xcv) * zsv;
            yb[(bbase + tg)*512 + d] = f2bu(yv);
        }
    }
}

// ---------------------------------------------------------------------------
// LayerNorm (up to 3 summed inputs), optional bf16 output
// ---------------------------------------------------------------------------
__global__ __launch_bounds__(64)
void ln_kernel(float* __restrict__ dst, const float* __restrict__ a,
               const float* __restrict__ b, const float* __restrict__ c,
               const float* __restrict__ g, const float* __restrict__ beta,
               ushort* __restrict__ outb)
{
    int row = blockIdx.x;
    int lane = threadIdx.x;
    size_t base = (size_t)row * DD;
    float x[8];
    #pragma unroll
    for (int j = 0; j < 2; ++j) {
        int e4 = j*64 + lane;
        float4 v = *(const float4*)(a + base + (size_t)e4*4);
        if (b) { float4 t = *(const float4*)(b + base + (size_t)e4*4); v.x+=t.x; v.y+=t.y; v.z+=t.z; v.w+=t.w; }
        if (c) { float4 t = *(const float4*)(c + base + (size_t)e4*4); v.x+=t.x; v.y+=t.y; v.z+=t.z; v.w+=t.w; }
        x[j*4+0]=v.x; x[j*4+1]=v.y; x[j*4+2]=v.z; x[j*4+3]=v.w;
    }
    float s = 0.f;
    #pragma unroll
    for (int i = 0; i < 8; ++i) s += x[i];
    #pragma unroll
    for (int m = 1; m < 64; m <<= 1) s += __shfl_xor(s, m);
    float mu = s * (1.f/DD);
    float vs = 0.f;
    #pragma unroll
    for (int i = 0; i < 8; ++i) { float dd = x[i]-mu; vs += dd*dd; }
    #pragma unroll
    for (int m = 1; m < 64; m <<= 1) vs += __shfl_xor(vs, m);
    float r = rsqrtf(vs*(1.f/DD) + 1e-5f);
    #pragma unroll
    for (int j = 0; j < 2; ++j) {
        int e4 = j*64 + lane;
        float4 gv = *(const float4*)(g    + (size_t)e4*4);
        float4 bv = *(const float4*)(beta + (size_t)e4*4);
        float4 o;
        o.x = (x[j*4+0]-mu)*r*gv.x + bv.x;
        o.y = (x[j*4+1]-mu)*r*gv.y + bv.y;
        o.z = (x[j*4+2]-mu)*r*gv.z + bv.z;
        o.w = (x[j*4+3]-mu)*r*gv.w + bv.w;
        *(float4*)(dst + base + (size_t)e4*4) = o;
        if (outb) {
            ushort* ob = outb + (size_t)row*512;
            ob[e4*4+0] = f2bu(o.x);
            ob[e4*4+1] = f2bu(o.y);
            ob[e4*4+2] = f2bu(o.z);
            ob[e4*4+3] = f2bu(o.w);
        }
    }
}

// ---------------------------------------------------------------------------
// proj finish: transpose [b*TT+n][96] -> out[b][p][n], de-normalize.
// ---------------------------------------------------------------------------
__global__ __launch_bounds__(256)
void proj_fin(const float* __restrict__ projtmp, const float* __restrict__ mean,
              const float* __restrict__ stdv, float* __restrict__ out)
{
    int b  = blockIdx.x >> 2;
    int n0 = (blockIdx.x & 3) << 6;
    __shared__ float tile[64][97];
    for (int i = threadIdx.x; i < 64*96; i += 256) {
        int rj = i / 96, cp = i % 96;
        tile[rj][cp] = projtmp[((size_t)b*TT + n0 + rj)*96 + cp];
    }
    __syncthreads();
    int nl = threadIdx.x & 63;
    int pg = threadIdx.x >> 6;          // 0..3
    int n = n0 + nl;
    float sd = stdv[b*NV + n];
    float mu = mean[b*NV + n];
    #pragma unroll
    for (int i = 0; i < 24; ++i) {
        int p = pg*24 + i;
        out[((size_t)b*PRED + p)*NV + n] = tile[nl][p]*sd + mu;
    }
}

// ---------------------------------------------------------------------------
extern "C" void kernel_launch(void* const* d_in, const int* in_sizes, int n_in,
                              void* d_out, int out_size, void* d_ws, size_t ws_size,
                              hipStream_t stream)
{
    (void)in_sizes; (void)n_in; (void)out_size; (void)ws_size;
    const float* x_enc   = (const float*)d_in[0];
    const float* x_mark  = (const float*)d_in[1];
    const float* emb_w   = (const float*)d_in[2];
    const float* emb_b   = (const float*)d_in[3];
    const float* m_win   = (const float*)d_in[4];
    const float* m_convw = (const float*)d_in[5];
    const float* m_convb = (const float*)d_in[6];
    const float* m_wx    = (const float*)d_in[7];
    const float* m_wdt   = (const float*)d_in[8];
    const float* m_bdt   = (const float*)d_in[9];
    const float* m_alog  = (const float*)d_in[10];
    const float* m_dpar  = (const float*)d_in[11];
    const float* m_wout  = (const float*)d_in[12];
    const float* ln1_g   = (const float*)d_in[13];
    const float* ln1_b   = (const float*)d_in[14];
    const float* ff1_w   = (const float*)d_in[15];
    const float* ff1_b   = (const float*)d_in[16];
    const float* ff2_w   = (const float*)d_in[17];
    const float* ff2_b   = (const float*)d_in[18];
    const float* ln2_g   = (const float*)d_in[19];
    const float* ln2_b   = (const float*)d_in[20];
    const float* lnf_g   = (const float*)d_in[21];
    const float* lnf_b   = (const float*)d_in[22];
    const float* proj_w  = (const float*)d_in[23];
    const float* proj_b  = (const float*)d_in[24];
    float* out = (float*)d_out;

    float* ws = (float*)d_ws;
    const size_t NBT = (size_t)MROWS;
    size_t off = 0;
    float* mean = ws + off; off += 8192;
    float* stdv = ws + off; off += 8192;
    ushort* w_emb  = (ushort*)(ws + off); off += 131072;     // 512*512 ush
    ushort* w_win  = (ushort*)(ws + off); off += 1048576;    // 4096*512 ush
    ushort* w_wout = (ushort*)(ws + off); off += 524288;     // 2048*512 ush
    ushort* w_ff1  = (ushort*)(ws + off); off += 262144;     // 1024*512 ush
    ushort* w_ff2  = (ushort*)(ws + off); off += 262144;
    ushort* w_comb = (ushort*)(ws + off); off += 557056;     // 4*544*512 ush
    ushort* w_proj = (ushort*)(ws + off); off += 24576;      // 96*512 ush
    ushort* pool = (ushort*)(ws + off); off += NBT*768;      // tokb | xcb | yb
    ushort* tokb = pool;                                     // [M][512] ush
    ushort* xcb  = pool;                                     // [M][1024] ush
    ushort* yb   = pool + NBT*1024;                          // [M][512] ush
    float* h   = ws + off; off += NBT*512;
    ushort* hb = (ushort*)(ws + off); off += NBT*256;        // [M][512] ush
    ushort* xzb = (ushort*)(ws + off); off += NBT*1024;      // [M][2048] ush
    ushort* fftb = xzb;                                      // alias (xzb dead at ffn)
    float* xc  = ws + off; off += NBT*1024;                  // merged [M][1024]
    float* bc2 = ws + off; off += NBT*64;                    // merged [M][64]
    float* sp  = ws + off; off += NBT*1024;                  // merged [M][1024]
    float* fbuf = ws + off; off += NBT*512;
    float* rbuf = ws + off; off += NBT*512;
    float* hs  = ws + off; off += (NCHK-1)*65536*4;
    float* psb = ws + off; off += (NCHK-1)*65536*4;
    float* hin = ws + off; off += (NCHK-1)*65536*4;
    float* projtmp = ws + off; off += NBT*96;

    // ---- weight packing (bf16 cast) ----
    packw<<<dim3((512*512+255)/256),  256, 0, stream>>>(emb_w, w_emb, 512*512);
    packw<<<dim3((4096*512+255)/256), 256, 0, stream>>>(m_win, w_win, 4096*512);
    packw<<<dim3((2048*512+255)/256), 256, 0, stream>>>(m_wout, w_wout, 2048*512);
    packw<<<dim3((1024*512+255)/256), 256, 0, stream>>>(ff1_w, w_ff1, 1024*512);
    packw<<<dim3((1024*512+255)/256), 256, 0, stream>>>(ff2_w, w_ff2, 1024*512);
    packw<<<dim3((96*512+255)/256),   256, 0, stream>>>(proj_w, w_proj, 96*512);
    mkcomb<<<dim3(544,4), 256, 0, stream>>>(m_wx, m_wdt, w_comb);

    stats_kernel<<<dim3(BB*16), 256, 0, stream>>>(x_enc, mean, stdv);
    tok_kernel<<<dim3(BB*40), 256, 0, stream>>>(x_enc, x_mark, mean, stdv, tokb);

    gemm3<1,0,1,1,0><<<dim3(66*8), 256, 0, stream>>>(tokb, 512, w_emb, 512,
        emb_b, h, DD, hb, 512, nullptr, MROWS, 512, 512);

    for (int l = 0; l < 2; ++l) {
        // merged win: N=2048 (dir0 cols 0..1023, dir1 1024..2047), bf16 out
        gemm3<0,0,0,1,0><<<dim3(66*32), 256, 0, stream>>>(hb, 512,
            w_win + (size_t)l*2048*512, 512, nullptr,
            nullptr, 0, xzb, 2048, nullptr, MROWS, 2048, 512);
        conv2<<<dim3((2*MROWS*DD)/256), 256, 0, stream>>>(xzb,
            m_convw + (size_t)l*2*DD*2, m_convb + (size_t)l*2*DD, xc, xcb);
        for (int dir = 0; dir < 2; ++dir) {
            int li = l*2 + dir;
            gemm3<0,0,0,0,1><<<dim3(66*9), 256, 0, stream>>>(
                xcb + dir*512, 1024,
                w_comb + (size_t)li*544*512, 512, m_bdt + (size_t)li*DD,
                sp + dir*512, 1024, nullptr, 64, bc2 + dir*32,
                MROWS, 544, 512);
        }
        for (int dir = 0; dir < 2; ++dir) {
            int li = l*2 + dir;
            const float* al = m_alog + (size_t)li*DD*SS;
            const float* dpp = m_dpar + (size_t)li*DD;
            scan_p1<<<dim3(256, NCHK-1), 256, 0, stream>>>(
                sp + dir*512, xc + dir*512, bc2 + dir*32, al, hs, psb, dir);
            scan_comb<<<dim3(256), 256, 0, stream>>>(hs, psb, hin);
            scan_p2<<<dim3(256, NCHK), 256, 0, stream>>>(
                sp + dir*512, xc + dir*512, xzb + dir*1024, bc2 + dir*32,
                al, dpp, hin, yb, dir);
            gemm3<0,0,1,0,0><<<dim3(66*8), 256, 0, stream>>>(yb, 512,
                w_wout + (size_t)li*512*512, 512, nullptr,
                (dir == 0) ? fbuf : rbuf, DD, nullptr, 0, nullptr,
                MROWS, 512, 512);
        }
        ln_kernel<<<dim3(MROWS), 64, 0, stream>>>(h, h, fbuf, rbuf,
            ln1_g + l*DD, ln1_b + l*DD, hb);
        gemm3<1,1,0,1,0><<<dim3(66*8), 256, 0, stream>>>(hb, 512,
            w_ff1 + (size_t)l*512*512, 512, ff1_b + l*DD,
            nullptr, 0, fftb, 512, nullptr, MROWS, 512, 512);
        gemm3<1,0,1,0,0><<<dim3(66*8), 256, 0, stream>>>(fftb, 512,
            w_ff2 + (size_t)l*512*512, 512, ff2_b + l*DD,
            xc, DD, nullptr, 0, nullptr, MROWS, 512, 512);
        ln_kernel<<<dim3(MROWS), 64, 0, stream>>>(h, h, xc, nullptr,
            ln2_g + l*DD, ln2_b + l*DD, hb);
    }
    ln_kernel<<<dim3(MROWS), 64, 0, stream>>>(fbuf, h, nullptr, nullptr,
                                              lnf_g, lnf_b, hb);
    gemm3<1,0,1,0,0><<<dim3(66*2), 256, 0, stream>>>(hb, 512, w_proj, 512,
        proj_b, projtmp, 96, nullptr, 0, nullptr, MROWS, 96, 512);
    proj_fin<<<dim3(BB*4), 256, 0, stream>>>(projtmp, mean, stdv, out);
}

// Round 25
// 655.767 us; speedup vs baseline: 2.1421x; 1.0708x over previous
//
#include <hip/hip_runtime.h>
#include <hip/hip_bf16.h>
#include <math.h>
#include <stddef.h>

#define BB 32
#define TT 262
#define DD 512
#define SS 16
#define RR 32
#define SEQ 512
#define NV 256
#define PRED 96
#define MROWS (BB*TT)   // 8384
#define NCHK 8
#define CSZ 33          // 8*33 = 264 >= 262

typedef __attribute__((ext_vector_type(4))) float f32x4;
typedef __attribute__((ext_vector_type(8))) short s16x8;

// ---------------- bf16 helpers ----------------
__device__ inline ushort f2bu(float x) {
    __hip_bfloat16 h = __float2bfloat16(x);
    ushort u; __builtin_memcpy(&u, &h, 2); return u;
}
__device__ inline float bu2f(ushort u) {
    __hip_bfloat16 h; __builtin_memcpy(&h, &u, 2);
    return __bfloat162float(h);
}

// async global->LDS, 16B per lane
__device__ inline void gload_lds16(const void* g, void* l) {
    __builtin_amdgcn_global_load_lds(
        (const __attribute__((address_space(1))) void*)g,
        (__attribute__((address_space(3))) void*)l, 16, 0, 0);
}

// ---------------------------------------------------------------------------
// weight bf16 cast (row-major, any size)
// ---------------------------------------------------------------------------
__global__ __launch_bounds__(256)
void packw(const float* __restrict__ in, ushort* __restrict__ out, int total)
{
    int idx = blockIdx.x * 256 + threadIdx.x;
    if (idx >= total) return;
    out[idx] = f2bu(in[idx]);
}

// ---------------------------------------------------------------------------
// combined scan-projection weight (dt path folded through wdt), bf16
// ---------------------------------------------------------------------------
__global__ __launch_bounds__(256)
void mkcomb(const float* __restrict__ wx, const float* __restrict__ wdt,
            ushort* __restrict__ comb)
{
    int n  = blockIdx.x;
    int li = blockIdx.y;
    const float* wxl = wx + (size_t)li*64*512;
    ushort* outb = comb + ((size_t)li*544 + n)*512;
    if (n < 512) {
        __shared__ float wr[32];
        if (threadIdx.x < 32)
            wr[threadIdx.x] = wdt[(size_t)li*512*32 + (size_t)n*32 + threadIdx.x];
        __syncthreads();
        for (int kk = threadIdx.x; kk < 512; kk += 256) {
            float acc = 0.f;
            #pragma unroll
            for (int r = 0; r < 32; ++r)
                acc = fmaf(wr[r], wxl[r*512 + kk], acc);
            outb[kk] = f2bu(acc);
        }
    } else {
        int s = n - 512;
        for (int kk = threadIdx.x; kk < 512; kk += 256)
            outb[kk] = f2bu(wxl[(32+s)*512 + kk]);
    }
}

// ---------------------------------------------------------------------------
// per-(b,n) mean/std over SEQ. grid = BB*16, block 256 = 16n x 16tg.
// ---------------------------------------------------------------------------
__global__ __launch_bounds__(256)
void stats_kernel(const float* __restrict__ x_enc,
                  float* __restrict__ mean, float* __restrict__ stdv)
{
    int b  = blockIdx.x >> 4;
    int n0 = (blockIdx.x & 15) << 4;
    int nl = threadIdx.x & 15;
    int tg = threadIdx.x >> 4;
    int n = n0 + nl;
    const float* base = x_enc + (size_t)b*SEQ*NV + n;
    float s0 = 0.f, s1 = 0.f, q0 = 0.f, q1 = 0.f;
    #pragma unroll 8
    for (int i = 0; i < 16; ++i) {
        int t = tg + i*32;
        float v0 = base[(size_t)t*NV];
        float v1 = base[(size_t)(t+16)*NV];
        s0 += v0; q0 = fmaf(v0, v0, q0);
        s1 += v1; q1 = fmaf(v1, v1, q1);
    }
    float s = s0 + s1, q = q0 + q1;
    __shared__ float ls[16][17], lq[16][17];
    ls[tg][nl] = s; lq[tg][nl] = q;
    __syncthreads();
    if (tg < 8) { ls[tg][nl] += ls[tg+8][nl]; lq[tg][nl] += lq[tg+8][nl]; }
    __syncthreads();
    if (tg < 4) { ls[tg][nl] += ls[tg+4][nl]; lq[tg][nl] += lq[tg+4][nl]; }
    __syncthreads();
    if (tg < 2) { ls[tg][nl] += ls[tg+2][nl]; lq[tg][nl] += lq[tg+2][nl]; }
    __syncthreads();
    if (tg == 0) {
        s = ls[0][nl] + ls[1][nl];
        q = lq[0][nl] + lq[1][nl];
        float mu  = s * (1.f/SEQ);
        float var = q * (1.f/SEQ) - mu*mu;
        mean[b*NV + n] = mu;
        stdv[b*NV + n] = sqrtf(var + 1e-5f);
    }
}

// ---------------------------------------------------------------------------
// tok: normalized transpose, bf16 rows of 512
// ---------------------------------------------------------------------------
__global__ __launch_bounds__(256)
void tok_kernel(const float* __restrict__ x_enc, const float* __restrict__ x_mark,
                const float* __restrict__ mean, const float* __restrict__ stdv,
                ushort* __restrict__ tokb)
{
    int b  = blockIdx.x / 40;
    int r  = blockIdx.x % 40;
    int tt = r / 5;
    int vt = r % 5;
    int t0 = tt << 6, v0 = vt << 6;
    __shared__ float tile[64][65];
    int lv = threadIdx.x & 63;
    for (int i = threadIdx.x >> 6; i < 64; i += 4) {
        int t = t0 + i, v = v0 + lv;
        float val = 0.f;
        if (v < NV) {
            val = (x_enc[((size_t)b*SEQ + t)*NV + v] - mean[b*NV + v]) / stdv[b*NV + v];
        } else if (v < TT) {
            val = x_mark[((size_t)b*SEQ + t)*6 + (v - NV)];
        }
        tile[i][lv] = val;
    }
    __syncthreads();
    for (int i = threadIdx.x >> 6; i < 64; i += 4) {
        int v = v0 + i;
        if (v < TT) {
            size_t row = (size_t)b*TT + v;
            tokb[row*512 + t0 + lv] = f2bu(tile[lv][i]);
        }
    }
}

// ---------------------------------------------------------------------------
// bf16 MFMA GEMM (NT; K multiple of 64). 128x64 tile, 4 waves (2M x 2N of
// 64x32), double-buffered 48KB LDS. grid = (66 * ntile(Nn), NDIR).
// gridDim.y = dir batch: per-dir pointer offsets aOff/wOff/biasOff/cOff/bcOff.
// SCANEP: n<512 -> softplus into C (ldc); n>=512 -> bcbuf[m*N_out + n-512].
// ---------------------------------------------------------------------------
template<int HAS_BIAS, int RELU, int WF32, int W3, int SCANEP>
__global__ __launch_bounds__(256)
void gemm3(const ushort* __restrict__ A3, int lda3,
           const ushort* __restrict__ W3p, int ldw3,
           const float* __restrict__ bias,
           float* __restrict__ C, int ldc,
           ushort* __restrict__ C3, int N_out,
           float* __restrict__ bcbuf,
           size_t aOff, size_t wOff, size_t biasOff, size_t cOff, size_t bcOff,
           int M, int Nn, int K3)
{
    const int dir = blockIdx.y;
    A3  += (size_t)dir * aOff;
    W3p += (size_t)dir * wOff;
    if (HAS_BIAS || SCANEP) bias += (size_t)dir * biasOff;
    if (WF32 || SCANEP) C += (size_t)dir * cOff;
    if (SCANEP) bcbuf += (size_t)dir * bcOff;

    __shared__ ushort lds[2][192*64];   // [buf][A(128x64) | W(64x64)] : 48 KB
    const int tid  = threadIdx.x;
    const int lane = tid & 63;
    const int wid  = tid >> 6;
    const int wr = wid >> 1, wc = wid & 1;

    int nwg = gridDim.x;
    int q8 = nwg >> 3, r8 = nwg & 7;
    int xcd = blockIdx.x & 7;
    int idx = blockIdx.x >> 3;
    int swz = (xcd < r8 ? xcd*(q8+1) : r8*(q8+1) + (xcd-r8)*q8) + idx;
    int ntile = (Nn + 63) >> 6;
    const int m0 = (swz / ntile) * 128;
    const int n0 = (swz % ntile) * 64;

    const int l8 = lane >> 3;
    const int sl = lane & 7;
    const int ssl = sl ^ l8;

    int arow[4], wrow[2];
    #pragma unroll
    for (int qq = 0; qq < 4; ++qq) {
        int r = (wid*4 + qq)*8 + l8;
        int ar = m0 + r; if (ar > M-1) ar = M-1;
        arow[qq] = ar;
    }
    #pragma unroll
    for (int qq = 0; qq < 2; ++qq) {
        int r = (wid*2 + qq)*8 + l8;
        int wrr = n0 + r; if (wrr > Nn-1) wrr = Nn-1;
        wrow[qq] = wrr;
    }

    f32x4 acc[4][2];
    #pragma unroll
    for (int i = 0; i < 4; ++i)
        #pragma unroll
        for (int j = 0; j < 2; ++j) acc[i][j] = (f32x4){0.f,0.f,0.f,0.f};

    const int nk = K3 >> 6;
    const int rl = lane & 15;
    const int kq = lane >> 4;

    auto stage = [&](int buf_, int kt_) {
        #pragma unroll
        for (int qq = 0; qq < 4; ++qq) {
            int c = wid*4 + qq;
            gload_lds16(A3 + (size_t)arow[qq]*lda3 + kt_*64 + ssl*8,
                        (void*)&lds[buf_][c*512]);
        }
        #pragma unroll
        for (int qq = 0; qq < 2; ++qq) {
            int c = wid*2 + qq;
            gload_lds16(W3p + (size_t)wrow[qq]*ldw3 + kt_*64 + ssl*8,
                        (void*)&lds[buf_][8192 + c*512]);
        }
    };

    stage(0, 0);
    __syncthreads();

    for (int kt = 0; kt < nk; ++kt) {
        int cur = kt & 1;
        if (kt + 1 < nk) stage(cur ^ 1, kt + 1);
        #pragma unroll
        for (int kk = 0; kk < 2; ++kk) {
            s16x8 av[4], wv[2];
            #pragma unroll
            for (int mi = 0; mi < 4; ++mi) {
                int row = wr*64 + mi*16 + rl;
                int ck = (kk*4 + kq) ^ (row & 7);
                av[mi] = *(const s16x8*)&lds[cur][row*64 + (ck<<3)];
            }
            #pragma unroll
            for (int ni = 0; ni < 2; ++ni) {
                int row = wc*32 + ni*16 + rl;
                int ck = (kk*4 + kq) ^ (row & 7);
                wv[ni] = *(const s16x8*)&lds[cur][8192 + row*64 + (ck<<3)];
            }
            #pragma unroll
            for (int mi = 0; mi < 4; ++mi)
                #pragma unroll
                for (int ni = 0; ni < 2; ++ni)
                    acc[mi][ni] = __builtin_amdgcn_mfma_f32_16x16x32_bf16(
                        av[mi], wv[ni], acc[mi][ni], 0, 0, 0);
        }
        __syncthreads();
    }

    #pragma unroll
    for (int ni = 0; ni < 2; ++ni) {
        int n = n0 + wc*32 + ni*16 + rl;
        if (n >= Nn) continue;
        float bv = (HAS_BIAS && !SCANEP) ? bias[n] : 0.f;
        #pragma unroll
        for (int mi = 0; mi < 4; ++mi) {
            #pragma unroll
            for (int j = 0; j < 4; ++j) {
                int m = m0 + wr*64 + mi*16 + kq*4 + j;
                if (m >= M) continue;
                float v = acc[mi][ni][j];
                if (SCANEP) {
                    if (n < 512) {
                        v += bias[n];
                        v = fmaxf(v, 0.f) + log1pf(__expf(-fabsf(v)));
                        C[(size_t)m*ldc + n] = v;
                    } else {
                        bcbuf[(size_t)m*N_out + (n - 512)] = v;
                    }
                } else {
                    if (HAS_BIAS) v += bv;
                    if (RELU) v = fmaxf(v, 0.f);
                    if (WF32) C[(size_t)m*ldc + n] = v;
                    if (W3)   C3[(size_t)m*N_out + n] = f2bu(v);
                }
            }
        }
    }
}

// ---------------------------------------------------------------------------
// conv2: both dirs in one launch. xzb bf16 [M][2048]; writes merged xc fp32
// [M][1024], xcb bf16 [M][1024]; silu(z) in place (bf16).
// ---------------------------------------------------------------------------
__global__ __launch_bounds__(256)
void conv2(ushort* __restrict__ xzb, const float* __restrict__ cwB,
           const float* __restrict__ cbB, float* __restrict__ xc,
           ushort* __restrict__ xcb)
{
    int gid = blockIdx.x * 256 + threadIdx.x;   // 2*M*512 exact
    int d = gid & 511;
    int r = gid >> 9;
    int dir = (r >= MROWS) ? 1 : 0;
    int bt = r - dir*MROWS;
    int t = bt % TT;
    const float* cw = cwB + dir*DD*2;
    const float* cb = cbB + dir*DD;
    size_t base = (size_t)bt*2048 + (size_t)dir*1024;
    float cur = bu2f(xzb[base + d]);
    int tn = dir ? t + 1 : t - 1;
    float prev = 0.f;
    if (tn >= 0 && tn < TT)
        prev = bu2f(xzb[base + (dir ? 2048 : -2048) + d]);
    float v = prev*cw[d*2] + cur*cw[d*2+1] + cb[d];
    float sv = v / (1.f + __expf(-v));
    size_t o = (size_t)bt*1024 + dir*512 + d;
    xc[o] = sv;
    xcb[o] = f2bu(sv);
    float z = bu2f(xzb[base + 512 + d]);
    xzb[base + 512 + d] = f2bu(z / (1.f + __expf(-z)));
}

// ---------------------------------------------------------------------------
// Chunked scan, pass 1. grid (256, NCHK-1, 2=dir). strides 1024/64.
// ---------------------------------------------------------------------------
__global__ __launch_bounds__(256)
void scan_p1(const float* __restrict__ sp_g, const float* __restrict__ xc_g,
             const float* __restrict__ bc_g, const float* __restrict__ alog,
             float* __restrict__ hs, float* __restrict__ ps)
{
    int dir = blockIdx.z;
    int rev = dir;
    sp_g += dir*512; xc_g += dir*512; bc_g += dir*32;
    alog += (size_t)dir*DD*SS;
    size_t doff = (size_t)dir*(NCHK-1)*65536*4;
    hs += doff; ps += doff;

    int sblk = blockIdx.x;
    int c    = blockIdx.y;
    int b  = sblk >> 3;
    int d0 = (sblk & 7) << 6;
    int tid = threadIdx.x;
    int sg = tid & 3;
    int dl = tid >> 2;
    int d  = d0 + dl;

    float Ac[4];
    #pragma unroll
    for (int j = 0; j < 4; ++j)
        Ac[j] = -__expf(alog[d*SS + sg*4 + j]);
    float h0=0.f,h1=0.f,h2=0.f,h3=0.f;
    float p0=1.f,p1=1.f,p2=1.f,p3=1.f;
    size_t bbase = (size_t)b*TT;
    int t0 = c*CSZ;
    #pragma unroll 3
    for (int i = 0; i < CSZ; ++i) {
        int t = t0 + i;
        size_t p = bbase + (rev ? TT-1-t : t);
        float spv = sp_g[p*1024 + d];
        float xcv = xc_g[p*1024 + d];
        float4 Bv = *(const float4*)(bc_g + p*64 + sg*4);
        float dtxc = spv*xcv;
        float e0 = __expf(spv*Ac[0]);
        float e1 = __expf(spv*Ac[1]);
        float e2 = __expf(spv*Ac[2]);
        float e3 = __expf(spv*Ac[3]);
        h0 = fmaf(e0,h0,dtxc*Bv.x); p0 *= e0;
        h1 = fmaf(e1,h1,dtxc*Bv.y); p1 *= e1;
        h2 = fmaf(e2,h2,dtxc*Bv.z); p2 *= e2;
        h3 = fmaf(e3,h3,dtxc*Bv.w); p3 *= e3;
    }
    size_t o = ((size_t)c*256 + sblk)*256 + tid;
    float4 hv; hv.x=h0; hv.y=h1; hv.z=h2; hv.w=h3;
    float4 pv; pv.x=p0; pv.y=p1; pv.z=p2; pv.w=p3;
    ((float4*)hs)[o] = hv;
    ((float4*)ps)[o] = pv;
}

// ---------------------------------------------------------------------------
// Chunked scan, combine. grid (256, 2=dir).
// ---------------------------------------------------------------------------
__global__ __launch_bounds__(256)
void scan_comb(const float* __restrict__ hs, const float* __restrict__ ps,
               float* __restrict__ hin)
{
    int dir = blockIdx.y;
    size_t doff = (size_t)dir*(NCHK-1)*65536;   // in f4 units
    size_t gid = (size_t)blockIdx.x*256 + threadIdx.x;   // 65536
    float4 h = {0.f,0.f,0.f,0.f};
    for (int c = 0; c < NCHK-1; ++c) {
        size_t o = doff + (size_t)c*65536 + gid;
        float4 hl = ((const float4*)hs)[o];
        float4 pv = ((const float4*)ps)[o];
        h.x = fmaf(pv.x, h.x, hl.x);
        h.y = fmaf(pv.y, h.y, hl.y);
        h.z = fmaf(pv.z, h.z, hl.z);
        h.w = fmaf(pv.w, h.w, hl.w);
        ((float4*)hin)[o] = h;
    }
}

// ---------------------------------------------------------------------------
// Chunked scan, pass 2. grid (256, NCHK, 2=dir). yb row-stacked [2M][512].
// ---------------------------------------------------------------------------
__global__ __launch_bounds__(256)
void scan_p2(const float* __restrict__ sp_g, const float* __restrict__ xc_g,
             const ushort* __restrict__ xz_u, const float* __restrict__ bc_g,
             const float* __restrict__ alog, const float* __restrict__ dparam,
             const float* __restrict__ hin, ushort* __restrict__ yb)
{
    int dir = blockIdx.z;
    int rev = dir;
    sp_g += dir*512; xc_g += dir*512; bc_g += dir*32; xz_u += dir*1024;
    alog += (size_t)dir*DD*SS; dparam += (size_t)dir*DD;
    hin += (size_t)dir*(NCHK-1)*65536*4;
    yb  += (size_t)dir*(size_t)MROWS*512;

    int sblk = blockIdx.x;
    int c    = blockIdx.y;
    int b  = sblk >> 3;
    int d0 = (sblk & 7) << 6;
    int tid = threadIdx.x;
    int sg = tid & 3;
    int dl = tid >> 2;
    int d  = d0 + dl;

    float Ac[4];
    #pragma unroll
    for (int j = 0; j < 4; ++j)
        Ac[j] = -__expf(alog[d*SS + sg*4 + j]);
    float dp = dparam[d];
    float h0=0.f,h1=0.f,h2=0.f,h3=0.f;
    if (c > 0) {
        float4 hv = ((const float4*)hin)[((size_t)(c-1)*256 + sblk)*256 + tid];
        h0=hv.x; h1=hv.y; h2=hv.z; h3=hv.w;
    }
    size_t bbase = (size_t)b*TT;
    int t0 = c*CSZ;
    #pragma unroll 3
    for (int i = 0; i < CSZ; ++i) {
        int t = t0 + i;
        int tc = t < TT ? t : TT-1;
        size_t p = bbase + (rev ? TT-1-tc : tc);
        float spv = sp_g[p*1024 + d];
        float xcv = xc_g[p*1024 + d];
        float zsv = bu2f(xz_u[p*2048 + 512 + d]);
        float4 Bv = *(const float4*)(bc_g + p*64 + sg*4);
        float4 Cv = *(const float4*)(bc_g + p*64 + 16 + sg*4);
        float dtxc = spv*xcv;
        float e0 = __expf(spv*Ac[0]);
        float e1 = __expf(spv*Ac[1]);
        float e2 = __expf(spv*Ac[2]);
        float e3 = __expf(spv*Ac[3]);
        h0 = fmaf(e0,h0,dtxc*Bv.x);
        h1 = fmaf(e1,h1,dtxc*Bv.y);
        h2 = fmaf(e2,h2,dtxc*Bv.z);
        h3 = fmaf(e3,h3,dtxc*Bv.w);
        float dot = h0*Cv.x + h1*Cv.y + h2*Cv.z + h3*Cv.w;
        dot += __shfl_xor(dot, 1);
        dot += __shfl_xor(dot, 2);
        if (sg == 0 && t < TT) {
            int tg = rev ? TT-1-t : t;
            float yv = (dot + dp*xcv) * zsv;
            yb[(bbase + tg)*512 + d] = f2bu(yv);
        }
    }
}

// ---------------------------------------------------------------------------
// LayerNorm (up to 3 summed inputs), optional bf16 output
// ---------------------------------------------------------------------------
__global__ __launch_bounds__(64)
void ln_kernel(float* __restrict__ dst, const float* __restrict__ a,
               const float* __restrict__ b, const float* __restrict__ c,
               const float* __restrict__ g, const float* __restrict__ beta,
               ushort* __restrict__ outb)
{
    int row = blockIdx.x;
    int lane = threadIdx.x;
    size_t base = (size_t)row * DD;
    float x[8];
    #pragma unroll
    for (int j = 0; j < 2; ++j) {
        int e4 = j*64 + lane;
        float4 v = *(const float4*)(a + base + (size_t)e4*4);
        if (b) { float4 t = *(const float4*)(b + base + (size_t)e4*4); v.x+=t.x; v.y+=t.y; v.z+=t.z; v.w+=t.w; }
        if (c) { float4 t = *(const float4*)(c + base + (size_t)e4*4); v.x+=t.x; v.y+=t.y; v.z+=t.z; v.w+=t.w; }
        x[j*4+0]=v.x; x[j*4+1]=v.y; x[j*4+2]=v.z; x[j*4+3]=v.w;
    }
    float s = 0.f;
    #pragma unroll
    for (int i = 0; i < 8; ++i) s += x[i];
    #pragma unroll
    for (int m = 1; m < 64; m <<= 1) s += __shfl_xor(s, m);
    float mu = s * (1.f/DD);
    float vs = 0.f;
    #pragma unroll
    for (int i = 0; i < 8; ++i) { float dd = x[i]-mu; vs += dd*dd; }
    #pragma unroll
    for (int m = 1; m < 64; m <<= 1) vs += __shfl_xor(vs, m);
    float r = rsqrtf(vs*(1.f/DD) + 1e-5f);
    #pragma unroll
    for (int j = 0; j < 2; ++j) {
        int e4 = j*64 + lane;
        float4 gv = *(const float4*)(g    + (size_t)e4*4);
        float4 bv = *(const float4*)(beta + (size_t)e4*4);
        float4 o;
        o.x = (x[j*4+0]-mu)*r*gv.x + bv.x;
        o.y = (x[j*4+1]-mu)*r*gv.y + bv.y;
        o.z = (x[j*4+2]-mu)*r*gv.z + bv.z;
        o.w = (x[j*4+3]-mu)*r*gv.w + bv.w;
        *(float4*)(dst + base + (size_t)e4*4) = o;
        if (outb) {
            ushort* ob = outb + (size_t)row*512;
            ob[e4*4+0] = f2bu(o.x);
            ob[e4*4+1] = f2bu(o.y);
            ob[e4*4+2] = f2bu(o.z);
            ob[e4*4+3] = f2bu(o.w);
        }
    }
}

// ---------------------------------------------------------------------------
// proj finish: transpose [b*TT+n][96] -> out[b][p][n], de-normalize.
// ---------------------------------------------------------------------------
__global__ __launch_bounds__(256)
void proj_fin(const float* __restrict__ projtmp, const float* __restrict__ mean,
              const float* __restrict__ stdv, float* __restrict__ out)
{
    int b  = blockIdx.x >> 2;
    int n0 = (blockIdx.x & 3) << 6;
    __shared__ float tile[64][97];
    for (int i = threadIdx.x; i < 64*96; i += 256) {
        int rj = i / 96, cp = i % 96;
        tile[rj][cp] = projtmp[((size_t)b*TT + n0 + rj)*96 + cp];
    }
    __syncthreads();
    int nl = threadIdx.x & 63;
    int pg = threadIdx.x >> 6;          // 0..3
    int n = n0 + nl;
    float sd = stdv[b*NV + n];
    float mu = mean[b*NV + n];
    #pragma unroll
    for (int i = 0; i < 24; ++i) {
        int p = pg*24 + i;
        out[((size_t)b*PRED + p)*NV + n] = tile[nl][p]*sd + mu;
    }
}

// ---------------------------------------------------------------------------
extern "C" void kernel_launch(void* const* d_in, const int* in_sizes, int n_in,
                              void* d_out, int out_size, void* d_ws, size_t ws_size,
                              hipStream_t stream)
{
    (void)in_sizes; (void)n_in; (void)out_size; (void)ws_size;
    const float* x_enc   = (const float*)d_in[0];
    const float* x_mark  = (const float*)d_in[1];
    const float* emb_w   = (const float*)d_in[2];
    const float* emb_b   = (const float*)d_in[3];
    const float* m_win   = (const float*)d_in[4];
    const float* m_convw = (const float*)d_in[5];
    const float* m_convb = (const float*)d_in[6];
    const float* m_wx    = (const float*)d_in[7];
    const float* m_wdt   = (const float*)d_in[8];
    const float* m_bdt   = (const float*)d_in[9];
    const float* m_alog  = (const float*)d_in[10];
    const float* m_dpar  = (const float*)d_in[11];
    const float* m_wout  = (const float*)d_in[12];
    const float* ln1_g   = (const float*)d_in[13];
    const float* ln1_b   = (const float*)d_in[14];
    const float* ff1_w   = (const float*)d_in[15];
    const float* ff1_b   = (const float*)d_in[16];
    const float* ff2_w   = (const float*)d_in[17];
    const float* ff2_b   = (const float*)d_in[18];
    const float* ln2_g   = (const float*)d_in[19];
    const float* ln2_b   = (const float*)d_in[20];
    const float* lnf_g   = (const float*)d_in[21];
    const float* lnf_b   = (const float*)d_in[22];
    const float* proj_w  = (const float*)d_in[23];
    const float* proj_b  = (const float*)d_in[24];
    float* out = (float*)d_out;

    float* ws = (float*)d_ws;
    const size_t NBT = (size_t)MROWS;
    size_t off = 0;
    float* mean = ws + off; off += 8192;
    float* stdv = ws + off; off += 8192;
    ushort* w_emb  = (ushort*)(ws + off); off += 131072;     // 512*512 ush
    ushort* w_win  = (ushort*)(ws + off); off += 1048576;    // 4096*512 ush
    ushort* w_wout = (ushort*)(ws + off); off += 524288;     // 2048*512 ush
    ushort* w_ff1  = (ushort*)(ws + off); off += 262144;     // 1024*512 ush
    ushort* w_ff2  = (ushort*)(ws + off); off += 262144;
    ushort* w_comb = (ushort*)(ws + off); off += 557056;     // 4*544*512 ush
    ushort* w_proj = (ushort*)(ws + off); off += 24576;      // 96*512 ush
    ushort* pool = (ushort*)(ws + off); off += NBT*768;      // tokb | xcb | yb2
    ushort* tokb = pool;                                     // [M][512] ush
    ushort* xcb  = pool;                                     // [M][1024] ush
    ushort* yb   = pool;                                     // [2M][512] ush (row-stacked)
    float* h   = ws + off; off += NBT*512;
    ushort* hb = (ushort*)(ws + off); off += NBT*256;        // [M][512] ush
    ushort* xzb = (ushort*)(ws + off); off += NBT*1024;      // [M][2048] ush
    ushort* fftb = xzb;                                      // alias (xzb dead at ffn)
    float* xc  = ws + off; off += NBT*1024;                  // merged [M][1024]
    float* bc2 = ws + off; off += NBT*64;                    // merged [M][64]
    float* sp  = ws + off; off += NBT*1024;                  // merged [M][1024]
    float* fbuf = ws + off; off += NBT*512;                  // fbuf|rbuf contiguous
    float* rbuf = ws + off; off += NBT*512;
    float* hs  = ws + off; off += (size_t)2*(NCHK-1)*65536*4;
    float* psb = ws + off; off += (size_t)2*(NCHK-1)*65536*4;
    float* hin = ws + off; off += (size_t)2*(NCHK-1)*65536*4;
    float* projtmp = ws + off; off += NBT*96;
    (void)rbuf;

    // ---- weight packing (bf16 cast) ----
    packw<<<dim3((512*512+255)/256),  256, 0, stream>>>(emb_w, w_emb, 512*512);
    packw<<<dim3((4096*512+255)/256), 256, 0, stream>>>(m_win, w_win, 4096*512);
    packw<<<dim3((2048*512+255)/256), 256, 0, stream>>>(m_wout, w_wout, 2048*512);
    packw<<<dim3((1024*512+255)/256), 256, 0, stream>>>(ff1_w, w_ff1, 1024*512);
    packw<<<dim3((1024*512+255)/256), 256, 0, stream>>>(ff2_w, w_ff2, 1024*512);
    packw<<<dim3((96*512+255)/256),   256, 0, stream>>>(proj_w, w_proj, 96*512);
    mkcomb<<<dim3(544,4), 256, 0, stream>>>(m_wx, m_wdt, w_comb);

    stats_kernel<<<dim3(BB*16), 256, 0, stream>>>(x_enc, mean, stdv);
    tok_kernel<<<dim3(BB*40), 256, 0, stream>>>(x_enc, x_mark, mean, stdv, tokb);

    gemm3<1,0,1,1,0><<<dim3(66*8), 256, 0, stream>>>(tokb, 512, w_emb, 512,
        emb_b, h, DD, hb, 512, nullptr, 0,0,0,0,0, MROWS, 512, 512);

    for (int l = 0; l < 2; ++l) {
        // merged win: N=2048 (both dirs), bf16 out
        gemm3<0,0,0,1,0><<<dim3(66*32), 256, 0, stream>>>(hb, 512,
            w_win + (size_t)l*2048*512, 512, nullptr,
            nullptr, 0, xzb, 2048, nullptr, 0,0,0,0,0, MROWS, 2048, 512);
        conv2<<<dim3((2*MROWS*DD)/256), 256, 0, stream>>>(xzb,
            m_convw + (size_t)l*2*DD*2, m_convb + (size_t)l*2*DD, xc, xcb);
        // comb GEMM, both dirs batched via gridDim.y
        gemm3<0,0,0,0,1><<<dim3(66*9, 2), 256, 0, stream>>>(
            xcb, 1024, w_comb + (size_t)l*2*544*512, 512,
            m_bdt + (size_t)l*2*DD, sp, 1024, nullptr, 64, bc2,
            /*aOff*/512, /*wOff*/(size_t)544*512, /*biasOff*/512,
            /*cOff*/512, /*bcOff*/32, MROWS, 544, 512);
        // scans, both dirs batched via grid.z / grid.y
        const float* al = m_alog + (size_t)l*2*DD*SS;
        const float* dpp = m_dpar + (size_t)l*2*DD;
        scan_p1<<<dim3(256, NCHK-1, 2), 256, 0, stream>>>(sp, xc, bc2, al,
            hs, psb);
        scan_comb<<<dim3(256, 2), 256, 0, stream>>>(hs, psb, hin);
        scan_p2<<<dim3(256, NCHK, 2), 256, 0, stream>>>(sp, xc, xzb, bc2,
            al, dpp, hin, yb);
        // wout, both dirs batched: A rows stacked, C fbuf|rbuf contiguous
        gemm3<0,0,1,0,0><<<dim3(66*8, 2), 256, 0, stream>>>(yb, 512,
            w_wout + (size_t)l*2*512*512, 512, nullptr,
            fbuf, DD, nullptr, 0, nullptr,
            /*aOff*/NBT*512, /*wOff*/(size_t)512*512, /*biasOff*/0,
            /*cOff*/NBT*512, /*bcOff*/0, MROWS, 512, 512);
        ln_kernel<<<dim3(MROWS), 64, 0, stream>>>(h, h, fbuf, rbuf,
            ln1_g + l*DD, ln1_b + l*DD, hb);
        gemm3<1,1,0,1,0><<<dim3(66*8), 256, 0, stream>>>(hb, 512,
            w_ff1 + (size_t)l*512*512, 512, ff1_b + l*DD,
            nullptr, 0, fftb, 512, nullptr, 0,0,0,0,0, MROWS, 512, 512);
        gemm3<1,0,1,0,0><<<dim3(66*8), 256, 0, stream>>>(fftb, 512,
            w_ff2 + (size_t)l*512*512, 512, ff2_b + l*DD,
            xc, DD, nullptr, 0, nullptr, 0,0,0,0,0, MROWS, 512, 512);
        ln_kernel<<<dim3(MROWS), 64, 0, stream>>>(h, h, xc, nullptr,
            ln2_g + l*DD, ln2_b + l*DD, hb);
    }
    ln_kernel<<<dim3(MROWS), 64, 0, stream>>>(fbuf, h, nullptr, nullptr,
                                              lnf_g, lnf_b, hb);
    gemm3<1,0,1,0,0><<<dim3(66*2), 256, 0, stream>>>(hb, 512, w_proj, 512,
        proj_b, projtmp, 96, nullptr, 0, nullptr, 0,0,0,0,0, MROWS, 96, 512);
    proj_fin<<<dim3(BB*4), 256, 0, stream>>>(projtmp, mean, stdv, out);
}